// Round 1
// baseline (1221.969 us; speedup 1.0000x reference)
//
#include <hip/hip_runtime.h>
#include <math.h>

#define NN 10000
#define EE 320000
#define DD 256
#define NT 10001            // NN + virtual node
#define E1C (EE + NN)       // 330000
#define E2C (EE + 2 * NN)   // 340000
#define ETC (E2C + NT)      // 350001 (with self loops)

// ---------- reduction helpers (blockDim.x == 256 assumed) ----------
__device__ __forceinline__ float wave_sum(float v) {
#pragma unroll
    for (int o = 32; o > 0; o >>= 1) v += __shfl_down(v, o, 64);
    return v;
}
__device__ __forceinline__ float wave_max(float v) {
#pragma unroll
    for (int o = 32; o > 0; o >>= 1) v = fmaxf(v, __shfl_down(v, o, 64));
    return v;
}
__device__ __forceinline__ float blk_sum256(float v, float* sm4) {
    v = wave_sum(v);
    int lane = threadIdx.x & 63, w = threadIdx.x >> 6;
    __syncthreads();
    if (lane == 0) sm4[w] = v;
    __syncthreads();
    return sm4[0] + sm4[1] + sm4[2] + sm4[3];
}

// ---------- node encoder: h0 = relu(LN(x @ enc_w + enc_b)) ----------
__global__ void k_enc(const float* __restrict__ x, const float* __restrict__ w,
                      const float* __restrict__ b, const float* __restrict__ g,
                      const float* __restrict__ bt, float* __restrict__ h) {
    __shared__ float sm4[4];
    __shared__ float xr[10];
    int v = blockIdx.x, j = threadIdx.x;
    if (j < 10) xr[j] = x[v * 10 + j];
    __syncthreads();
    float acc = b[j];
#pragma unroll
    for (int k = 0; k < 10; k++) acc += xr[k] * w[k * DD + j];
    float m = blk_sum256(acc, sm4) * (1.f / DD);
    float d = acc - m;
    float var = blk_sum256(d * d, sm4) * (1.f / DD);
    float y = d * rsqrtf(var + 1e-5f) * g[j] + bt[j];
    h[v * DD + j] = fmaxf(y, 0.f);
}

// ---------- column sums of h0 for ctx ----------
__global__ void k_ctx(const float* __restrict__ h, float* __restrict__ ctx) {
    int c = threadIdx.x;
    float acc = 0.f;
    for (int v = blockIdx.x; v < NN; v += gridDim.x) acc += h[v * DD + c];
    atomicAdd(&ctx[c], acc);
}

// ---------- adaptive virtual node ----------
__global__ void k_vn(const float* __restrict__ ctx,
                     const float* __restrict__ w1, const float* __restrict__ b1,
                     const float* __restrict__ g, const float* __restrict__ bt,
                     const float* __restrict__ w2, const float* __restrict__ b2,
                     const float* __restrict__ vnb,
                     float* __restrict__ h, float* __restrict__ comb) {
    __shared__ float sm4[4];
    __shared__ float cs[DD];
    __shared__ float t[DD];
    int j = threadIdx.x;
    cs[j] = ctx[j] * (1.f / NN);
    __syncthreads();
    float acc = b1[j];
    for (int k = 0; k < DD; k++) acc += cs[k] * w1[k * DD + j];
    float m = blk_sum256(acc, sm4) * (1.f / DD);
    float d = acc - m;
    float var = blk_sum256(d * d, sm4) * (1.f / DD);
    float y = fmaxf(d * rsqrtf(var + 1e-5f) * g[j] + bt[j], 0.f);
    t[j] = y;
    __syncthreads();
    float a2 = b2[j];
    for (int k = 0; k < DD; k++) a2 += t[k] * w2[k * DD + j];
    float vn = vnb[j] + tanhf(a2);
    h[NN * DD + j] = vn;
    comb[j] = vn;   // jk slot 0 (virtual row of initial h)
}

// ---------- degree + edge-attr sums over dst0 (first E2C edges) ----------
__global__ void k_deg(const int* __restrict__ ei, const float* __restrict__ ea,
                      int* __restrict__ degi, float* __restrict__ asum) {
    int e = blockIdx.x * 256 + threadIdx.x;
    if (e >= E2C) return;
    int dst; float a0, a1, a2;
    if (e < EE)       { dst = ei[EE + e]; a0 = ea[e * 3]; a1 = ea[e * 3 + 1]; a2 = ea[e * 3 + 2]; }
    else if (e < E1C) { dst = e - EE; a0 = 0.5f; a1 = 0.f; a2 = 0.f; }
    else              { dst = NN;     a0 = 0.5f; a1 = 0.f; a2 = 0.f; }
    atomicAdd(&degi[dst], 1);
    atomicAdd(&asum[dst * 3], a0);
    if (a1 != 0.f) atomicAdd(&asum[dst * 3 + 1], a1);
    if (a2 != 0.f) atomicAdd(&asum[dst * 3 + 2], a2);
}

__global__ void k_loopattr(const int* __restrict__ degi, const float* __restrict__ asum,
                           float* __restrict__ lattr) {
    int v = blockIdx.x * 256 + threadIdx.x;
    if (v >= NT) return;
    float dg = fmaxf((float)degi[v], 1.f);
    lattr[v * 3]     = asum[v * 3] / dg;
    lattr[v * 3 + 1] = asum[v * 3 + 1] / dg;
    lattr[v * 3 + 2] = asum[v * 3 + 2] / dg;
}

// ---------- exclusive scan of (deg+1) -> CSR offsets ----------
__global__ void k_scan(const int* __restrict__ degi, int* __restrict__ offs,
                       int* __restrict__ cursor) {
    __shared__ int sm[256];
    __shared__ int running;
    int t = threadIdx.x;
    if (t == 0) running = 0;
    __syncthreads();
    for (int base = 0; base < NT; base += 256) {
        int v = base + t;
        int val = (v < NT) ? (degi[v] + 1) : 0;
        sm[t] = val;
        __syncthreads();
        for (int o = 1; o < 256; o <<= 1) {
            int add = (t >= o) ? sm[t - o] : 0;
            __syncthreads();
            sm[t] += add;
            __syncthreads();
        }
        int incl = sm[t];
        int ro = running;
        __syncthreads();
        if (v < NT) { int e0 = ro + incl - val; offs[v] = e0; cursor[v] = e0; }
        if (t == 255) running = ro + incl;
        __syncthreads();
    }
    if (t == 0) offs[NT] = running;
}

// ---------- scatter edges into per-dst CSR buckets ----------
__global__ void k_scatter(const int* __restrict__ ei, int* __restrict__ cursor,
                          int* __restrict__ seid, int* __restrict__ ssrc) {
    int e = blockIdx.x * 256 + threadIdx.x;
    if (e >= ETC) return;
    int src, dst;
    if (e < EE)       { src = ei[e]; dst = ei[EE + e]; }
    else if (e < E1C) { src = NN; dst = e - EE; }
    else if (e < E2C) { src = e - E1C; dst = NN; }
    else              { src = dst = e - E2C; }
    int pos = atomicAdd(&cursor[dst], 1);
    seid[pos] = e;
    ssrc[pos] = src;
}

// ---------- we_dot[l][k][h] = sum_c e_w[l,k,h*64+c] * att_edge[l,h,c] ----------
__global__ void k_wedot(const float* __restrict__ ew, const float* __restrict__ ae,
                        float* __restrict__ wd) {
    int t = threadIdx.x;
    if (t >= 36) return;
    int l = t / 12, k = (t / 4) % 3, h = t % 4;
    float s = 0.f;
    for (int c = 0; c < 64; c++)
        s += ew[l * 768 + k * DD + h * 64 + c] * ae[l * DD + h * 64 + c];
    wd[t] = s;   // layout [l][k][h]
}

// ---------- xs = h @ W (4 rows / block), fused al_s / al_d ----------
__global__ void __launch_bounds__(256) k_gemm4(
        const float* __restrict__ h, const float* __restrict__ w,
        const float* __restrict__ as_, const float* __restrict__ ad_,
        float* __restrict__ xs, float* __restrict__ als, float* __restrict__ ald) {
    int j = threadIdx.x;
    int v0 = blockIdx.x * 4;
    int nrows = NT - v0; if (nrows > 4) nrows = 4;
    const float* h0 = h + (size_t)v0 * DD;
    float acc0 = 0.f, acc1 = 0.f, acc2 = 0.f, acc3 = 0.f;
    for (int k = 0; k < DD; k++) {
        float wk = w[k * DD + j];
        acc0 += h0[k] * wk;
        acc1 += h0[DD + k] * wk;
        acc2 += h0[2 * DD + k] * wk;
        acc3 += h0[3 * DD + k] * wk;
    }
    float asj = as_[j], adj = ad_[j];
    int lane = j & 63, hh = j >> 6;
#pragma unroll
    for (int r = 0; r < 4; r++) {
        float a = (r == 0) ? acc0 : (r == 1) ? acc1 : (r == 2) ? acc2 : acc3;
        if (r < nrows) {
            int v = v0 + r;
            xs[(size_t)v * DD + j] = a;
            float s1 = wave_sum(a * asj);
            float s2 = wave_sum(a * adj);
            if (lane == 0) { als[v * 4 + hh] = s1; ald[v * 4 + hh] = s2; }
        }
    }
}

// ---------- per-edge attention logits (leaky relu applied) ----------
__global__ void k_alpha(const int* __restrict__ ei, const float* __restrict__ ea,
                        const float* __restrict__ lattr,
                        const float* __restrict__ als, const float* __restrict__ ald,
                        const float* __restrict__ wd,   // this layer's 12 floats [k*4+h]
                        float* __restrict__ alpha) {
    int e = blockIdx.x * 256 + threadIdx.x;
    if (e >= ETC) return;
    int src, dst; float a0, a1, a2;
    if (e < EE)       { src = ei[e]; dst = ei[EE + e]; a0 = ea[e * 3]; a1 = ea[e * 3 + 1]; a2 = ea[e * 3 + 2]; }
    else if (e < E1C) { src = NN; dst = e - EE; a0 = 0.5f; a1 = 0.f; a2 = 0.f; }
    else if (e < E2C) { src = e - E1C; dst = NN; a0 = 0.5f; a1 = 0.f; a2 = 0.f; }
    else              { src = dst = e - E2C; a0 = lattr[src * 3]; a1 = lattr[src * 3 + 1]; a2 = lattr[src * 3 + 2]; }
    float4 s4 = *(const float4*)(als + src * 4);
    float4 d4 = *(const float4*)(ald + dst * 4);
    const float* sp = (const float*)&s4;
    const float* dp = (const float*)&d4;
    float4 o;
    float* op = (float*)&o;
#pragma unroll
    for (int hh = 0; hh < 4; hh++) {
        float al = sp[hh] + dp[hh] + a0 * wd[hh] + a1 * wd[4 + hh] + a2 * wd[8 + hh];
        op[hh] = al > 0.f ? al : 0.2f * al;
    }
    *(float4*)(alpha + (size_t)e * 4) = o;
}

// ---------- per-dst softmax + message aggregation (regular nodes) ----------
__global__ void __launch_bounds__(256) k_msg(
        const int* __restrict__ offs, const int* __restrict__ seid,
        const int* __restrict__ ssrc, float* __restrict__ alpha,
        const float* __restrict__ xs, float* __restrict__ outa) {
    int v = blockIdx.x;
    int j = threadIdx.x, lane = j & 63, w = j >> 6;
    if (v == NN) { outa[(size_t)v * DD + j] = 0.f; return; }  // virtual dst handled separately
    __shared__ float smx[4], ssum[4];
    int b0 = offs[v], deg = offs[v + 1] - b0;
    // phase 1: per-head max (wave w == head w)
    float m = -3.4e38f;
    for (int i = lane; i < deg; i += 64) {
        int e = seid[b0 + i];
        m = fmaxf(m, alpha[(size_t)e * 4 + w]);
    }
    m = wave_max(m);
    if (lane == 0) smx[w] = m;
    __syncthreads();
    // phase 2: exp + sum (store exp back in place)
    float mh = smx[w];
    float s = 0.f;
    for (int i = lane; i < deg; i += 64) {
        int e = seid[b0 + i];
        float a = __expf(alpha[(size_t)e * 4 + w] - mh);
        alpha[(size_t)e * 4 + w] = a;
        s += a;
    }
    s = wave_sum(s);
    if (lane == 0) ssum[w] = s;
    __syncthreads();
    // phase 3: weighted accumulate, thread j owns channel j
    int hh = j >> 6;
    float inv = 1.f / (ssum[hh] + 1e-16f);
    float acc = 0.f;
    for (int i = 0; i < deg; i++) {
        int p = b0 + i;
        int e = seid[p], src = ssrc[p];
        acc += alpha[(size_t)e * 4 + hh] * xs[(size_t)src * DD + j];
    }
    outa[(size_t)v * DD + j] = acc * inv;
}

// ---------- virtual-node softmax stats (its edges are 2 known ranges) ----------
__global__ void k_vmaxsum(const float* __restrict__ alpha, float* __restrict__ vstats) {
    __shared__ float smx[4];
    int j = threadIdx.x, lane = j & 63, w = j >> 6;
    float m = -3.4e38f;
    for (int i = lane; i < NN; i += 64) m = fmaxf(m, alpha[(size_t)(E1C + i) * 4 + w]);
    if (lane == 0) m = fmaxf(m, alpha[(size_t)(E2C + NN) * 4 + w]);
    m = wave_max(m);
    if (lane == 0) smx[w] = m;
    __syncthreads();
    float mh = smx[w];
    float s = 0.f;
    for (int i = lane; i < NN; i += 64) s += __expf(alpha[(size_t)(E1C + i) * 4 + w] - mh);
    if (lane == 0) s += __expf(alpha[(size_t)(E2C + NN) * 4 + w] - mh);
    s = wave_sum(s);
    if (lane == 0) { vstats[w] = mh; vstats[4 + w] = s; }
}

// ---------- virtual-node weighted accumulation ----------
__global__ void k_vacc(const float* __restrict__ alpha, const float* __restrict__ xs,
                       const float* __restrict__ vstats, float* __restrict__ outa) {
    int j = threadIdx.x, hh = j >> 6;
    float mh = vstats[hh], inv = 1.f / (vstats[4 + hh] + 1e-16f);
    float acc = 0.f;
    for (int i = blockIdx.x; i < NT; i += gridDim.x) {
        int e, src;
        if (i < NN) { e = E1C + i; src = i; }
        else        { e = E2C + NN; src = NN; }
        acc += __expf(alpha[(size_t)e * 4 + hh] - mh) * xs[(size_t)src * DD + j];
    }
    atomicAdd(&outa[(size_t)NN * DD + j], acc * inv);
}

// ---------- bias + LN + residual relu ----------
__global__ void k_post(const float* __restrict__ outa, const float* __restrict__ bias,
                       const float* __restrict__ g, const float* __restrict__ bt,
                       const float* __restrict__ hin, float* __restrict__ hout,
                       float* __restrict__ jkslot) {
    __shared__ float sm4[4];
    int v = blockIdx.x, j = threadIdx.x;
    float t = outa[(size_t)v * DD + j] + bias[j];
    float m = blk_sum256(t, sm4) * (1.f / DD);
    float d = t - m;
    float var = blk_sum256(d * d, sm4) * (1.f / DD);
    float y = d * rsqrtf(var + 1e-5f) * g[j] + bt[j];
    float r = fmaxf(y + hin[(size_t)v * DD + j], 0.f);
    hout[(size_t)v * DD + j] = r;
    if (v == NN) jkslot[j] = r;
}

// ---------- agent encoder ----------
__global__ void k_agent(const float* __restrict__ af, const float* __restrict__ w,
                        const float* __restrict__ b, const float* __restrict__ g,
                        const float* __restrict__ bt, float* __restrict__ comb) {
    __shared__ float sm4[4];
    __shared__ float xr[10];
    int j = threadIdx.x;
    if (j < 10) xr[j] = af[j];
    __syncthreads();
    float acc = b[j];
#pragma unroll
    for (int k = 0; k < 10; k++) acc += xr[k] * w[k * DD + j];
    float m = blk_sum256(acc, sm4) * (1.f / DD);
    float d = acc - m;
    float var = blk_sum256(d * d, sm4) * (1.f / DD);
    float y = d * rsqrtf(var + 1e-5f) * g[j] + bt[j];
    comb[1024 + j] = fmaxf(y, 0.f);
}

// ---------- dueling head ----------
__global__ void k_head(const float* __restrict__ comb,
                       const float* __restrict__ vw1, const float* __restrict__ vb1,
                       const float* __restrict__ vg, const float* __restrict__ vbt,
                       const float* __restrict__ vw2, const float* __restrict__ vb2,
                       const float* __restrict__ aw1, const float* __restrict__ ab1,
                       const float* __restrict__ ag, const float* __restrict__ abt,
                       const float* __restrict__ aw2, const float* __restrict__ ab2,
                       float* __restrict__ out) {
    __shared__ float sm4[4];
    __shared__ float cb[1280];
    __shared__ float tl[DD];
    __shared__ float adv[9];
    __shared__ float valv;
    int j = threadIdx.x;
    for (int k = j; k < 1280; k += 256) cb[k] = comb[k];
    __syncthreads();
    // value head
    float acc = vb1[j];
    for (int k = 0; k < 1280; k++) acc += cb[k] * vw1[k * DD + j];
    float m = blk_sum256(acc, sm4) * (1.f / DD);
    float d = acc - m;
    float var = blk_sum256(d * d, sm4) * (1.f / DD);
    float y = fmaxf(d * rsqrtf(var + 1e-5f) * vg[j] + vbt[j], 0.f);
    float vs = blk_sum256(y * vw2[j], sm4);
    if (j == 0) valv = vs + vb2[0];
    // advantage head
    float acc2 = ab1[j];
    for (int k = 0; k < 1280; k++) acc2 += cb[k] * aw1[k * DD + j];
    float m2 = blk_sum256(acc2, sm4) * (1.f / DD);
    float d2 = acc2 - m2;
    float var2 = blk_sum256(d2 * d2, sm4) * (1.f / DD);
    float y2 = fmaxf(d2 * rsqrtf(var2 + 1e-5f) * ag[j] + abt[j], 0.f);
    tl[j] = y2;
    __syncthreads();
    if (j < 9) {
        float s = ab2[j];
        for (int k = 0; k < DD; k++) s += tl[k] * aw2[k * 9 + j];
        adv[j] = s;
    }
    __syncthreads();
    if (j < 9) {
        float mean = 0.f;
        for (int o = 0; o < 9; o++) mean += adv[o];
        mean *= (1.f / 9.f);
        out[j] = valv + adv[j] - mean;
    }
}

extern "C" void kernel_launch(void* const* d_in, const int* in_sizes, int n_in,
                              void* d_out, int out_size, void* d_ws, size_t ws_size,
                              hipStream_t stream) {
    (void)in_sizes; (void)n_in; (void)out_size; (void)ws_size;
    const float* x      = (const float*)d_in[0];
    const int*   ei     = (const int*)d_in[1];
    const float* ea     = (const float*)d_in[2];
    const float* af     = (const float*)d_in[3];
    const float* enc_w  = (const float*)d_in[4];
    const float* enc_b  = (const float*)d_in[5];
    const float* enc_g  = (const float*)d_in[6];
    const float* enc_bt = (const float*)d_in[7];
    const float* vn_base= (const float*)d_in[8];
    const float* vn_w1  = (const float*)d_in[9];
    const float* vn_b1  = (const float*)d_in[10];
    const float* vn_g   = (const float*)d_in[11];
    const float* vn_bt  = (const float*)d_in[12];
    const float* vn_w2  = (const float*)d_in[13];
    const float* vn_b2  = (const float*)d_in[14];
    const float* gat_w  = (const float*)d_in[15];
    const float* att_src= (const float*)d_in[16];
    const float* att_dst= (const float*)d_in[17];
    const float* att_edge=(const float*)d_in[18];
    const float* edge_w = (const float*)d_in[19];
    const float* gat_b  = (const float*)d_in[20];
    const float* ln_g   = (const float*)d_in[21];
    const float* ln_b   = (const float*)d_in[22];
    const float* ag_w   = (const float*)d_in[23];
    const float* ag_b   = (const float*)d_in[24];
    const float* ag_g   = (const float*)d_in[25];
    const float* ag_bt  = (const float*)d_in[26];
    const float* v_w1   = (const float*)d_in[27];
    const float* v_b1   = (const float*)d_in[28];
    const float* v_g    = (const float*)d_in[29];
    const float* v_bt   = (const float*)d_in[30];
    const float* v_w2   = (const float*)d_in[31];
    const float* v_b2   = (const float*)d_in[32];
    const float* a_w1   = (const float*)d_in[33];
    const float* a_b1   = (const float*)d_in[34];
    const float* a_g    = (const float*)d_in[35];
    const float* a_bt   = (const float*)d_in[36];
    const float* a_w2   = (const float*)d_in[37];
    const float* a_b2   = (const float*)d_in[38];

    char* p = (char*)d_ws;
    auto alloc = [&](size_t bytes) {
        char* r = p;
        p += (bytes + 255) & ~(size_t)255;
        return r;
    };
    // three big row buffers, rotated: cur h | xs | out-accum (post writes h_next in place over outa)
    float* big0  = (float*)alloc((size_t)NT * DD * 4);
    float* xs    = (float*)alloc((size_t)NT * DD * 4);
    float* big2  = (float*)alloc((size_t)NT * DD * 4);
    float* alpha = (float*)alloc((size_t)ETC * 4 * 4);
    float* als   = (float*)alloc((size_t)NT * 4 * 4);
    float* ald   = (float*)alloc((size_t)NT * 4 * 4);
    float* ctx   = (float*)alloc(DD * 4);
    float* comb  = (float*)alloc(1280 * 4);
    float* asum  = (float*)alloc((size_t)NT * 3 * 4);
    float* lattr = (float*)alloc((size_t)NT * 3 * 4);
    float* wd    = (float*)alloc(36 * 4);
    float* vstats= (float*)alloc(8 * 4);
    int* degi    = (int*)alloc((size_t)NT * 4);
    int* offs    = (int*)alloc((size_t)(NT + 1) * 4);
    int* cursor  = (int*)alloc((size_t)NT * 4);
    int* seid    = (int*)alloc((size_t)ETC * 4);
    int* ssrc    = (int*)alloc((size_t)ETC * 4);

    hipMemsetAsync(ctx, 0, DD * 4, stream);
    hipMemsetAsync(degi, 0, (size_t)NT * 4, stream);
    hipMemsetAsync(asum, 0, (size_t)NT * 3 * 4, stream);

    k_enc<<<NN, 256, 0, stream>>>(x, enc_w, enc_b, enc_g, enc_bt, big0);
    k_ctx<<<64, 256, 0, stream>>>(big0, ctx);
    k_vn<<<1, 256, 0, stream>>>(ctx, vn_w1, vn_b1, vn_g, vn_bt, vn_w2, vn_b2, vn_base, big0, comb);
    k_deg<<<(E2C + 255) / 256, 256, 0, stream>>>(ei, ea, degi, asum);
    k_loopattr<<<(NT + 255) / 256, 256, 0, stream>>>(degi, asum, lattr);
    k_scan<<<1, 256, 0, stream>>>(degi, offs, cursor);
    k_scatter<<<(ETC + 255) / 256, 256, 0, stream>>>(ei, cursor, seid, ssrc);
    k_wedot<<<1, 64, 0, stream>>>(edge_w, att_edge, wd);

    float* cur = big0;
    float* po  = big2;
    for (int l = 0; l < 3; l++) {
        k_gemm4<<<(NT + 3) / 4, 256, 0, stream>>>(cur, gat_w + (size_t)l * DD * DD,
                                                  att_src + l * DD, att_dst + l * DD,
                                                  xs, als, ald);
        k_alpha<<<(ETC + 255) / 256, 256, 0, stream>>>(ei, ea, lattr, als, ald, wd + l * 12, alpha);
        k_msg<<<NT, 256, 0, stream>>>(offs, seid, ssrc, alpha, xs, po);
        k_vmaxsum<<<1, 256, 0, stream>>>(alpha, vstats);
        k_vacc<<<64, 256, 0, stream>>>(alpha, xs, vstats, po);
        k_post<<<NT, 256, 0, stream>>>(po, gat_b + l * DD, ln_g + l * DD, ln_b + l * DD,
                                       cur, po, comb + (l + 1) * DD);
        float* t = cur; cur = po; po = t;
    }
    k_agent<<<1, 256, 0, stream>>>(af, ag_w, ag_b, ag_g, ag_bt, comb);
    k_head<<<1, 256, 0, stream>>>(comb, v_w1, v_b1, v_g, v_bt, v_w2, v_b2,
                                  a_w1, a_b1, a_g, a_bt, a_w2, a_b2, (float*)d_out);
}

// Round 2
// 814.912 us; speedup vs baseline: 1.4995x; 1.4995x over previous
//
#include <hip/hip_runtime.h>
#include <math.h>

#define NN 10000
#define EE 320000
#define DD 256
#define NT 10001            // NN + virtual node
#define E1C (EE + NN)       // 330000
#define E2C (EE + 2 * NN)   // 340000
#define ETC (E2C + NT)      // 350001 (with self loops)

// ---------- reduction helpers (blockDim.x == 256 assumed) ----------
__device__ __forceinline__ float wave_sum(float v) {
#pragma unroll
    for (int o = 32; o > 0; o >>= 1) v += __shfl_down(v, o, 64);
    return v;
}
__device__ __forceinline__ float blk_sum256(float v, float* sm4) {
    v = wave_sum(v);
    int lane = threadIdx.x & 63, w = threadIdx.x >> 6;
    __syncthreads();
    if (lane == 0) sm4[w] = v;
    __syncthreads();
    return sm4[0] + sm4[1] + sm4[2] + sm4[3];
}

// ---------- node encoder: h0 = relu(LN(x @ enc_w + enc_b)) ----------
__global__ void k_enc(const float* __restrict__ x, const float* __restrict__ w,
                      const float* __restrict__ b, const float* __restrict__ g,
                      const float* __restrict__ bt, float* __restrict__ h) {
    __shared__ float sm4[4];
    __shared__ float xr[10];
    int v = blockIdx.x, j = threadIdx.x;
    if (j < 10) xr[j] = x[v * 10 + j];
    __syncthreads();
    float acc = b[j];
#pragma unroll
    for (int k = 0; k < 10; k++) acc += xr[k] * w[k * DD + j];
    float m = blk_sum256(acc, sm4) * (1.f / DD);
    float d = acc - m;
    float var = blk_sum256(d * d, sm4) * (1.f / DD);
    float y = d * rsqrtf(var + 1e-5f) * g[j] + bt[j];
    h[v * DD + j] = fmaxf(y, 0.f);
}

// ---------- column sums of h0 for ctx ----------
__global__ void k_ctx(const float* __restrict__ h, float* __restrict__ ctx) {
    int c = threadIdx.x;
    float acc = 0.f;
    for (int v = blockIdx.x; v < NN; v += gridDim.x) acc += h[v * DD + c];
    atomicAdd(&ctx[c], acc);
}

// ---------- adaptive virtual node ----------
__global__ void k_vn(const float* __restrict__ ctx,
                     const float* __restrict__ w1, const float* __restrict__ b1,
                     const float* __restrict__ g, const float* __restrict__ bt,
                     const float* __restrict__ w2, const float* __restrict__ b2,
                     const float* __restrict__ vnb,
                     float* __restrict__ h, float* __restrict__ comb) {
    __shared__ float sm4[4];
    __shared__ float cs[DD];
    __shared__ float t[DD];
    int j = threadIdx.x;
    cs[j] = ctx[j] * (1.f / NN);
    __syncthreads();
    float acc = b1[j];
    for (int k = 0; k < DD; k++) acc += cs[k] * w1[k * DD + j];
    float m = blk_sum256(acc, sm4) * (1.f / DD);
    float d = acc - m;
    float var = blk_sum256(d * d, sm4) * (1.f / DD);
    float y = fmaxf(d * rsqrtf(var + 1e-5f) * g[j] + bt[j], 0.f);
    t[j] = y;
    __syncthreads();
    float a2 = b2[j];
    for (int k = 0; k < DD; k++) a2 += t[k] * w2[k * DD + j];
    float vn = vnb[j] + tanhf(a2);
    h[NN * DD + j] = vn;
    comb[j] = vn;   // jk slot 0 (virtual row of initial h)
}

// ---------- regular-edge in-degree histogram (1 atomic per edge) ----------
__global__ void k_deg(const int* __restrict__ ei, int* __restrict__ degi) {
    int e = blockIdx.x * 256 + threadIdx.x;
    if (e >= EE) return;
    atomicAdd(&degi[ei[EE + e]], 1);
}

// ---------- shfl-based exclusive scan of (degR + virtual/self additions) ----------
__global__ void k_scan(const int* __restrict__ degi, int* __restrict__ offs,
                       int* __restrict__ cursor) {
    __shared__ int wsum[4];
    __shared__ int running_s;
    int t = threadIdx.x, lane = t & 63, w = t >> 6;
    if (t == 0) running_s = 0;
    __syncthreads();
    for (int base = 0; base < NT; base += 256) {
        int v = base + t;
        int val = 0;
        if (v < NN) val = degi[v] + 2;          // + vn-edge + self-loop
        else if (v == NN) val = NN + 1;         // virtual: NN in-edges + self-loop
        int x = val;
#pragma unroll
        for (int o = 1; o < 64; o <<= 1) {
            int y = __shfl_up(x, o, 64);
            if (lane >= o) x += y;
        }
        if (lane == 63) wsum[w] = x;
        __syncthreads();
        int prefix = running_s;
        for (int ww = 0; ww < w; ww++) prefix += wsum[ww];
        if (v <= NN) { int e0 = prefix + x - val; offs[v] = e0; cursor[v] = e0; }
        __syncthreads();
        if (t == 0) running_s += wsum[0] + wsum[1] + wsum[2] + wsum[3];
        __syncthreads();
    }
    if (threadIdx.x == 0) offs[NT] = running_s;
}

// ---------- scatter regular edges into CSR (packed {src, eid}) ----------
__global__ void k_scatter(const int* __restrict__ ei, int* __restrict__ cursor,
                          int2* __restrict__ sp) {
    int e = blockIdx.x * 256 + threadIdx.x;
    if (e >= EE) return;
    int src = ei[e], dst = ei[EE + e];
    int pos = atomicAdd(&cursor[dst], 1);
    sp[pos] = make_int2(src, e);
}

// ---------- fill deterministic CSR slots: vn edges + self loops ----------
__global__ void k_fill(const int* __restrict__ offs, int2* __restrict__ sp) {
    int v = blockIdx.x * 256 + threadIdx.x;
    if (v > NN) return;
    int bN = offs[NN];
    if (v < NN) {
        int e1 = offs[v + 1];
        sp[e1 - 2] = make_int2(NN, EE + v);      // vn -> v
        sp[e1 - 1] = make_int2(v, E2C + v);      // self loop
        sp[bN + v] = make_int2(v, E1C + v);      // v -> vn (virtual segment)
    } else {
        sp[bN + NN] = make_int2(NN, E2C + NN);   // virtual self loop
    }
}

// ---------- loop_attr via segmented sums over CSR (no atomics) ----------
__global__ void k_lattr(const int* __restrict__ offs, const int2* __restrict__ sp,
                        const float* __restrict__ ea, float* __restrict__ lattr) {
    int t = threadIdx.x, lane = t & 63, w = t >> 6;
    int v = blockIdx.x * 4 + w;
    if (v > NN) return;
    if (v == NN) {
        if (lane == 0) { lattr[v * 3] = 0.5f; lattr[v * 3 + 1] = 0.f; lattr[v * 3 + 2] = 0.f; }
        return;
    }
    int b0 = offs[v];
    int cnt = offs[v + 1] - b0 - 2;      // regular in-edges
    float s0 = 0.f, s1 = 0.f, s2 = 0.f;
    for (int i = lane; i < cnt; i += 64) {
        int e = sp[b0 + i].y;
        s0 += ea[e * 3];
        s1 += ea[e * 3 + 1];
        s2 += ea[e * 3 + 2];
    }
    s0 = wave_sum(s0); s1 = wave_sum(s1); s2 = wave_sum(s2);
    if (lane == 0) {
        float inv = 1.f / (float)(cnt + 1);  // deg0 = regular + vn edge
        lattr[v * 3]     = (s0 + 0.5f) * inv;
        lattr[v * 3 + 1] = s1 * inv;
        lattr[v * 3 + 2] = s2 * inv;
    }
}

// ---------- we_dot[l][k][h] = sum_c e_w[l,k,h*64+c] * att_edge[l,h,c] ----------
__global__ void k_wedot(const float* __restrict__ ew, const float* __restrict__ ae,
                        float* __restrict__ wd) {
    int t = threadIdx.x;
    if (t >= 36) return;
    int l = t / 12, k = (t / 4) % 3, h = t % 4;
    float s = 0.f;
    for (int c = 0; c < 64; c++)
        s += ew[l * 768 + k * DD + h * 64 + c] * ae[l * DD + h * 64 + c];
    wd[t] = s;   // layout [l][k][h]
}

// ---------- xs = h @ W (16 rows / block), fused al_s / al_d ----------
__global__ void __launch_bounds__(256) k_gemm16(
        const float* __restrict__ h, const float* __restrict__ w,
        const float* __restrict__ as_, const float* __restrict__ ad_,
        float* __restrict__ xs, float* __restrict__ als, float* __restrict__ ald) {
    int j = threadIdx.x;
    int v0 = blockIdx.x * 16;
    int nrows = NT - v0; if (nrows > 16) nrows = 16;
    const float* h0 = h + (size_t)v0 * DD;
    float acc[16];
#pragma unroll
    for (int r = 0; r < 16; r++) acc[r] = 0.f;
    if (nrows == 16) {
#pragma unroll 4
        for (int k = 0; k < DD; k++) {
            float wk = w[k * DD + j];
#pragma unroll
            for (int r = 0; r < 16; r++) acc[r] += h0[r * DD + k] * wk;
        }
    } else {
        for (int k = 0; k < DD; k++) {
            float wk = w[k * DD + j];
#pragma unroll
            for (int r = 0; r < 16; r++) if (r < nrows) acc[r] += h0[r * DD + k] * wk;
        }
    }
    float asj = as_[j], adj = ad_[j];
    int lane = j & 63, hh = j >> 6;
#pragma unroll
    for (int r = 0; r < 16; r++) {
        if (r < nrows) {
            int v = v0 + r;
            xs[(size_t)v * DD + j] = acc[r];
            float s1 = wave_sum(acc[r] * asj);
            float s2 = wave_sum(acc[r] * adj);
            if (lane == 0) { als[v * 4 + hh] = s1; ald[v * 4 + hh] = s2; }
        }
    }
}

// ---------- per-edge PARTIAL logits in CSR order: als[src] + edge term ----------
__global__ void k_alpha(const int2* __restrict__ sp, const float* __restrict__ ea,
                        const float* __restrict__ lattr, const float* __restrict__ als,
                        const float* __restrict__ wd,   // this layer's 12 floats [k*4+h]
                        float* __restrict__ alpha) {
    int p = blockIdx.x * 256 + threadIdx.x;
    if (p >= ETC) return;
    int2 se = sp[p];
    int src = se.x, e = se.y;
    float a0, a1, a2;
    if (e < EE)       { a0 = ea[e * 3]; a1 = ea[e * 3 + 1]; a2 = ea[e * 3 + 2]; }
    else if (e < E2C) { a0 = 0.5f; a1 = 0.f; a2 = 0.f; }
    else              { int v = e - E2C; a0 = lattr[v * 3]; a1 = lattr[v * 3 + 1]; a2 = lattr[v * 3 + 2]; }
    float4 s4 = *(const float4*)(als + src * 4);
    const float* sp4 = (const float*)&s4;
    float4 o;
    float* op = (float*)&o;
#pragma unroll
    for (int hh = 0; hh < 4; hh++)
        op[hh] = sp4[hh] + a0 * wd[hh] + a1 * wd[4 + hh] + a2 * wd[8 + hh];
    *(float4*)(alpha + (size_t)p * 4) = o;   // NO leaky, NO ald (added in consumer)
}

// ---------- per-dst online softmax + 4-wave-parallel aggregation ----------
__global__ void __launch_bounds__(256) k_msg(
        const int* __restrict__ offs, const int2* __restrict__ sp,
        const float* __restrict__ alpha, const float* __restrict__ ald,
        const float* __restrict__ xs, float* __restrict__ outa) {
    int v = blockIdx.x;
    int t = threadIdx.x, lane = t & 63, w = t >> 6;
    if (v == NN) { outa[(size_t)NN * DD + t] = 0.f; return; }  // virtual handled separately
    __shared__ float am[4][4], asv[4][4];
    __shared__ float red[4][256];
    __shared__ float fin[8];        // m[4], inv[4]
    int b0 = offs[v], deg = offs[v + 1] - b0;
    float4 ad4 = *(const float4*)(ald + v * 4);
    const float* adp = (const float*)&ad4;
    // phase A: online (max,sum) per head, lanes strided over segment (coalesced f4)
    float m0 = -3.4e38f, m1 = -3.4e38f, m2 = -3.4e38f, m3 = -3.4e38f;
    float s0 = 0.f, s1 = 0.f, s2 = 0.f, s3 = 0.f;
    for (int i = t; i < deg; i += 256) {
        float4 a4 = *(const float4*)(alpha + (size_t)(b0 + i) * 4);
        float f0 = a4.x + adp[0]; f0 = f0 > 0.f ? f0 : 0.2f * f0;
        float f1 = a4.y + adp[1]; f1 = f1 > 0.f ? f1 : 0.2f * f1;
        float f2 = a4.z + adp[2]; f2 = f2 > 0.f ? f2 : 0.2f * f2;
        float f3 = a4.w + adp[3]; f3 = f3 > 0.f ? f3 : 0.2f * f3;
        if (f0 > m0) { s0 = s0 * __expf(m0 - f0) + 1.f; m0 = f0; } else s0 += __expf(f0 - m0);
        if (f1 > m1) { s1 = s1 * __expf(m1 - f1) + 1.f; m1 = f1; } else s1 += __expf(f1 - m1);
        if (f2 > m2) { s2 = s2 * __expf(m2 - f2) + 1.f; m2 = f2; } else s2 += __expf(f2 - m2);
        if (f3 > m3) { s3 = s3 * __expf(m3 - f3) + 1.f; m3 = f3; } else s3 += __expf(f3 - m3);
    }
#pragma unroll
    for (int o = 1; o < 64; o <<= 1) {
        float mo, so, M;
        mo = __shfl_xor(m0, o, 64); so = __shfl_xor(s0, o, 64);
        M = fmaxf(m0, mo); s0 = s0 * __expf(m0 - M) + so * __expf(mo - M); m0 = M;
        mo = __shfl_xor(m1, o, 64); so = __shfl_xor(s1, o, 64);
        M = fmaxf(m1, mo); s1 = s1 * __expf(m1 - M) + so * __expf(mo - M); m1 = M;
        mo = __shfl_xor(m2, o, 64); so = __shfl_xor(s2, o, 64);
        M = fmaxf(m2, mo); s2 = s2 * __expf(m2 - M) + so * __expf(mo - M); m2 = M;
        mo = __shfl_xor(m3, o, 64); so = __shfl_xor(s3, o, 64);
        M = fmaxf(m3, mo); s3 = s3 * __expf(m3 - M) + so * __expf(mo - M); m3 = M;
    }
    if (lane == 0) {
        am[w][0] = m0; am[w][1] = m1; am[w][2] = m2; am[w][3] = m3;
        asv[w][0] = s0; asv[w][1] = s1; asv[w][2] = s2; asv[w][3] = s3;
    }
    __syncthreads();
    if (t < 4) {   // per head: combine 4 waves
        float M = fmaxf(fmaxf(am[0][t], am[1][t]), fmaxf(am[2][t], am[3][t]));
        float S = asv[0][t] * __expf(am[0][t] - M) + asv[1][t] * __expf(am[1][t] - M)
                + asv[2][t] * __expf(am[2][t] - M) + asv[3][t] * __expf(am[3][t] - M);
        fin[t] = M;
        fin[4 + t] = 1.f / (S + 1e-16f);
    }
    __syncthreads();
    // phase 3: wave w takes edges i = w, w+4, ...; lane covers channels 4*lane..+3
    int hh = lane >> 4;
    float mh = fin[hh], inv = fin[4 + hh], adh = adp[hh];
    float4 acc = make_float4(0.f, 0.f, 0.f, 0.f);
    for (int i = w; i < deg; i += 4) {
        int p = b0 + i;
        float a = alpha[(size_t)p * 4 + hh] + adh;
        a = a > 0.f ? a : 0.2f * a;
        float wt = __expf(a - mh) * inv;
        int src = sp[p].x;
        float4 x4 = *(const float4*)(xs + (size_t)src * DD + lane * 4);
        acc.x += wt * x4.x; acc.y += wt * x4.y; acc.z += wt * x4.z; acc.w += wt * x4.w;
    }
    *(float4*)(&red[w][lane * 4]) = acc;
    __syncthreads();
    outa[(size_t)v * DD + t] = red[0][t] + red[1][t] + red[2][t] + red[3][t];
}

// ---------- virtual-node softmax stats over its (contiguous) CSR segment ----------
__global__ void k_vstat(const int* __restrict__ offs, const float* __restrict__ alpha,
                        const float* __restrict__ ald, float* __restrict__ vstats) {
    __shared__ float am[16][4], asv[16][4];
    int t = threadIdx.x, lane = t & 63, w = t >> 6;
    int b0 = offs[NN], deg = NN + 1;
    float4 ad4 = *(const float4*)(ald + NN * 4);
    const float* adp = (const float*)&ad4;
    float m0 = -3.4e38f, m1 = -3.4e38f, m2 = -3.4e38f, m3 = -3.4e38f;
    float s0 = 0.f, s1 = 0.f, s2 = 0.f, s3 = 0.f;
    for (int i = t; i < deg; i += 1024) {
        float4 a4 = *(const float4*)(alpha + (size_t)(b0 + i) * 4);
        float f0 = a4.x + adp[0]; f0 = f0 > 0.f ? f0 : 0.2f * f0;
        float f1 = a4.y + adp[1]; f1 = f1 > 0.f ? f1 : 0.2f * f1;
        float f2 = a4.z + adp[2]; f2 = f2 > 0.f ? f2 : 0.2f * f2;
        float f3 = a4.w + adp[3]; f3 = f3 > 0.f ? f3 : 0.2f * f3;
        if (f0 > m0) { s0 = s0 * __expf(m0 - f0) + 1.f; m0 = f0; } else s0 += __expf(f0 - m0);
        if (f1 > m1) { s1 = s1 * __expf(m1 - f1) + 1.f; m1 = f1; } else s1 += __expf(f1 - m1);
        if (f2 > m2) { s2 = s2 * __expf(m2 - f2) + 1.f; m2 = f2; } else s2 += __expf(f2 - m2);
        if (f3 > m3) { s3 = s3 * __expf(m3 - f3) + 1.f; m3 = f3; } else s3 += __expf(f3 - m3);
    }
#pragma unroll
    for (int o = 1; o < 64; o <<= 1) {
        float mo, so, M;
        mo = __shfl_xor(m0, o, 64); so = __shfl_xor(s0, o, 64);
        M = fmaxf(m0, mo); s0 = s0 * __expf(m0 - M) + so * __expf(mo - M); m0 = M;
        mo = __shfl_xor(m1, o, 64); so = __shfl_xor(s1, o, 64);
        M = fmaxf(m1, mo); s1 = s1 * __expf(m1 - M) + so * __expf(mo - M); m1 = M;
        mo = __shfl_xor(m2, o, 64); so = __shfl_xor(s2, o, 64);
        M = fmaxf(m2, mo); s2 = s2 * __expf(m2 - M) + so * __expf(mo - M); m2 = M;
        mo = __shfl_xor(m3, o, 64); so = __shfl_xor(s3, o, 64);
        M = fmaxf(m3, mo); s3 = s3 * __expf(m3 - M) + so * __expf(mo - M); m3 = M;
    }
    if (lane == 0) {
        am[w][0] = m0; am[w][1] = m1; am[w][2] = m2; am[w][3] = m3;
        asv[w][0] = s0; asv[w][1] = s1; asv[w][2] = s2; asv[w][3] = s3;
    }
    __syncthreads();
    if (t < 4) {
        float M = -3.4e38f;
        for (int ww = 0; ww < 16; ww++) M = fmaxf(M, am[ww][t]);
        float S = 0.f;
        for (int ww = 0; ww < 16; ww++) S += asv[ww][t] * __expf(am[ww][t] - M);
        vstats[t] = M;
        vstats[4 + t] = 1.f / (S + 1e-16f);
    }
}

// ---------- virtual-node weighted accumulation (sequential src rows) ----------
__global__ void k_vacc(const int* __restrict__ offs, const float* __restrict__ alpha,
                       const float* __restrict__ ald, const float* __restrict__ xs,
                       const float* __restrict__ vstats, float* __restrict__ outa) {
    int j = threadIdx.x, hh = j >> 6;
    int b0 = offs[NN];
    float mh = vstats[hh], inv = vstats[4 + hh];
    float adh = ald[NN * 4 + hh];
    float acc = 0.f;
    for (int i = blockIdx.x; i < NN + 1; i += gridDim.x) {
        float a = alpha[(size_t)(b0 + i) * 4 + hh] + adh;
        a = a > 0.f ? a : 0.2f * a;
        float wt = __expf(a - mh) * inv;
        int src = (i < NN) ? i : NN;
        acc += wt * xs[(size_t)src * DD + j];
    }
    atomicAdd(&outa[(size_t)NN * DD + j], acc);
}

// ---------- bias + LN + residual relu ----------
__global__ void k_post(const float* __restrict__ outa, const float* __restrict__ bias,
                       const float* __restrict__ g, const float* __restrict__ bt,
                       const float* __restrict__ hin, float* __restrict__ hout,
                       float* __restrict__ jkslot) {
    __shared__ float sm4[4];
    int v = blockIdx.x, j = threadIdx.x;
    float t = outa[(size_t)v * DD + j] + bias[j];
    float m = blk_sum256(t, sm4) * (1.f / DD);
    float d = t - m;
    float var = blk_sum256(d * d, sm4) * (1.f / DD);
    float y = d * rsqrtf(var + 1e-5f) * g[j] + bt[j];
    float r = fmaxf(y + hin[(size_t)v * DD + j], 0.f);
    hout[(size_t)v * DD + j] = r;
    if (v == NN) jkslot[j] = r;
}

// ---------- agent encoder ----------
__global__ void k_agent(const float* __restrict__ af, const float* __restrict__ w,
                        const float* __restrict__ b, const float* __restrict__ g,
                        const float* __restrict__ bt, float* __restrict__ comb) {
    __shared__ float sm4[4];
    __shared__ float xr[10];
    int j = threadIdx.x;
    if (j < 10) xr[j] = af[j];
    __syncthreads();
    float acc = b[j];
#pragma unroll
    for (int k = 0; k < 10; k++) acc += xr[k] * w[k * DD + j];
    float m = blk_sum256(acc, sm4) * (1.f / DD);
    float d = acc - m;
    float var = blk_sum256(d * d, sm4) * (1.f / DD);
    float y = d * rsqrtf(var + 1e-5f) * g[j] + bt[j];
    comb[1024 + j] = fmaxf(y, 0.f);
}

// ---------- dueling head, stage 1: 40-way k-sliced partial GEMMs ----------
__global__ void k_head1(const float* __restrict__ comb,
                        const float* __restrict__ vw1, const float* __restrict__ aw1,
                        float* __restrict__ pv, float* __restrict__ pa) {
    int j = threadIdx.x, s = blockIdx.x;
    int k0 = s * 32;
    float accv = 0.f, acca = 0.f;
#pragma unroll
    for (int kk = 0; kk < 32; kk++) {
        float c = comb[k0 + kk];
        accv += c * vw1[(k0 + kk) * DD + j];
        acca += c * aw1[(k0 + kk) * DD + j];
    }
    pv[s * DD + j] = accv;
    pa[s * DD + j] = acca;
}

// ---------- dueling head, stage 2: combine + LN + second layers ----------
__global__ void k_head2(const float* __restrict__ pv, const float* __restrict__ pa,
                        const float* __restrict__ vb1, const float* __restrict__ vg,
                        const float* __restrict__ vbt, const float* __restrict__ vw2,
                        const float* __restrict__ vb2,
                        const float* __restrict__ ab1, const float* __restrict__ ag,
                        const float* __restrict__ abt, const float* __restrict__ aw2,
                        const float* __restrict__ ab2, float* __restrict__ out) {
    __shared__ float sm4[4];
    __shared__ float tl[DD];
    __shared__ float adv[9];
    __shared__ float valv;
    int j = threadIdx.x;
    float acc = vb1[j], acc2 = ab1[j];
    for (int s = 0; s < 40; s++) { acc += pv[s * DD + j]; acc2 += pa[s * DD + j]; }
    // value head
    float m = blk_sum256(acc, sm4) * (1.f / DD);
    float d = acc - m;
    float var = blk_sum256(d * d, sm4) * (1.f / DD);
    float y = fmaxf(d * rsqrtf(var + 1e-5f) * vg[j] + vbt[j], 0.f);
    float vs = blk_sum256(y * vw2[j], sm4);
    if (j == 0) valv = vs + vb2[0];
    // advantage head
    float m2 = blk_sum256(acc2, sm4) * (1.f / DD);
    float d2 = acc2 - m2;
    float var2 = blk_sum256(d2 * d2, sm4) * (1.f / DD);
    float y2 = fmaxf(d2 * rsqrtf(var2 + 1e-5f) * ag[j] + abt[j], 0.f);
    tl[j] = y2;
    __syncthreads();
    if (j < 9) {
        float s = ab2[j];
        for (int k = 0; k < DD; k++) s += tl[k] * aw2[k * 9 + j];
        adv[j] = s;
    }
    __syncthreads();
    if (j < 9) {
        float mean = 0.f;
        for (int o = 0; o < 9; o++) mean += adv[o];
        mean *= (1.f / 9.f);
        out[j] = valv + adv[j] - mean;
    }
}

extern "C" void kernel_launch(void* const* d_in, const int* in_sizes, int n_in,
                              void* d_out, int out_size, void* d_ws, size_t ws_size,
                              hipStream_t stream) {
    (void)in_sizes; (void)n_in; (void)out_size; (void)ws_size;
    const float* x      = (const float*)d_in[0];
    const int*   ei     = (const int*)d_in[1];
    const float* ea     = (const float*)d_in[2];
    const float* af     = (const float*)d_in[3];
    const float* enc_w  = (const float*)d_in[4];
    const float* enc_b  = (const float*)d_in[5];
    const float* enc_g  = (const float*)d_in[6];
    const float* enc_bt = (const float*)d_in[7];
    const float* vn_base= (const float*)d_in[8];
    const float* vn_w1  = (const float*)d_in[9];
    const float* vn_b1  = (const float*)d_in[10];
    const float* vn_g   = (const float*)d_in[11];
    const float* vn_bt  = (const float*)d_in[12];
    const float* vn_w2  = (const float*)d_in[13];
    const float* vn_b2  = (const float*)d_in[14];
    const float* gat_w  = (const float*)d_in[15];
    const float* att_src= (const float*)d_in[16];
    const float* att_dst= (const float*)d_in[17];
    const float* att_edge=(const float*)d_in[18];
    const float* edge_w = (const float*)d_in[19];
    const float* gat_b  = (const float*)d_in[20];
    const float* ln_g   = (const float*)d_in[21];
    const float* ln_b   = (const float*)d_in[22];
    const float* ag_w   = (const float*)d_in[23];
    const float* ag_b   = (const float*)d_in[24];
    const float* ag_g   = (const float*)d_in[25];
    const float* ag_bt  = (const float*)d_in[26];
    const float* v_w1   = (const float*)d_in[27];
    const float* v_b1   = (const float*)d_in[28];
    const float* v_g    = (const float*)d_in[29];
    const float* v_bt   = (const float*)d_in[30];
    const float* v_w2   = (const float*)d_in[31];
    const float* v_b2   = (const float*)d_in[32];
    const float* a_w1   = (const float*)d_in[33];
    const float* a_b1   = (const float*)d_in[34];
    const float* a_g    = (const float*)d_in[35];
    const float* a_bt   = (const float*)d_in[36];
    const float* a_w2   = (const float*)d_in[37];
    const float* a_b2   = (const float*)d_in[38];

    char* p = (char*)d_ws;
    auto alloc = [&](size_t bytes) {
        char* r = p;
        p += (bytes + 255) & ~(size_t)255;
        return r;
    };
    float* big0  = (float*)alloc((size_t)NT * DD * 4);
    float* xs    = (float*)alloc((size_t)NT * DD * 4);
    float* big2  = (float*)alloc((size_t)NT * DD * 4);
    float* alpha = (float*)alloc((size_t)ETC * 4 * 4);
    int2*  sp    = (int2*) alloc((size_t)ETC * 8);
    float* als   = (float*)alloc((size_t)NT * 4 * 4);
    float* ald   = (float*)alloc((size_t)NT * 4 * 4);
    float* ctx   = (float*)alloc(DD * 4);
    float* comb  = (float*)alloc(1280 * 4);
    float* lattr = (float*)alloc((size_t)NT * 3 * 4);
    float* wd    = (float*)alloc(36 * 4);
    float* vstats= (float*)alloc(8 * 4);
    float* pv    = (float*)alloc(40 * DD * 4);
    float* pa    = (float*)alloc(40 * DD * 4);
    int* degi    = (int*)alloc((size_t)NT * 4);
    int* offs    = (int*)alloc((size_t)(NT + 1) * 4);
    int* cursor  = (int*)alloc((size_t)NT * 4);

    hipMemsetAsync(ctx, 0, DD * 4, stream);
    hipMemsetAsync(degi, 0, (size_t)NT * 4, stream);

    k_enc<<<NN, 256, 0, stream>>>(x, enc_w, enc_b, enc_g, enc_bt, big0);
    k_ctx<<<64, 256, 0, stream>>>(big0, ctx);
    k_vn<<<1, 256, 0, stream>>>(ctx, vn_w1, vn_b1, vn_g, vn_bt, vn_w2, vn_b2, vn_base, big0, comb);
    k_deg<<<(EE + 255) / 256, 256, 0, stream>>>(ei, degi);
    k_scan<<<1, 256, 0, stream>>>(degi, offs, cursor);
    k_scatter<<<(EE + 255) / 256, 256, 0, stream>>>(ei, cursor, sp);
    k_fill<<<(NT + 255) / 256, 256, 0, stream>>>(offs, sp);
    k_lattr<<<(NT + 3) / 4, 256, 0, stream>>>(offs, sp, ea, lattr);
    k_wedot<<<1, 64, 0, stream>>>(edge_w, att_edge, wd);

    float* cur = big0;
    float* po  = big2;
    for (int l = 0; l < 3; l++) {
        k_gemm16<<<(NT + 15) / 16, 256, 0, stream>>>(cur, gat_w + (size_t)l * DD * DD,
                                                     att_src + l * DD, att_dst + l * DD,
                                                     xs, als, ald);
        k_alpha<<<(ETC + 255) / 256, 256, 0, stream>>>(sp, ea, lattr, als, wd + l * 12, alpha);
        k_msg<<<NT, 256, 0, stream>>>(offs, sp, alpha, ald, xs, po);
        k_vstat<<<1, 1024, 0, stream>>>(offs, alpha, ald, vstats);
        k_vacc<<<64, 256, 0, stream>>>(offs, alpha, ald, xs, vstats, po);
        k_post<<<NT, 256, 0, stream>>>(po, gat_b + l * DD, ln_g + l * DD, ln_b + l * DD,
                                       cur, po, comb + (l + 1) * DD);
        float* t = cur; cur = po; po = t;
    }
    k_agent<<<1, 256, 0, stream>>>(af, ag_w, ag_b, ag_g, ag_bt, comb);
    k_head1<<<40, 256, 0, stream>>>(comb, v_w1, a_w1, pv, pa);
    k_head2<<<1, 256, 0, stream>>>(pv, pa, v_b1, v_g, v_bt, v_w2, v_b2,
                                   a_b1, a_g, a_bt, a_w2, a_b2, (float*)d_out);
}

// Round 3
// 656.062 us; speedup vs baseline: 1.8626x; 1.2421x over previous
//
#include <hip/hip_runtime.h>
#include <math.h>

#define NN 10000
#define EE 320000
#define DD 256
#define NT 10001            // NN + virtual node
#define E1C (EE + NN)       // 330000
#define E2C (EE + 2 * NN)   // 340000
#define ETC (E2C + NT)      // 350001 (with self loops)

typedef __attribute__((ext_vector_type(8))) short s16x8;
typedef __attribute__((ext_vector_type(4))) float f32x4;

__device__ __forceinline__ unsigned short f2bf(float f) {
    unsigned u = __float_as_uint(f);
    return (unsigned short)((u + 0x7FFFu + ((u >> 16) & 1u)) >> 16);
}
__device__ __forceinline__ float bf2f(unsigned short u) {
    return __uint_as_float((unsigned)u << 16);
}

// ---------- reduction helpers (blockDim.x == 256 assumed) ----------
__device__ __forceinline__ float wave_sum(float v) {
#pragma unroll
    for (int o = 32; o > 0; o >>= 1) v += __shfl_down(v, o, 64);
    return v;
}
__device__ __forceinline__ float blk_sum256(float v, float* sm4) {
    v = wave_sum(v);
    int lane = threadIdx.x & 63, w = threadIdx.x >> 6;
    __syncthreads();
    if (lane == 0) sm4[w] = v;
    __syncthreads();
    return sm4[0] + sm4[1] + sm4[2] + sm4[3];
}

// ---------- node encoder: h0 = relu(LN(x @ enc_w + enc_b)) ----------
__global__ void k_enc(const float* __restrict__ x, const float* __restrict__ w,
                      const float* __restrict__ b, const float* __restrict__ g,
                      const float* __restrict__ bt, float* __restrict__ h,
                      unsigned short* __restrict__ hb) {
    __shared__ float sm4[4];
    __shared__ float xr[10];
    int v = blockIdx.x, j = threadIdx.x;
    if (j < 10) xr[j] = x[v * 10 + j];
    __syncthreads();
    float acc = b[j];
#pragma unroll
    for (int k = 0; k < 10; k++) acc += xr[k] * w[k * DD + j];
    float m = blk_sum256(acc, sm4) * (1.f / DD);
    float d = acc - m;
    float var = blk_sum256(d * d, sm4) * (1.f / DD);
    float y = d * rsqrtf(var + 1e-5f) * g[j] + bt[j];
    float r = fmaxf(y, 0.f);
    h[v * DD + j] = r;
    hb[v * DD + j] = f2bf(r);
}

// ---------- column sums of h0 for ctx ----------
__global__ void k_ctx(const float* __restrict__ h, float* __restrict__ ctx) {
    int c = threadIdx.x;
    float acc = 0.f;
    for (int v = blockIdx.x; v < NN; v += gridDim.x) acc += h[v * DD + c];
    atomicAdd(&ctx[c], acc);
}

// ---------- adaptive virtual node ----------
__global__ void k_vn(const float* __restrict__ ctx,
                     const float* __restrict__ w1, const float* __restrict__ b1,
                     const float* __restrict__ g, const float* __restrict__ bt,
                     const float* __restrict__ w2, const float* __restrict__ b2,
                     const float* __restrict__ vnb,
                     float* __restrict__ h, unsigned short* __restrict__ hb,
                     float* __restrict__ comb) {
    __shared__ float sm4[4];
    __shared__ float cs[DD];
    __shared__ float t[DD];
    int j = threadIdx.x;
    cs[j] = ctx[j] * (1.f / NN);
    __syncthreads();
    float acc = b1[j];
    for (int k = 0; k < DD; k++) acc += cs[k] * w1[k * DD + j];
    float m = blk_sum256(acc, sm4) * (1.f / DD);
    float d = acc - m;
    float var = blk_sum256(d * d, sm4) * (1.f / DD);
    float y = fmaxf(d * rsqrtf(var + 1e-5f) * g[j] + bt[j], 0.f);
    t[j] = y;
    __syncthreads();
    float a2 = b2[j];
    for (int k = 0; k < DD; k++) a2 += t[k] * w2[k * DD + j];
    float vn = vnb[j] + tanhf(a2);
    h[NN * DD + j] = vn;
    hb[NN * DD + j] = f2bf(vn);
    comb[j] = vn;   // jk slot 0 (virtual row of initial h)
}

// ---------- regular-edge in-degree histogram (1 atomic per edge) ----------
__global__ void k_deg(const int* __restrict__ ei, int* __restrict__ degi) {
    int e = blockIdx.x * 256 + threadIdx.x;
    if (e >= EE) return;
    atomicAdd(&degi[ei[EE + e]], 1);
}

// ---------- shfl-based exclusive scan of (degR + virtual/self additions) ----------
__global__ void k_scan(const int* __restrict__ degi, int* __restrict__ offs,
                       int* __restrict__ cursor) {
    __shared__ int wsum[4];
    __shared__ int running_s;
    int t = threadIdx.x, lane = t & 63, w = t >> 6;
    if (t == 0) running_s = 0;
    __syncthreads();
    for (int base = 0; base < NT; base += 256) {
        int v = base + t;
        int val = 0;
        if (v < NN) val = degi[v] + 2;          // + vn-edge + self-loop
        else if (v == NN) val = NN + 1;         // virtual: NN in-edges + self-loop
        int x = val;
#pragma unroll
        for (int o = 1; o < 64; o <<= 1) {
            int y = __shfl_up(x, o, 64);
            if (lane >= o) x += y;
        }
        if (lane == 63) wsum[w] = x;
        __syncthreads();
        int prefix = running_s;
        for (int ww = 0; ww < w; ww++) prefix += wsum[ww];
        if (v <= NN) { int e0 = prefix + x - val; offs[v] = e0; cursor[v] = e0; }
        __syncthreads();
        if (t == 0) running_s += wsum[0] + wsum[1] + wsum[2] + wsum[3];
        __syncthreads();
    }
    if (threadIdx.x == 0) offs[NT] = running_s;
}

// ---------- scatter regular edges into CSR (packed {src, eid}) ----------
__global__ void k_scatter(const int* __restrict__ ei, int* __restrict__ cursor,
                          int2* __restrict__ sp) {
    int e = blockIdx.x * 256 + threadIdx.x;
    if (e >= EE) return;
    int src = ei[e], dst = ei[EE + e];
    int pos = atomicAdd(&cursor[dst], 1);
    sp[pos] = make_int2(src, e);
}

// ---------- fill deterministic CSR slots: vn edges + self loops ----------
__global__ void k_fill(const int* __restrict__ offs, int2* __restrict__ sp) {
    int v = blockIdx.x * 256 + threadIdx.x;
    if (v > NN) return;
    int bN = offs[NN];
    if (v < NN) {
        int e1 = offs[v + 1];
        sp[e1 - 2] = make_int2(NN, EE + v);      // vn -> v
        sp[e1 - 1] = make_int2(v, E2C + v);      // self loop
        sp[bN + v] = make_int2(v, E1C + v);      // v -> vn (virtual segment)
    } else {
        sp[bN + NN] = make_int2(NN, E2C + NN);   // virtual self loop
    }
}

// ---------- loop_attr via segmented sums over CSR (no atomics) ----------
__global__ void k_lattr(const int* __restrict__ offs, const int2* __restrict__ sp,
                        const float* __restrict__ ea, float* __restrict__ lattr) {
    int t = threadIdx.x, lane = t & 63, w = t >> 6;
    int v = blockIdx.x * 4 + w;
    if (v > NN) return;
    if (v == NN) {
        if (lane == 0) { lattr[v * 3] = 0.5f; lattr[v * 3 + 1] = 0.f; lattr[v * 3 + 2] = 0.f; }
        return;
    }
    int b0 = offs[v];
    int cnt = offs[v + 1] - b0 - 2;      // regular in-edges
    float s0 = 0.f, s1 = 0.f, s2 = 0.f;
    for (int i = lane; i < cnt; i += 64) {
        int e = sp[b0 + i].y;
        s0 += ea[e * 3];
        s1 += ea[e * 3 + 1];
        s2 += ea[e * 3 + 2];
    }
    s0 = wave_sum(s0); s1 = wave_sum(s1); s2 = wave_sum(s2);
    if (lane == 0) {
        float inv = 1.f / (float)(cnt + 1);  // deg0 = regular + vn edge
        lattr[v * 3]     = (s0 + 0.5f) * inv;
        lattr[v * 3 + 1] = s1 * inv;
        lattr[v * 3 + 2] = s2 * inv;
    }
}

// ---------- we_dot[l][k][h] = sum_c e_w[l,k,h*64+c] * att_edge[l,h,c] ----------
__global__ void k_wedot(const float* __restrict__ ew, const float* __restrict__ ae,
                        float* __restrict__ wd) {
    int t = threadIdx.x;
    if (t >= 36) return;
    int l = t / 12, k = (t / 4) % 3, h = t % 4;
    float s = 0.f;
    for (int c = 0; c < 64; c++)
        s += ew[l * 768 + k * DD + h * 64 + c] * ae[l * DD + h * 64 + c];
    wd[t] = s;   // layout [l][k][h]
}

// ---------- transpose gat_w to bf16 Wt[l][n][k] ----------
__global__ void k_wconv(const float* __restrict__ gw, unsigned short* __restrict__ wt) {
    int b = blockIdx.x;
    int l = b >> 8, k = b & 255, j = threadIdx.x;
    float v = gw[l * 65536 + k * 256 + j];
    wt[l * 65536 + j * 256 + k] = f2bf(v);
}

// ---------- xs = h @ W via bf16 MFMA (64 rows/block, 4 waves x 16 rows) ----------
// A-frag (16x32): row = lane&15, k = (lane>>4)*8 + i
// B-frag (32x16): col = lane&15, k = (lane>>4)*8 + i   (read from Wt[n][k])
// C/D:            col = lane&15, row = (lane>>4)*4 + reg   [m89-verified]
__global__ void __launch_bounds__(256) k_gemm_mfma(
        const unsigned short* __restrict__ hb, const unsigned short* __restrict__ wt,
        const float* __restrict__ as_, const float* __restrict__ ad_,
        unsigned short* __restrict__ xsb, float* __restrict__ als, float* __restrict__ ald) {
    __shared__ unsigned short tile[64][256];
    int t = threadIdx.x, lane = t & 63, w = t >> 6;
    int v0 = blockIdx.x * 64;
    int rbase = v0 + w * 16;
    int li = lane & 15, g = lane >> 4;
    int arow = rbase + li; if (arow > NN) arow = NN;
    int koff = g * 8;
    const unsigned short* aptr = hb + (size_t)arow * DD + koff;
    const unsigned short* bptr = wt + (size_t)li * DD + koff;
    f32x4 acc[16];
#pragma unroll
    for (int n = 0; n < 16; n++) acc[n] = (f32x4){0.f, 0.f, 0.f, 0.f};
#pragma unroll
    for (int kb = 0; kb < 8; kb++) {
        s16x8 af = *(const s16x8*)(aptr + kb * 32);
#pragma unroll
        for (int n = 0; n < 16; n++) {
            s16x8 bf = *(const s16x8*)(bptr + (size_t)n * 16 * DD + kb * 32);
            acc[n] = __builtin_amdgcn_mfma_f32_16x16x32_bf16(af, bf, acc[n], 0, 0, 0);
        }
    }
    // epilogue 1: als/ald per row (16-lane group reductions)
    float asv[16], adv[16];
#pragma unroll
    for (int n = 0; n < 16; n++) { asv[n] = as_[n * 16 + li]; adv[n] = ad_[n * 16 + li]; }
#pragma unroll
    for (int r = 0; r < 4; r++) {
        int vrow = rbase + 4 * g + r;
#pragma unroll
        for (int h = 0; h < 4; h++) {
            float ps = acc[4 * h][r] * asv[4 * h] + acc[4 * h + 1][r] * asv[4 * h + 1]
                     + acc[4 * h + 2][r] * asv[4 * h + 2] + acc[4 * h + 3][r] * asv[4 * h + 3];
            float pd = acc[4 * h][r] * adv[4 * h] + acc[4 * h + 1][r] * adv[4 * h + 1]
                     + acc[4 * h + 2][r] * adv[4 * h + 2] + acc[4 * h + 3][r] * adv[4 * h + 3];
#pragma unroll
            for (int o = 1; o < 16; o <<= 1) {
                ps += __shfl_xor(ps, o, 64);
                pd += __shfl_xor(pd, o, 64);
            }
            if (li == 0 && vrow <= NN) { als[vrow * 4 + h] = ps; ald[vrow * 4 + h] = pd; }
        }
    }
    // epilogue 2: xs -> bf16 via per-wave LDS transpose (coalesced 16B stores)
#pragma unroll
    for (int n = 0; n < 16; n++)
#pragma unroll
        for (int r = 0; r < 4; r++)
            tile[w * 16 + 4 * g + r][n * 16 + li] = f2bf(acc[n][r]);
    // wave-local rows only: HW orders ds_write->ds_read within a wave
#pragma unroll
    for (int it = 0; it < 8; it++) {
        int flat = it * 64 + lane;            // 0..511
        int row = w * 16 + (flat >> 5);
        int c8 = flat & 31;
        int vrow = v0 + row;
        if (vrow <= NN)
            *(uint4*)(xsb + (size_t)vrow * DD + c8 * 8) = *(const uint4*)(&tile[row][c8 * 8]);
    }
}

// ---------- per-edge PARTIAL logits in CSR order: als[src] + edge term ----------
__global__ void k_alpha(const int2* __restrict__ sp, const float* __restrict__ ea,
                        const float* __restrict__ lattr, const float* __restrict__ als,
                        const float* __restrict__ wd,   // this layer's 12 floats [k*4+h]
                        float* __restrict__ alpha) {
    int p = blockIdx.x * 256 + threadIdx.x;
    if (p >= ETC) return;
    int2 se = sp[p];
    int src = se.x, e = se.y;
    float a0, a1, a2;
    if (e < EE)       { a0 = ea[e * 3]; a1 = ea[e * 3 + 1]; a2 = ea[e * 3 + 2]; }
    else if (e < E2C) { a0 = 0.5f; a1 = 0.f; a2 = 0.f; }
    else              { int v = e - E2C; a0 = lattr[v * 3]; a1 = lattr[v * 3 + 1]; a2 = lattr[v * 3 + 2]; }
    float4 s4 = *(const float4*)(als + src * 4);
    const float* sp4 = (const float*)&s4;
    float4 o;
    float* op = (float*)&o;
#pragma unroll
    for (int hh = 0; hh < 4; hh++)
        op[hh] = sp4[hh] + a0 * wd[hh] + a1 * wd[4 + hh] + a2 * wd[8 + hh];
    *(float4*)(alpha + (size_t)p * 4) = o;   // NO leaky, NO ald (added in consumer)
}

// ---------- per-dst online softmax + aggregation (bf16 xs gathers) ----------
__global__ void __launch_bounds__(256) k_msg(
        const int* __restrict__ offs, const int2* __restrict__ sp,
        const float* __restrict__ alpha, const float* __restrict__ ald,
        const unsigned short* __restrict__ xsb, float* __restrict__ outa) {
    int v = blockIdx.x;
    int t = threadIdx.x, lane = t & 63, w = t >> 6;
    if (v == NN) { outa[(size_t)NN * DD + t] = 0.f; return; }  // virtual handled separately
    __shared__ float am[4][4], asv[4][4];
    __shared__ float red[8][256];
    __shared__ float fin[8];        // m[4], inv[4]
    int b0 = offs[v], deg = offs[v + 1] - b0;
    float4 ad4 = *(const float4*)(ald + v * 4);
    const float* adp = (const float*)&ad4;
    // phase A: online (max,sum) per head, threads strided over segment (coalesced f4)
    float m0 = -3.4e38f, m1 = -3.4e38f, m2 = -3.4e38f, m3 = -3.4e38f;
    float s0 = 0.f, s1 = 0.f, s2 = 0.f, s3 = 0.f;
    for (int i = t; i < deg; i += 256) {
        float4 a4 = *(const float4*)(alpha + (size_t)(b0 + i) * 4);
        float f0 = a4.x + adp[0]; f0 = f0 > 0.f ? f0 : 0.2f * f0;
        float f1 = a4.y + adp[1]; f1 = f1 > 0.f ? f1 : 0.2f * f1;
        float f2 = a4.z + adp[2]; f2 = f2 > 0.f ? f2 : 0.2f * f2;
        float f3 = a4.w + adp[3]; f3 = f3 > 0.f ? f3 : 0.2f * f3;
        if (f0 > m0) { s0 = s0 * __expf(m0 - f0) + 1.f; m0 = f0; } else s0 += __expf(f0 - m0);
        if (f1 > m1) { s1 = s1 * __expf(m1 - f1) + 1.f; m1 = f1; } else s1 += __expf(f1 - m1);
        if (f2 > m2) { s2 = s2 * __expf(m2 - f2) + 1.f; m2 = f2; } else s2 += __expf(f2 - m2);
        if (f3 > m3) { s3 = s3 * __expf(m3 - f3) + 1.f; m3 = f3; } else s3 += __expf(f3 - m3);
    }
#pragma unroll
    for (int o = 1; o < 64; o <<= 1) {
        float mo, so, M;
        mo = __shfl_xor(m0, o, 64); so = __shfl_xor(s0, o, 64);
        M = fmaxf(m0, mo); s0 = s0 * __expf(m0 - M) + so * __expf(mo - M); m0 = M;
        mo = __shfl_xor(m1, o, 64); so = __shfl_xor(s1, o, 64);
        M = fmaxf(m1, mo); s1 = s1 * __expf(m1 - M) + so * __expf(mo - M); m1 = M;
        mo = __shfl_xor(m2, o, 64); so = __shfl_xor(s2, o, 64);
        M = fmaxf(m2, mo); s2 = s2 * __expf(m2 - M) + so * __expf(mo - M); m2 = M;
        mo = __shfl_xor(m3, o, 64); so = __shfl_xor(s3, o, 64);
        M = fmaxf(m3, mo); s3 = s3 * __expf(m3 - M) + so * __expf(mo - M); m3 = M;
    }
    if (lane == 0) {
        am[w][0] = m0; am[w][1] = m1; am[w][2] = m2; am[w][3] = m3;
        asv[w][0] = s0; asv[w][1] = s1; asv[w][2] = s2; asv[w][3] = s3;
    }
    __syncthreads();
    if (t < 4) {   // per head: combine 4 waves
        float M = fmaxf(fmaxf(am[0][t], am[1][t]), fmaxf(am[2][t], am[3][t]));
        float S = asv[0][t] * __expf(am[0][t] - M) + asv[1][t] * __expf(am[1][t] - M)
                + asv[2][t] * __expf(am[2][t] - M) + asv[3][t] * __expf(am[3][t] - M);
        fin[t] = M;
        fin[4 + t] = 1.f / (S + 1e-16f);
    }
    __syncthreads();
    // phase 3: 8 edge-slots (4 waves x 2 half-waves); 32 lanes x ushort8 per row
    int sub = lane >> 5, l32 = lane & 31;
    int hh = l32 >> 3;
    float mh = fin[hh], inv = fin[4 + hh], adh = adp[hh];
    float a8[8];
#pragma unroll
    for (int q = 0; q < 8; q++) a8[q] = 0.f;
    for (int i = w * 2 + sub; i < deg; i += 8) {
        int p = b0 + i;
        float a = alpha[(size_t)p * 4 + hh] + adh;
        a = a > 0.f ? a : 0.2f * a;
        float wt2 = __expf(a - mh) * inv;
        int src = sp[p].x;
        uint4 xq = *(const uint4*)(xsb + (size_t)src * DD + l32 * 8);
        const unsigned short* xp = (const unsigned short*)&xq;
#pragma unroll
        for (int q = 0; q < 8; q++) a8[q] += wt2 * bf2f(xp[q]);
    }
    *(float4*)(&red[w * 2 + sub][l32 * 8])     = make_float4(a8[0], a8[1], a8[2], a8[3]);
    *(float4*)(&red[w * 2 + sub][l32 * 8 + 4]) = make_float4(a8[4], a8[5], a8[6], a8[7]);
    __syncthreads();
    float o = 0.f;
#pragma unroll
    for (int q = 0; q < 8; q++) o += red[q][t];
    outa[(size_t)v * DD + t] = o;
}

// ---------- virtual-node softmax stats over its (contiguous) CSR segment ----------
__global__ void k_vstat(const int* __restrict__ offs, const float* __restrict__ alpha,
                        const float* __restrict__ ald, float* __restrict__ vstats) {
    __shared__ float am[16][4], asv[16][4];
    int t = threadIdx.x, lane = t & 63, w = t >> 6;
    int b0 = offs[NN], deg = NN + 1;
    float4 ad4 = *(const float4*)(ald + NN * 4);
    const float* adp = (const float*)&ad4;
    float m0 = -3.4e38f, m1 = -3.4e38f, m2 = -3.4e38f, m3 = -3.4e38f;
    float s0 = 0.f, s1 = 0.f, s2 = 0.f, s3 = 0.f;
    for (int i = t; i < deg; i += 1024) {
        float4 a4 = *(const float4*)(alpha + (size_t)(b0 + i) * 4);
        float f0 = a4.x + adp[0]; f0 = f0 > 0.f ? f0 : 0.2f * f0;
        float f1 = a4.y + adp[1]; f1 = f1 > 0.f ? f1 : 0.2f * f1;
        float f2 = a4.z + adp[2]; f2 = f2 > 0.f ? f2 : 0.2f * f2;
        float f3 = a4.w + adp[3]; f3 = f3 > 0.f ? f3 : 0.2f * f3;
        if (f0 > m0) { s0 = s0 * __expf(m0 - f0) + 1.f; m0 = f0; } else s0 += __expf(f0 - m0);
        if (f1 > m1) { s1 = s1 * __expf(m1 - f1) + 1.f; m1 = f1; } else s1 += __expf(f1 - m1);
        if (f2 > m2) { s2 = s2 * __expf(m2 - f2) + 1.f; m2 = f2; } else s2 += __expf(f2 - m2);
        if (f3 > m3) { s3 = s3 * __expf(m3 - f3) + 1.f; m3 = f3; } else s3 += __expf(f3 - m3);
    }
#pragma unroll
    for (int o = 1; o < 64; o <<= 1) {
        float mo, so, M;
        mo = __shfl_xor(m0, o, 64); so = __shfl_xor(s0, o, 64);
        M = fmaxf(m0, mo); s0 = s0 * __expf(m0 - M) + so * __expf(mo - M); m0 = M;
        mo = __shfl_xor(m1, o, 64); so = __shfl_xor(s1, o, 64);
        M = fmaxf(m1, mo); s1 = s1 * __expf(m1 - M) + so * __expf(mo - M); m1 = M;
        mo = __shfl_xor(m2, o, 64); so = __shfl_xor(s2, o, 64);
        M = fmaxf(m2, mo); s2 = s2 * __expf(m2 - M) + so * __expf(mo - M); m2 = M;
        mo = __shfl_xor(m3, o, 64); so = __shfl_xor(s3, o, 64);
        M = fmaxf(m3, mo); s3 = s3 * __expf(m3 - M) + so * __expf(mo - M); m3 = M;
    }
    if (lane == 0) {
        am[w][0] = m0; am[w][1] = m1; am[w][2] = m2; am[w][3] = m3;
        asv[w][0] = s0; asv[w][1] = s1; asv[w][2] = s2; asv[w][3] = s3;
    }
    __syncthreads();
    if (t < 4) {
        float M = -3.4e38f;
        for (int ww = 0; ww < 16; ww++) M = fmaxf(M, am[ww][t]);
        float S = 0.f;
        for (int ww = 0; ww < 16; ww++) S += asv[ww][t] * __expf(am[ww][t] - M);
        vstats[t] = M;
        vstats[4 + t] = 1.f / (S + 1e-16f);
    }
}

// ---------- virtual-node weighted accumulation (sequential src rows) ----------
__global__ void k_vacc(const int* __restrict__ offs, const float* __restrict__ alpha,
                       const float* __restrict__ ald, const unsigned short* __restrict__ xsb,
                       const float* __restrict__ vstats, float* __restrict__ outa) {
    int j = threadIdx.x, hh = j >> 6;
    int b0 = offs[NN];
    float mh = vstats[hh], inv = vstats[4 + hh];
    float adh = ald[NN * 4 + hh];
    float acc = 0.f;
    for (int i = blockIdx.x; i < NN + 1; i += gridDim.x) {
        float a = alpha[(size_t)(b0 + i) * 4 + hh] + adh;
        a = a > 0.f ? a : 0.2f * a;
        float wt = __expf(a - mh) * inv;
        int src = (i < NN) ? i : NN;
        acc += wt * bf2f(xsb[(size_t)src * DD + j]);
    }
    atomicAdd(&outa[(size_t)NN * DD + j], acc);
}

// ---------- bias + LN + residual relu (fp32 + bf16 copies of h_next) ----------
__global__ void k_post(const float* __restrict__ outa, const float* __restrict__ bias,
                       const float* __restrict__ g, const float* __restrict__ bt,
                       const float* __restrict__ hin, float* __restrict__ hout,
                       unsigned short* __restrict__ hbout, float* __restrict__ jkslot) {
    __shared__ float sm4[4];
    int v = blockIdx.x, j = threadIdx.x;
    float t = outa[(size_t)v * DD + j] + bias[j];
    float m = blk_sum256(t, sm4) * (1.f / DD);
    float d = t - m;
    float var = blk_sum256(d * d, sm4) * (1.f / DD);
    float y = d * rsqrtf(var + 1e-5f) * g[j] + bt[j];
    float r = fmaxf(y + hin[(size_t)v * DD + j], 0.f);
    hout[(size_t)v * DD + j] = r;
    hbout[(size_t)v * DD + j] = f2bf(r);
    if (v == NN) jkslot[j] = r;
}

// ---------- agent encoder ----------
__global__ void k_agent(const float* __restrict__ af, const float* __restrict__ w,
                        const float* __restrict__ b, const float* __restrict__ g,
                        const float* __restrict__ bt, float* __restrict__ comb) {
    __shared__ float sm4[4];
    __shared__ float xr[10];
    int j = threadIdx.x;
    if (j < 10) xr[j] = af[j];
    __syncthreads();
    float acc = b[j];
#pragma unroll
    for (int k = 0; k < 10; k++) acc += xr[k] * w[k * DD + j];
    float m = blk_sum256(acc, sm4) * (1.f / DD);
    float d = acc - m;
    float var = blk_sum256(d * d, sm4) * (1.f / DD);
    float y = d * rsqrtf(var + 1e-5f) * g[j] + bt[j];
    comb[1024 + j] = fmaxf(y, 0.f);
}

// ---------- dueling head, stage 1: 40-way k-sliced partial GEMMs ----------
__global__ void k_head1(const float* __restrict__ comb,
                        const float* __restrict__ vw1, const float* __restrict__ aw1,
                        float* __restrict__ pv, float* __restrict__ pa) {
    int j = threadIdx.x, s = blockIdx.x;
    int k0 = s * 32;
    float accv = 0.f, acca = 0.f;
#pragma unroll
    for (int kk = 0; kk < 32; kk++) {
        float c = comb[k0 + kk];
        accv += c * vw1[(k0 + kk) * DD + j];
        acca += c * aw1[(k0 + kk) * DD + j];
    }
    pv[s * DD + j] = accv;
    pa[s * DD + j] = acca;
}

// ---------- dueling head, stage 2: combine + LN + second layers ----------
__global__ void k_head2(const float* __restrict__ pv, const float* __restrict__ pa,
                        const float* __restrict__ vb1, const float* __restrict__ vg,
                        const float* __restrict__ vbt, const float* __restrict__ vw2,
                        const float* __restrict__ vb2,
                        const float* __restrict__ ab1, const float* __restrict__ ag,
                        const float* __restrict__ abt, const float* __restrict__ aw2,
                        const float* __restrict__ ab2, float* __restrict__ out) {
    __shared__ float sm4[4];
    __shared__ float tl[DD];
    __shared__ float adv[9];
    __shared__ float valv;
    int j = threadIdx.x;
    float acc = vb1[j], acc2 = ab1[j];
    for (int s = 0; s < 40; s++) { acc += pv[s * DD + j]; acc2 += pa[s * DD + j]; }
    // value head
    float m = blk_sum256(acc, sm4) * (1.f / DD);
    float d = acc - m;
    float var = blk_sum256(d * d, sm4) * (1.f / DD);
    float y = fmaxf(d * rsqrtf(var + 1e-5f) * vg[j] + vbt[j], 0.f);
    float vs = blk_sum256(y * vw2[j], sm4);
    if (j == 0) valv = vs + vb2[0];
    // advantage head
    float m2 = blk_sum256(acc2, sm4) * (1.f / DD);
    float d2 = acc2 - m2;
    float var2 = blk_sum256(d2 * d2, sm4) * (1.f / DD);
    float y2 = fmaxf(d2 * rsqrtf(var2 + 1e-5f) * ag[j] + abt[j], 0.f);
    tl[j] = y2;
    __syncthreads();
    if (j < 9) {
        float s = ab2[j];
        for (int k = 0; k < DD; k++) s += tl[k] * aw2[k * 9 + j];
        adv[j] = s;
    }
    __syncthreads();
    if (j < 9) {
        float mean = 0.f;
        for (int o = 0; o < 9; o++) mean += adv[o];
        mean *= (1.f / 9.f);
        out[j] = valv + adv[j] - mean;
    }
}

extern "C" void kernel_launch(void* const* d_in, const int* in_sizes, int n_in,
                              void* d_out, int out_size, void* d_ws, size_t ws_size,
                              hipStream_t stream) {
    (void)in_sizes; (void)n_in; (void)out_size; (void)ws_size;
    const float* x      = (const float*)d_in[0];
    const int*   ei     = (const int*)d_in[1];
    const float* ea     = (const float*)d_in[2];
    const float* af     = (const float*)d_in[3];
    const float* enc_w  = (const float*)d_in[4];
    const float* enc_b  = (const float*)d_in[5];
    const float* enc_g  = (const float*)d_in[6];
    const float* enc_bt = (const float*)d_in[7];
    const float* vn_base= (const float*)d_in[8];
    const float* vn_w1  = (const float*)d_in[9];
    const float* vn_b1  = (const float*)d_in[10];
    const float* vn_g   = (const float*)d_in[11];
    const float* vn_bt  = (const float*)d_in[12];
    const float* vn_w2  = (const float*)d_in[13];
    const float* vn_b2  = (const float*)d_in[14];
    const float* gat_w  = (const float*)d_in[15];
    const float* att_src= (const float*)d_in[16];
    const float* att_dst= (const float*)d_in[17];
    const float* att_edge=(const float*)d_in[18];
    const float* edge_w = (const float*)d_in[19];
    const float* gat_b  = (const float*)d_in[20];
    const float* ln_g   = (const float*)d_in[21];
    const float* ln_b   = (const float*)d_in[22];
    const float* ag_w   = (const float*)d_in[23];
    const float* ag_b   = (const float*)d_in[24];
    const float* ag_g   = (const float*)d_in[25];
    const float* ag_bt  = (const float*)d_in[26];
    const float* v_w1   = (const float*)d_in[27];
    const float* v_b1   = (const float*)d_in[28];
    const float* v_g    = (const float*)d_in[29];
    const float* v_bt   = (const float*)d_in[30];
    const float* v_w2   = (const float*)d_in[31];
    const float* v_b2   = (const float*)d_in[32];
    const float* a_w1   = (const float*)d_in[33];
    const float* a_b1   = (const float*)d_in[34];
    const float* a_g    = (const float*)d_in[35];
    const float* a_bt   = (const float*)d_in[36];
    const float* a_w2   = (const float*)d_in[37];
    const float* a_b2   = (const float*)d_in[38];

    char* p = (char*)d_ws;
    auto alloc = [&](size_t bytes) {
        char* r = p;
        p += (bytes + 255) & ~(size_t)255;
        return r;
    };
    float* big0  = (float*)alloc((size_t)NT * DD * 4);
    float* big2  = (float*)alloc((size_t)NT * DD * 4);
    unsigned short* hb  = (unsigned short*)alloc((size_t)NT * DD * 2);
    unsigned short* xsb = (unsigned short*)alloc((size_t)NT * DD * 2);
    unsigned short* wt  = (unsigned short*)alloc((size_t)3 * DD * DD * 2);
    float* alpha = (float*)alloc((size_t)ETC * 4 * 4);
    int2*  sp    = (int2*) alloc((size_t)ETC * 8);
    float* als   = (float*)alloc((size_t)NT * 4 * 4);
    float* ald   = (float*)alloc((size_t)NT * 4 * 4);
    float* ctx   = (float*)alloc(DD * 4);
    float* comb  = (float*)alloc(1280 * 4);
    float* lattr = (float*)alloc((size_t)NT * 3 * 4);
    float* wd    = (float*)alloc(36 * 4);
    float* vstats= (float*)alloc(8 * 4);
    float* pv    = (float*)alloc(40 * DD * 4);
    float* pa    = (float*)alloc(40 * DD * 4);
    int* degi    = (int*)alloc((size_t)NT * 4);
    int* offs    = (int*)alloc((size_t)(NT + 1) * 4);
    int* cursor  = (int*)alloc((size_t)NT * 4);

    hipMemsetAsync(ctx, 0, DD * 4, stream);
    hipMemsetAsync(degi, 0, (size_t)NT * 4, stream);

    k_enc<<<NN, 256, 0, stream>>>(x, enc_w, enc_b, enc_g, enc_bt, big0, hb);
    k_ctx<<<64, 256, 0, stream>>>(big0, ctx);
    k_vn<<<1, 256, 0, stream>>>(ctx, vn_w1, vn_b1, vn_g, vn_bt, vn_w2, vn_b2, vn_base, big0, hb, comb);
    k_deg<<<(EE + 255) / 256, 256, 0, stream>>>(ei, degi);
    k_scan<<<1, 256, 0, stream>>>(degi, offs, cursor);
    k_scatter<<<(EE + 255) / 256, 256, 0, stream>>>(ei, cursor, sp);
    k_fill<<<(NT + 255) / 256, 256, 0, stream>>>(offs, sp);
    k_lattr<<<(NT + 3) / 4, 256, 0, stream>>>(offs, sp, ea, lattr);
    k_wedot<<<1, 64, 0, stream>>>(edge_w, att_edge, wd);
    k_wconv<<<768, 256, 0, stream>>>(gat_w, wt);

    float* cur = big0;
    float* po  = big2;
    for (int l = 0; l < 3; l++) {
        k_gemm_mfma<<<(NT + 63) / 64, 256, 0, stream>>>(hb, wt + (size_t)l * DD * DD,
                                                        att_src + l * DD, att_dst + l * DD,
                                                        xsb, als, ald);
        k_alpha<<<(ETC + 255) / 256, 256, 0, stream>>>(sp, ea, lattr, als, wd + l * 12, alpha);
        k_msg<<<NT, 256, 0, stream>>>(offs, sp, alpha, ald, xsb, po);
        k_vstat<<<1, 1024, 0, stream>>>(offs, alpha, ald, vstats);
        k_vacc<<<64, 256, 0, stream>>>(offs, alpha, ald, xsb, vstats, po);
        k_post<<<NT, 256, 0, stream>>>(po, gat_b + l * DD, ln_g + l * DD, ln_b + l * DD,
                                       cur, po, hb, comb + (l + 1) * DD);
        float* t = cur; cur = po; po = t;
    }
    k_agent<<<1, 256, 0, stream>>>(af, ag_w, ag_b, ag_g, ag_bt, comb);
    k_head1<<<40, 256, 0, stream>>>(comb, v_w1, a_w1, pv, pa);
    k_head2<<<1, 256, 0, stream>>>(pv, pa, v_b1, v_g, v_bt, v_w2, v_b2,
                                   a_b1, a_g, a_bt, a_w2, a_b2, (float*)d_out);
}

// Round 4
// 503.984 us; speedup vs baseline: 2.4246x; 1.3018x over previous
//
#include <hip/hip_runtime.h>
#include <math.h>

#define NN 10000
#define EE 320000
#define DD 256
#define NT 10001            // NN + virtual node
#define E1C (EE + NN)       // 330000
#define E2C (EE + 2 * NN)   // 340000
#define ETC (E2C + NT)      // 350001 (with self loops)

typedef __attribute__((ext_vector_type(8))) short s16x8;
typedef __attribute__((ext_vector_type(4))) float f32x4;

__device__ __forceinline__ unsigned short f2bf(float f) {
    unsigned u = __float_as_uint(f);
    return (unsigned short)((u + 0x7FFFu + ((u >> 16) & 1u)) >> 16);
}
__device__ __forceinline__ float bf2f(unsigned short u) {
    return __uint_as_float((unsigned)u << 16);
}

// ---------- reduction helpers (blockDim.x == 256 assumed) ----------
__device__ __forceinline__ float wave_sum(float v) {
#pragma unroll
    for (int o = 32; o > 0; o >>= 1) v += __shfl_down(v, o, 64);
    return v;
}
__device__ __forceinline__ float blk_sum256(float v, float* sm4) {
    v = wave_sum(v);
    int lane = threadIdx.x & 63, w = threadIdx.x >> 6;
    __syncthreads();
    if (lane == 0) sm4[w] = v;
    __syncthreads();
    return sm4[0] + sm4[1] + sm4[2] + sm4[3];
}

// ---------- node encoder: h0 = relu(LN(x @ enc_w + enc_b)) ----------
__global__ void k_enc(const float* __restrict__ x, const float* __restrict__ w,
                      const float* __restrict__ b, const float* __restrict__ g,
                      const float* __restrict__ bt, float* __restrict__ h,
                      unsigned short* __restrict__ hb) {
    __shared__ float sm4[4];
    __shared__ float xr[10];
    int v = blockIdx.x, j = threadIdx.x;
    if (j < 10) xr[j] = x[v * 10 + j];
    __syncthreads();
    float acc = b[j];
#pragma unroll
    for (int k = 0; k < 10; k++) acc += xr[k] * w[k * DD + j];
    float m = blk_sum256(acc, sm4) * (1.f / DD);
    float d = acc - m;
    float var = blk_sum256(d * d, sm4) * (1.f / DD);
    float y = d * rsqrtf(var + 1e-5f) * g[j] + bt[j];
    float r = fmaxf(y, 0.f);
    h[v * DD + j] = r;
    hb[v * DD + j] = f2bf(r);
}

// ---------- column sums of h0 for ctx ----------
__global__ void k_ctx(const float* __restrict__ h, float* __restrict__ ctx) {
    int c = threadIdx.x;
    float acc = 0.f;
    for (int v = blockIdx.x; v < NN; v += gridDim.x) acc += h[v * DD + c];
    atomicAdd(&ctx[c], acc);
}

// ---------- adaptive virtual node ----------
__global__ void k_vn(const float* __restrict__ ctx,
                     const float* __restrict__ w1, const float* __restrict__ b1,
                     const float* __restrict__ g, const float* __restrict__ bt,
                     const float* __restrict__ w2, const float* __restrict__ b2,
                     const float* __restrict__ vnb,
                     float* __restrict__ h, unsigned short* __restrict__ hb,
                     float* __restrict__ comb) {
    __shared__ float sm4[4];
    __shared__ float cs[DD];
    __shared__ float t[DD];
    int j = threadIdx.x;
    cs[j] = ctx[j] * (1.f / NN);
    __syncthreads();
    float acc = b1[j];
    for (int k = 0; k < DD; k++) acc += cs[k] * w1[k * DD + j];
    float m = blk_sum256(acc, sm4) * (1.f / DD);
    float d = acc - m;
    float var = blk_sum256(d * d, sm4) * (1.f / DD);
    float y = fmaxf(d * rsqrtf(var + 1e-5f) * g[j] + bt[j], 0.f);
    t[j] = y;
    __syncthreads();
    float a2 = b2[j];
    for (int k = 0; k < DD; k++) a2 += t[k] * w2[k * DD + j];
    float vn = vnb[j] + tanhf(a2);
    h[NN * DD + j] = vn;
    hb[NN * DD + j] = f2bf(vn);
    comb[j] = vn;   // jk slot 0 (virtual row of initial h)
}

// ---------- regular-edge in-degree histogram (1 atomic per edge) ----------
__global__ void k_deg(const int* __restrict__ ei, int* __restrict__ degi) {
    int e = blockIdx.x * 256 + threadIdx.x;
    if (e >= EE) return;
    atomicAdd(&degi[ei[EE + e]], 1);
}

// ---------- 1024-wide exclusive scan of (degR + virtual/self additions) ----------
__global__ void k_scan(const int* __restrict__ degi, int* __restrict__ offs,
                       int* __restrict__ cursor) {
    __shared__ int wsum[16];
    __shared__ int running_s;
    int t = threadIdx.x, lane = t & 63, w = t >> 6;
    if (t == 0) running_s = 0;
    __syncthreads();
    for (int base = 0; base < NT; base += 1024) {
        int v = base + t;
        int val = 0;
        if (v < NN) val = degi[v] + 2;          // + vn-edge + self-loop
        else if (v == NN) val = NN + 1;         // virtual: NN in-edges + self-loop
        int x = val;
#pragma unroll
        for (int o = 1; o < 64; o <<= 1) {
            int y = __shfl_up(x, o, 64);
            if (lane >= o) x += y;
        }
        if (lane == 63) wsum[w] = x;
        __syncthreads();
        int prefix = running_s;
        for (int ww = 0; ww < w; ww++) prefix += wsum[ww];
        if (v <= NN) { int e0 = prefix + x - val; offs[v] = e0; cursor[v] = e0; }
        __syncthreads();
        if (t == 0) {
            int s = 0;
            for (int i = 0; i < 16; i++) s += wsum[i];
            running_s += s;
        }
        __syncthreads();
    }
    if (threadIdx.x == 0) offs[NT] = running_s;
}

// ---------- scatter regular edges into CSR (packed {src, eid}) ----------
__global__ void k_scatter(const int* __restrict__ ei, int* __restrict__ cursor,
                          int2* __restrict__ sp) {
    int e = blockIdx.x * 256 + threadIdx.x;
    if (e >= EE) return;
    int src = ei[e], dst = ei[EE + e];
    int pos = atomicAdd(&cursor[dst], 1);
    sp[pos] = make_int2(src, e);
}

// ---------- fused: fill deterministic CSR slots + loop_attr segmented sums ----------
__global__ void k_flattr(const int* __restrict__ offs, int2* __restrict__ sp,
                         const float* __restrict__ ea, float* __restrict__ lattr) {
    int t = threadIdx.x, lane = t & 63, w = t >> 6;
    int v = blockIdx.x * 4 + w;
    if (v > NN) return;
    int bN = offs[NN];
    if (v == NN) {
        if (lane == 0) {
            lattr[v * 3] = 0.5f; lattr[v * 3 + 1] = 0.f; lattr[v * 3 + 2] = 0.f;
            sp[bN + NN] = make_int2(NN, E2C + NN);   // virtual self loop
        }
        return;
    }
    int b0 = offs[v], e1 = offs[v + 1];
    if (lane == 0) {
        sp[e1 - 2] = make_int2(NN, EE + v);      // vn -> v
        sp[e1 - 1] = make_int2(v, E2C + v);      // self loop
        sp[bN + v] = make_int2(v, E1C + v);      // v -> vn (virtual segment)
    }
    int cnt = e1 - b0 - 2;                       // regular in-edges
    float s0 = 0.f, s1 = 0.f, s2 = 0.f;
    for (int i = lane; i < cnt; i += 64) {
        int e = sp[b0 + i].y;
        s0 += ea[e * 3];
        s1 += ea[e * 3 + 1];
        s2 += ea[e * 3 + 2];
    }
    s0 = wave_sum(s0); s1 = wave_sum(s1); s2 = wave_sum(s2);
    if (lane == 0) {
        float inv = 1.f / (float)(cnt + 1);      // deg0 = regular + vn edge
        lattr[v * 3]     = (s0 + 0.5f) * inv;
        lattr[v * 3 + 1] = s1 * inv;
        lattr[v * 3 + 2] = s2 * inv;
    }
}

// ---------- we_dot[l][k][h] = sum_c e_w[l,k,h*64+c] * att_edge[l,h,c] ----------
__global__ void k_wedot(const float* __restrict__ ew, const float* __restrict__ ae,
                        float* __restrict__ wd) {
    int t = threadIdx.x;
    if (t >= 36) return;
    int l = t / 12, k = (t / 4) % 3, h = t % 4;
    float s = 0.f;
    for (int c = 0; c < 64; c++)
        s += ew[l * 768 + k * DD + h * 64 + c] * ae[l * DD + h * 64 + c];
    wd[t] = s;   // layout [l][k][h]
}

// ---------- per-edge, per-layer, per-head edge-attr dots, bf16 packed ----------
__global__ void k_edot(const int2* __restrict__ sp, const float* __restrict__ ea,
                       const float* __restrict__ lattr, const float* __restrict__ wd,
                       unsigned short* __restrict__ edot) {
    int p = blockIdx.x * 256 + threadIdx.x;
    if (p >= ETC) return;
    int e = sp[p].y;
    float a0, a1, a2;
    if (e < EE)       { a0 = ea[e * 3]; a1 = ea[e * 3 + 1]; a2 = ea[e * 3 + 2]; }
    else if (e < E2C) { a0 = 0.5f; a1 = 0.f; a2 = 0.f; }
    else              { int v = e - E2C; a0 = lattr[v * 3]; a1 = lattr[v * 3 + 1]; a2 = lattr[v * 3 + 2]; }
#pragma unroll
    for (int l = 0; l < 3; l++) {
        ushort4 o;
        o.x = f2bf(a0 * wd[l * 12 + 0] + a1 * wd[l * 12 + 4] + a2 * wd[l * 12 + 8]);
        o.y = f2bf(a0 * wd[l * 12 + 1] + a1 * wd[l * 12 + 5] + a2 * wd[l * 12 + 9]);
        o.z = f2bf(a0 * wd[l * 12 + 2] + a1 * wd[l * 12 + 6] + a2 * wd[l * 12 + 10]);
        o.w = f2bf(a0 * wd[l * 12 + 3] + a1 * wd[l * 12 + 7] + a2 * wd[l * 12 + 11]);
        *(ushort4*)(edot + (size_t)l * ETC * 4 + (size_t)p * 4) = o;
    }
}

// ---------- transpose gat_w to bf16 Wt[l][n][k] ----------
__global__ void k_wconv(const float* __restrict__ gw, unsigned short* __restrict__ wt) {
    int b = blockIdx.x;
    int l = b >> 8, k = b & 255, j = threadIdx.x;
    float v = gw[l * 65536 + k * 256 + j];
    wt[l * 65536 + j * 256 + k] = f2bf(v);
}

// ---------- xs = h @ W via bf16 MFMA (64 rows/block, 4 waves x 16 rows) ----------
__global__ void __launch_bounds__(256) k_gemm_mfma(
        const unsigned short* __restrict__ hb, const unsigned short* __restrict__ wt,
        const float* __restrict__ as_, const float* __restrict__ ad_,
        unsigned short* __restrict__ xsb, float* __restrict__ als, float* __restrict__ ald) {
    __shared__ unsigned short tile[64][256];
    int t = threadIdx.x, lane = t & 63, w = t >> 6;
    int v0 = blockIdx.x * 64;
    int rbase = v0 + w * 16;
    int li = lane & 15, g = lane >> 4;
    int arow = rbase + li; if (arow > NN) arow = NN;
    int koff = g * 8;
    const unsigned short* aptr = hb + (size_t)arow * DD + koff;
    const unsigned short* bptr = wt + (size_t)li * DD + koff;
    f32x4 acc[16];
#pragma unroll
    for (int n = 0; n < 16; n++) acc[n] = (f32x4){0.f, 0.f, 0.f, 0.f};
#pragma unroll
    for (int kb = 0; kb < 8; kb++) {
        s16x8 af = *(const s16x8*)(aptr + kb * 32);
#pragma unroll
        for (int n = 0; n < 16; n++) {
            s16x8 bf = *(const s16x8*)(bptr + (size_t)n * 16 * DD + kb * 32);
            acc[n] = __builtin_amdgcn_mfma_f32_16x16x32_bf16(af, bf, acc[n], 0, 0, 0);
        }
    }
    float asv[16], adv[16];
#pragma unroll
    for (int n = 0; n < 16; n++) { asv[n] = as_[n * 16 + li]; adv[n] = ad_[n * 16 + li]; }
#pragma unroll
    for (int r = 0; r < 4; r++) {
        int vrow = rbase + 4 * g + r;
#pragma unroll
        for (int h = 0; h < 4; h++) {
            float ps = acc[4 * h][r] * asv[4 * h] + acc[4 * h + 1][r] * asv[4 * h + 1]
                     + acc[4 * h + 2][r] * asv[4 * h + 2] + acc[4 * h + 3][r] * asv[4 * h + 3];
            float pd = acc[4 * h][r] * adv[4 * h] + acc[4 * h + 1][r] * adv[4 * h + 1]
                     + acc[4 * h + 2][r] * adv[4 * h + 2] + acc[4 * h + 3][r] * adv[4 * h + 3];
#pragma unroll
            for (int o = 1; o < 16; o <<= 1) {
                ps += __shfl_xor(ps, o, 64);
                pd += __shfl_xor(pd, o, 64);
            }
            if (li == 0 && vrow <= NN) { als[vrow * 4 + h] = ps; ald[vrow * 4 + h] = pd; }
        }
    }
#pragma unroll
    for (int n = 0; n < 16; n++)
#pragma unroll
        for (int r = 0; r < 4; r++)
            tile[w * 16 + 4 * g + r][n * 16 + li] = f2bf(acc[n][r]);
#pragma unroll
    for (int it = 0; it < 8; it++) {
        int flat = it * 64 + lane;
        int row = w * 16 + (flat >> 5);
        int c8 = flat & 31;
        int vrow = v0 + row;
        if (vrow <= NN)
            *(uint4*)(xsb + (size_t)vrow * DD + c8 * 8) = *(const uint4*)(&tile[row][c8 * 8]);
    }
}

// ---------- single-pass softmax-aggregation + fused LN/residual epilogue ----------
// per dst block: 8 edge-slots (4 waves x 2 half-waves), 32 lanes x 8 ch each.
// no max-subtraction: logits are O(1) (LN'd h x 0.05-scale weights).
__global__ void __launch_bounds__(256) k_msg(
        const int* __restrict__ offs, const int2* __restrict__ sp,
        const unsigned short* __restrict__ edotL,
        const float* __restrict__ als, const float* __restrict__ ald,
        const unsigned short* __restrict__ xsb,
        const float* __restrict__ bias, const float* __restrict__ g,
        const float* __restrict__ bt, const float* __restrict__ hin,
        float* __restrict__ hout, unsigned short* __restrict__ hbout) {
    int v = blockIdx.x;
    if (v == NN) return;                         // virtual dst: k_vacc/k_vpost
    int t = threadIdx.x, lane = t & 63, w = t >> 6;
    int sub = lane >> 5, l32 = lane & 31, slot = w * 2 + sub;
    int hh = l32 >> 3;
    __shared__ float red[4][8][33];
    __shared__ float wsred[4][4];
    __shared__ float fin[4];
    __shared__ float sm4[4];
    int b0 = offs[v], deg = offs[v + 1] - b0;
    float adh = ald[v * 4 + hh];
    float acc[8];
#pragma unroll
    for (int q = 0; q < 8; q++) acc[q] = 0.f;
    float swt = 0.f;
    for (int i = slot; i < deg; i += 8) {
        int p = b0 + i;
        int src = sp[p].x;
        float a = als[src * 4 + hh] + bf2f(edotL[(size_t)p * 4 + hh]) + adh;
        a = a > 0.f ? a : 0.2f * a;
        float wt = __expf(a);
        uint4 xq = *(const uint4*)(xsb + (size_t)src * DD + l32 * 8);
        const unsigned short* xp = (const unsigned short*)&xq;
#pragma unroll
        for (int q = 0; q < 8; q++) acc[q] += wt * bf2f(xp[q]);
        if ((l32 & 7) == 0) swt += wt;
    }
    // combine the two half-wave slots in-register
#pragma unroll
    for (int q = 0; q < 8; q++) acc[q] += __shfl_xor(acc[q], 32, 64);
    swt += __shfl_xor(swt, 32, 64);
    if (sub == 0) {
#pragma unroll
        for (int q = 0; q < 8; q++) red[w][q][l32] = acc[q];   // conflict-free
        if ((l32 & 7) == 0) wsred[w][hh] = swt;
    }
    __syncthreads();
    if (t < 4) {
        float ws = wsred[0][t] + wsred[1][t] + wsred[2][t] + wsred[3][t];
        fin[t] = 1.f / (ws + 1e-16f);
    }
    __syncthreads();
    int c = t, q = c & 7, l = c >> 3;
    float o = (red[0][q][l] + red[1][q][l] + red[2][q][l] + red[3][q][l]) * fin[c >> 6];
    // fused bias + LN + residual relu
    float tt = o + bias[c];
    float m = blk_sum256(tt, sm4) * (1.f / DD);
    float d = tt - m;
    float var = blk_sum256(d * d, sm4) * (1.f / DD);
    float y = d * rsqrtf(var + 1e-5f) * g[c] + bt[c];
    float r = fmaxf(y + hin[(size_t)v * DD + c], 0.f);
    hout[(size_t)v * DD + c] = r;
    hbout[(size_t)v * DD + c] = f2bf(r);
}

// ---------- virtual-node partial aggregation (deterministic, no atomics) ----------
__global__ void k_vacc(const int* __restrict__ offs, const unsigned short* __restrict__ edotL,
                       const float* __restrict__ als, const float* __restrict__ ald,
                       const unsigned short* __restrict__ xsb,
                       float* __restrict__ pvacc, float* __restrict__ pws) {
    int b = blockIdx.x, j = threadIdx.x, hh = j >> 6;
    int b0 = offs[NN];
    float adh = ald[NN * 4 + hh];
    int i0 = b * 157, i1 = i0 + 157;
    if (i1 > NN + 1) i1 = NN + 1;
    float acc = 0.f, swt = 0.f;
    for (int i = i0; i < i1; i++) {
        float a = als[i * 4 + hh] + bf2f(edotL[(size_t)(b0 + i) * 4 + hh]) + adh;
        a = a > 0.f ? a : 0.2f * a;
        float wt = __expf(a);
        acc += wt * bf2f(xsb[(size_t)i * DD + j]);
        if ((j & 63) == 0) swt += wt;
    }
    pvacc[b * DD + j] = acc;
    if ((j & 63) == 0) pws[b * 4 + hh] = swt;
}

// ---------- virtual-node normalize + LN + residual ----------
__global__ void k_vpost(const float* __restrict__ pvacc, const float* __restrict__ pws,
                        const float* __restrict__ bias, const float* __restrict__ g,
                        const float* __restrict__ bt, const float* __restrict__ hin,
                        float* __restrict__ hout, unsigned short* __restrict__ hb,
                        float* __restrict__ jkslot) {
    __shared__ float sm4[4];
    int j = threadIdx.x, hh = j >> 6;
    float acc = 0.f;
    for (int b = 0; b < 64; b++) acc += pvacc[b * DD + j];
    float ws = 0.f;
    for (int b = 0; b < 64; b++) ws += pws[b * 4 + hh];
    float o = acc / (ws + 1e-16f);
    float tt = o + bias[j];
    float m = blk_sum256(tt, sm4) * (1.f / DD);
    float d = tt - m;
    float var = blk_sum256(d * d, sm4) * (1.f / DD);
    float y = d * rsqrtf(var + 1e-5f) * g[j] + bt[j];
    float r = fmaxf(y + hin[(size_t)NN * DD + j], 0.f);
    hout[(size_t)NN * DD + j] = r;
    hb[(size_t)NN * DD + j] = f2bf(r);
    jkslot[j] = r;
}

// ---------- agent encoder ----------
__global__ void k_agent(const float* __restrict__ af, const float* __restrict__ w,
                        const float* __restrict__ b, const float* __restrict__ g,
                        const float* __restrict__ bt, float* __restrict__ comb) {
    __shared__ float sm4[4];
    __shared__ float xr[10];
    int j = threadIdx.x;
    if (j < 10) xr[j] = af[j];
    __syncthreads();
    float acc = b[j];
#pragma unroll
    for (int k = 0; k < 10; k++) acc += xr[k] * w[k * DD + j];
    float m = blk_sum256(acc, sm4) * (1.f / DD);
    float d = acc - m;
    float var = blk_sum256(d * d, sm4) * (1.f / DD);
    float y = d * rsqrtf(var + 1e-5f) * g[j] + bt[j];
    comb[1024 + j] = fmaxf(y, 0.f);
}

// ---------- dueling head, stage 1: 40-way k-sliced partial GEMMs ----------
__global__ void k_head1(const float* __restrict__ comb,
                        const float* __restrict__ vw1, const float* __restrict__ aw1,
                        float* __restrict__ pv, float* __restrict__ pa) {
    int j = threadIdx.x, s = blockIdx.x;
    int k0 = s * 32;
    float accv = 0.f, acca = 0.f;
#pragma unroll
    for (int kk = 0; kk < 32; kk++) {
        float c = comb[k0 + kk];
        accv += c * vw1[(k0 + kk) * DD + j];
        acca += c * aw1[(k0 + kk) * DD + j];
    }
    pv[s * DD + j] = accv;
    pa[s * DD + j] = acca;
}

// ---------- dueling head, stage 2 ----------
__global__ void k_head2(const float* __restrict__ pv, const float* __restrict__ pa,
                        const float* __restrict__ vb1, const float* __restrict__ vg,
                        const float* __restrict__ vbt, const float* __restrict__ vw2,
                        const float* __restrict__ vb2,
                        const float* __restrict__ ab1, const float* __restrict__ ag,
                        const float* __restrict__ abt, const float* __restrict__ aw2,
                        const float* __restrict__ ab2, float* __restrict__ out) {
    __shared__ float sm4[4];
    __shared__ float tl[DD];
    __shared__ float adv[9];
    __shared__ float valv;
    int j = threadIdx.x;
    float acc = vb1[j], acc2 = ab1[j];
    for (int s = 0; s < 40; s++) { acc += pv[s * DD + j]; acc2 += pa[s * DD + j]; }
    float m = blk_sum256(acc, sm4) * (1.f / DD);
    float d = acc - m;
    float var = blk_sum256(d * d, sm4) * (1.f / DD);
    float y = fmaxf(d * rsqrtf(var + 1e-5f) * vg[j] + vbt[j], 0.f);
    float vs = blk_sum256(y * vw2[j], sm4);
    if (j == 0) valv = vs + vb2[0];
    float m2 = blk_sum256(acc2, sm4) * (1.f / DD);
    float d2 = acc2 - m2;
    float var2 = blk_sum256(d2 * d2, sm4) * (1.f / DD);
    float y2 = fmaxf(d2 * rsqrtf(var2 + 1e-5f) * ag[j] + abt[j], 0.f);
    tl[j] = y2;
    __syncthreads();
    if (j < 9) {
        float s = ab2[j];
        for (int k = 0; k < DD; k++) s += tl[k] * aw2[k * 9 + j];
        adv[j] = s;
    }
    __syncthreads();
    if (j < 9) {
        float mean = 0.f;
        for (int o = 0; o < 9; o++) mean += adv[o];
        mean *= (1.f / 9.f);
        out[j] = valv + adv[j] - mean;
    }
}

extern "C" void kernel_launch(void* const* d_in, const int* in_sizes, int n_in,
                              void* d_out, int out_size, void* d_ws, size_t ws_size,
                              hipStream_t stream) {
    (void)in_sizes; (void)n_in; (void)out_size; (void)ws_size;
    const float* x      = (const float*)d_in[0];
    const int*   ei     = (const int*)d_in[1];
    const float* ea     = (const float*)d_in[2];
    const float* af     = (const float*)d_in[3];
    const float* enc_w  = (const float*)d_in[4];
    const float* enc_b  = (const float*)d_in[5];
    const float* enc_g  = (const float*)d_in[6];
    const float* enc_bt = (const float*)d_in[7];
    const float* vn_base= (const float*)d_in[8];
    const float* vn_w1  = (const float*)d_in[9];
    const float* vn_b1  = (const float*)d_in[10];
    const float* vn_g   = (const float*)d_in[11];
    const float* vn_bt  = (const float*)d_in[12];
    const float* vn_w2  = (const float*)d_in[13];
    const float* vn_b2  = (const float*)d_in[14];
    const float* gat_w  = (const float*)d_in[15];
    const float* att_src= (const float*)d_in[16];
    const float* att_dst= (const float*)d_in[17];
    const float* att_edge=(const float*)d_in[18];
    const float* edge_w = (const float*)d_in[19];
    const float* gat_b  = (const float*)d_in[20];
    const float* ln_g   = (const float*)d_in[21];
    const float* ln_b   = (const float*)d_in[22];
    const float* ag_w   = (const float*)d_in[23];
    const float* ag_b   = (const float*)d_in[24];
    const float* ag_g   = (const float*)d_in[25];
    const float* ag_bt  = (const float*)d_in[26];
    const float* v_w1   = (const float*)d_in[27];
    const float* v_b1   = (const float*)d_in[28];
    const float* v_g    = (const float*)d_in[29];
    const float* v_bt   = (const float*)d_in[30];
    const float* v_w2   = (const float*)d_in[31];
    const float* v_b2   = (const float*)d_in[32];
    const float* a_w1   = (const float*)d_in[33];
    const float* a_b1   = (const float*)d_in[34];
    const float* a_g    = (const float*)d_in[35];
    const float* a_bt   = (const float*)d_in[36];
    const float* a_w2   = (const float*)d_in[37];
    const float* a_b2   = (const float*)d_in[38];

    char* p = (char*)d_ws;
    auto alloc = [&](size_t bytes) {
        char* r = p;
        p += (bytes + 255) & ~(size_t)255;
        return r;
    };
    float* big0  = (float*)alloc((size_t)NT * DD * 4);
    float* big2  = (float*)alloc((size_t)NT * DD * 4);
    unsigned short* hb   = (unsigned short*)alloc((size_t)NT * DD * 2);
    unsigned short* xsb  = (unsigned short*)alloc((size_t)NT * DD * 2);
    unsigned short* wt   = (unsigned short*)alloc((size_t)3 * DD * DD * 2);
    unsigned short* edot = (unsigned short*)alloc((size_t)3 * ETC * 4 * 2);
    int2*  sp    = (int2*) alloc((size_t)ETC * 8);
    float* als   = (float*)alloc((size_t)NT * 4 * 4);
    float* ald   = (float*)alloc((size_t)NT * 4 * 4);
    float* ctx   = (float*)alloc(DD * 4);
    float* comb  = (float*)alloc(1280 * 4);
    float* lattr = (float*)alloc((size_t)NT * 3 * 4);
    float* wd    = (float*)alloc(36 * 4);
    float* pvacc = (float*)alloc((size_t)64 * DD * 4);
    float* pws   = (float*)alloc((size_t)64 * 4 * 4);
    float* pv    = (float*)alloc(40 * DD * 4);
    float* pa    = (float*)alloc(40 * DD * 4);
    int* degi    = (int*)alloc((size_t)NT * 4);
    int* offs    = (int*)alloc((size_t)(NT + 1) * 4);
    int* cursor  = (int*)alloc((size_t)NT * 4);

    hipMemsetAsync(ctx, 0, DD * 4, stream);
    hipMemsetAsync(degi, 0, (size_t)NT * 4, stream);

    k_enc<<<NN, 256, 0, stream>>>(x, enc_w, enc_b, enc_g, enc_bt, big0, hb);
    k_ctx<<<64, 256, 0, stream>>>(big0, ctx);
    k_vn<<<1, 256, 0, stream>>>(ctx, vn_w1, vn_b1, vn_g, vn_bt, vn_w2, vn_b2, vn_base, big0, hb, comb);
    k_deg<<<(EE + 255) / 256, 256, 0, stream>>>(ei, degi);
    k_scan<<<1, 1024, 0, stream>>>(degi, offs, cursor);
    k_scatter<<<(EE + 255) / 256, 256, 0, stream>>>(ei, cursor, sp);
    k_flattr<<<(NT + 3) / 4, 256, 0, stream>>>(offs, sp, ea, lattr);
    k_wedot<<<1, 64, 0, stream>>>(edge_w, att_edge, wd);
    k_edot<<<(ETC + 255) / 256, 256, 0, stream>>>(sp, ea, lattr, wd, edot);
    k_wconv<<<768, 256, 0, stream>>>(gat_w, wt);

    float* cur = big0;
    float* po  = big2;
    for (int l = 0; l < 3; l++) {
        const unsigned short* edotL = edot + (size_t)l * ETC * 4;
        k_gemm_mfma<<<(NT + 63) / 64, 256, 0, stream>>>(hb, wt + (size_t)l * DD * DD,
                                                        att_src + l * DD, att_dst + l * DD,
                                                        xsb, als, ald);
        k_msg<<<NT, 256, 0, stream>>>(offs, sp, edotL, als, ald, xsb,
                                      gat_b + l * DD, ln_g + l * DD, ln_b + l * DD,
                                      cur, po, hb);
        k_vacc<<<64, 256, 0, stream>>>(offs, edotL, als, ald, xsb, pvacc, pws);
        k_vpost<<<1, 256, 0, stream>>>(pvacc, pws, gat_b + l * DD, ln_g + l * DD, ln_b + l * DD,
                                       cur, po, hb, comb + (l + 1) * DD);
        float* t = cur; cur = po; po = t;
    }
    k_agent<<<1, 256, 0, stream>>>(af, ag_w, ag_b, ag_g, ag_bt, comb);
    k_head1<<<40, 256, 0, stream>>>(comb, v_w1, a_w1, pv, pa);
    k_head2<<<1, 256, 0, stream>>>(pv, pa, v_b1, v_g, v_bt, v_w2, v_b2,
                                   a_b1, a_g, a_bt, a_w2, a_b2, (float*)d_out);
}

// Round 5
// 453.340 us; speedup vs baseline: 2.6955x; 1.1117x over previous
//
#include <hip/hip_runtime.h>
#include <math.h>

#define NN 10000
#define EE 320000
#define DD 256
#define NT 10001            // NN + virtual node
#define E1C (EE + NN)       // 330000
#define E2C (EE + 2 * NN)   // 340000
#define ETC (E2C + NT)      // 350001 (with self loops)
#define VB 157              // virtual-node partial blocks (64 rows each)

typedef __attribute__((ext_vector_type(8))) short s16x8;
typedef __attribute__((ext_vector_type(4))) float f32x4;

__device__ __forceinline__ unsigned short f2bf(float f) {
    unsigned u = __float_as_uint(f);
    return (unsigned short)((u + 0x7FFFu + ((u >> 16) & 1u)) >> 16);
}
__device__ __forceinline__ float bf2f(unsigned short u) {
    return __uint_as_float((unsigned)u << 16);
}

// ---------- reduction helpers (blockDim.x == 256 assumed) ----------
__device__ __forceinline__ float wave_sum(float v) {
#pragma unroll
    for (int o = 32; o > 0; o >>= 1) v += __shfl_down(v, o, 64);
    return v;
}
__device__ __forceinline__ float blk_sum256(float v, float* sm4) {
    v = wave_sum(v);
    int lane = threadIdx.x & 63, w = threadIdx.x >> 6;
    __syncthreads();
    if (lane == 0) sm4[w] = v;
    __syncthreads();
    return sm4[0] + sm4[1] + sm4[2] + sm4[3];
}

// ---------- node encoder: h0 = relu(LN(x @ enc_w + enc_b)) ----------
__global__ void k_enc(const float* __restrict__ x, const float* __restrict__ w,
                      const float* __restrict__ b, const float* __restrict__ g,
                      const float* __restrict__ bt, float* __restrict__ h,
                      unsigned short* __restrict__ hb) {
    __shared__ float sm4[4];
    __shared__ float xr[10];
    int v = blockIdx.x, j = threadIdx.x;
    if (j < 10) xr[j] = x[v * 10 + j];
    __syncthreads();
    float acc = b[j];
#pragma unroll
    for (int k = 0; k < 10; k++) acc += xr[k] * w[k * DD + j];
    float m = blk_sum256(acc, sm4) * (1.f / DD);
    float d = acc - m;
    float var = blk_sum256(d * d, sm4) * (1.f / DD);
    float y = d * rsqrtf(var + 1e-5f) * g[j] + bt[j];
    float r = fmaxf(y, 0.f);
    h[v * DD + j] = r;
    hb[v * DD + j] = f2bf(r);
}

// ---------- column sums of h0 for ctx ----------
__global__ void k_ctx(const float* __restrict__ h, float* __restrict__ ctx) {
    int c = threadIdx.x;
    float acc = 0.f;
    for (int v = blockIdx.x; v < NN; v += gridDim.x) acc += h[v * DD + c];
    atomicAdd(&ctx[c], acc);
}

// ---------- adaptive virtual node ----------
__global__ void k_vn(const float* __restrict__ ctx,
                     const float* __restrict__ w1, const float* __restrict__ b1,
                     const float* __restrict__ g, const float* __restrict__ bt,
                     const float* __restrict__ w2, const float* __restrict__ b2,
                     const float* __restrict__ vnb,
                     float* __restrict__ h, unsigned short* __restrict__ hb,
                     float* __restrict__ comb) {
    __shared__ float sm4[4];
    __shared__ float cs[DD];
    __shared__ float t[DD];
    int j = threadIdx.x;
    cs[j] = ctx[j] * (1.f / NN);
    __syncthreads();
    float acc = b1[j];
    for (int k = 0; k < DD; k++) acc += cs[k] * w1[k * DD + j];
    float m = blk_sum256(acc, sm4) * (1.f / DD);
    float d = acc - m;
    float var = blk_sum256(d * d, sm4) * (1.f / DD);
    float y = fmaxf(d * rsqrtf(var + 1e-5f) * g[j] + bt[j], 0.f);
    t[j] = y;
    __syncthreads();
    float a2 = b2[j];
    for (int k = 0; k < DD; k++) a2 += t[k] * w2[k * DD + j];
    float vn = vnb[j] + tanhf(a2);
    h[NN * DD + j] = vn;
    hb[NN * DD + j] = f2bf(vn);
    comb[j] = vn;   // jk slot 0 (virtual row of initial h)
}

// ---------- regular-edge in-degree histogram (1 atomic per edge) ----------
__global__ void k_deg(const int* __restrict__ ei, int* __restrict__ degi) {
    int e = blockIdx.x * 256 + threadIdx.x;
    if (e >= EE) return;
    atomicAdd(&degi[ei[EE + e]], 1);
}

// ---------- 1024-wide exclusive scan of (degR + virtual/self additions) ----------
__global__ void k_scan(const int* __restrict__ degi, int* __restrict__ offs,
                       int* __restrict__ cursor) {
    __shared__ int wsum[16];
    __shared__ int running_s;
    int t = threadIdx.x, lane = t & 63, w = t >> 6;
    if (t == 0) running_s = 0;
    __syncthreads();
    for (int base = 0; base < NT; base += 1024) {
        int v = base + t;
        int val = 0;
        if (v < NN) val = degi[v] + 2;          // + vn-edge + self-loop
        else if (v == NN) val = NN + 1;         // virtual: NN in-edges + self-loop
        int x = val;
#pragma unroll
        for (int o = 1; o < 64; o <<= 1) {
            int y = __shfl_up(x, o, 64);
            if (lane >= o) x += y;
        }
        if (lane == 63) wsum[w] = x;
        __syncthreads();
        int prefix = running_s;
        for (int ww = 0; ww < w; ww++) prefix += wsum[ww];
        if (v <= NN) { int e0 = prefix + x - val; offs[v] = e0; cursor[v] = e0; }
        __syncthreads();
        if (t == 0) {
            int s = 0;
            for (int i = 0; i < 16; i++) s += wsum[i];
            running_s += s;
        }
        __syncthreads();
    }
    if (threadIdx.x == 0) offs[NT] = running_s;
}

// ---------- scatter regular edges into CSR (packed {src, eid}) ----------
__global__ void k_scatter(const int* __restrict__ ei, int* __restrict__ cursor,
                          int2* __restrict__ sp) {
    int e = blockIdx.x * 256 + threadIdx.x;
    if (e >= EE) return;
    int src = ei[e], dst = ei[EE + e];
    int pos = atomicAdd(&cursor[dst], 1);
    sp[pos] = make_int2(src, e);
}

// ---------- fused: fill deterministic CSR slots + loop_attr segmented sums ----------
__global__ void k_flattr(const int* __restrict__ offs, int2* __restrict__ sp,
                         const float* __restrict__ ea, float* __restrict__ lattr) {
    int t = threadIdx.x, lane = t & 63, w = t >> 6;
    int v = blockIdx.x * 4 + w;
    if (v > NN) return;
    int bN = offs[NN];
    if (v == NN) {
        if (lane == 0) {
            lattr[v * 3] = 0.5f; lattr[v * 3 + 1] = 0.f; lattr[v * 3 + 2] = 0.f;
            sp[bN + NN] = make_int2(NN, E2C + NN);   // virtual self loop
        }
        return;
    }
    int b0 = offs[v], e1 = offs[v + 1];
    if (lane == 0) {
        sp[e1 - 2] = make_int2(NN, EE + v);      // vn -> v
        sp[e1 - 1] = make_int2(v, E2C + v);      // self loop
        sp[bN + v] = make_int2(v, E1C + v);      // v -> vn (virtual segment)
    }
    int cnt = e1 - b0 - 2;                       // regular in-edges
    float s0 = 0.f, s1 = 0.f, s2 = 0.f;
    for (int i = lane; i < cnt; i += 64) {
        int e = sp[b0 + i].y;
        s0 += ea[e * 3];
        s1 += ea[e * 3 + 1];
        s2 += ea[e * 3 + 2];
    }
    s0 = wave_sum(s0); s1 = wave_sum(s1); s2 = wave_sum(s2);
    if (lane == 0) {
        float inv = 1.f / (float)(cnt + 1);      // deg0 = regular + vn edge
        lattr[v * 3]     = (s0 + 0.5f) * inv;
        lattr[v * 3 + 1] = s1 * inv;
        lattr[v * 3 + 2] = s2 * inv;
    }
}

// ---------- we_dot[l][k][h] = sum_c e_w[l,k,h*64+c] * att_edge[l,h,c] ----------
__global__ void k_wedot(const float* __restrict__ ew, const float* __restrict__ ae,
                        float* __restrict__ wd) {
    int t = threadIdx.x;
    if (t >= 36) return;
    int l = t / 12, k = (t / 4) % 3, h = t % 4;
    float s = 0.f;
    for (int c = 0; c < 64; c++)
        s += ew[l * 768 + k * DD + h * 64 + c] * ae[l * DD + h * 64 + c];
    wd[t] = s;   // layout [l][k][h]
}

// ---------- per-edge, per-layer, per-head edge-attr dots, bf16 packed ----------
__global__ void k_edot(const int2* __restrict__ sp, const float* __restrict__ ea,
                       const float* __restrict__ lattr, const float* __restrict__ wd,
                       unsigned short* __restrict__ edot) {
    int p = blockIdx.x * 256 + threadIdx.x;
    if (p >= ETC) return;
    int e = sp[p].y;
    float a0, a1, a2;
    if (e < EE)       { a0 = ea[e * 3]; a1 = ea[e * 3 + 1]; a2 = ea[e * 3 + 2]; }
    else if (e < E2C) { a0 = 0.5f; a1 = 0.f; a2 = 0.f; }
    else              { int v = e - E2C; a0 = lattr[v * 3]; a1 = lattr[v * 3 + 1]; a2 = lattr[v * 3 + 2]; }
#pragma unroll
    for (int l = 0; l < 3; l++) {
        ushort4 o;
        o.x = f2bf(a0 * wd[l * 12 + 0] + a1 * wd[l * 12 + 4] + a2 * wd[l * 12 + 8]);
        o.y = f2bf(a0 * wd[l * 12 + 1] + a1 * wd[l * 12 + 5] + a2 * wd[l * 12 + 9]);
        o.z = f2bf(a0 * wd[l * 12 + 2] + a1 * wd[l * 12 + 6] + a2 * wd[l * 12 + 10]);
        o.w = f2bf(a0 * wd[l * 12 + 3] + a1 * wd[l * 12 + 7] + a2 * wd[l * 12 + 11]);
        *(ushort4*)(edot + (size_t)l * ETC * 4 + (size_t)p * 4) = o;
    }
}

// ---------- transpose gat_w to bf16 Wt[l][n][k] ----------
__global__ void k_wconv(const float* __restrict__ gw, unsigned short* __restrict__ wt) {
    int b = blockIdx.x;
    int l = b >> 8, k = b & 255, j = threadIdx.x;
    float v = gw[l * 65536 + k * 256 + j];
    wt[l * 65536 + j * 256 + k] = f2bf(v);
}

// ---------- xs = h @ W via bf16 MFMA (64 rows/block, 4 waves x 16 rows) ----------
__global__ void __launch_bounds__(256) k_gemm_mfma(
        const unsigned short* __restrict__ hb, const unsigned short* __restrict__ wt,
        const float* __restrict__ as_, const float* __restrict__ ad_,
        unsigned short* __restrict__ xsb, float* __restrict__ als, float* __restrict__ ald) {
    __shared__ unsigned short tile[64][256];
    int t = threadIdx.x, lane = t & 63, w = t >> 6;
    int v0 = blockIdx.x * 64;
    int rbase = v0 + w * 16;
    int li = lane & 15, g = lane >> 4;
    int arow = rbase + li; if (arow > NN) arow = NN;
    int koff = g * 8;
    const unsigned short* aptr = hb + (size_t)arow * DD + koff;
    const unsigned short* bptr = wt + (size_t)li * DD + koff;
    f32x4 acc[16];
#pragma unroll
    for (int n = 0; n < 16; n++) acc[n] = (f32x4){0.f, 0.f, 0.f, 0.f};
#pragma unroll
    for (int kb = 0; kb < 8; kb++) {
        s16x8 af = *(const s16x8*)(aptr + kb * 32);
#pragma unroll
        for (int n = 0; n < 16; n++) {
            s16x8 bf = *(const s16x8*)(bptr + (size_t)n * 16 * DD + kb * 32);
            acc[n] = __builtin_amdgcn_mfma_f32_16x16x32_bf16(af, bf, acc[n], 0, 0, 0);
        }
    }
    float asv[16], adv[16];
#pragma unroll
    for (int n = 0; n < 16; n++) { asv[n] = as_[n * 16 + li]; adv[n] = ad_[n * 16 + li]; }
#pragma unroll
    for (int r = 0; r < 4; r++) {
        int vrow = rbase + 4 * g + r;
#pragma unroll
        for (int h = 0; h < 4; h++) {
            float ps = acc[4 * h][r] * asv[4 * h] + acc[4 * h + 1][r] * asv[4 * h + 1]
                     + acc[4 * h + 2][r] * asv[4 * h + 2] + acc[4 * h + 3][r] * asv[4 * h + 3];
            float pd = acc[4 * h][r] * adv[4 * h] + acc[4 * h + 1][r] * adv[4 * h + 1]
                     + acc[4 * h + 2][r] * adv[4 * h + 2] + acc[4 * h + 3][r] * adv[4 * h + 3];
#pragma unroll
            for (int o = 1; o < 16; o <<= 1) {
                ps += __shfl_xor(ps, o, 64);
                pd += __shfl_xor(pd, o, 64);
            }
            if (li == 0 && vrow <= NN) { als[vrow * 4 + h] = ps; ald[vrow * 4 + h] = pd; }
        }
    }
#pragma unroll
    for (int n = 0; n < 16; n++)
#pragma unroll
        for (int r = 0; r < 4; r++)
            tile[w * 16 + 4 * g + r][n * 16 + li] = f2bf(acc[n][r]);
#pragma unroll
    for (int it = 0; it < 8; it++) {
        int flat = it * 64 + lane;
        int row = w * 16 + (flat >> 5);
        int c8 = flat & 31;
        int vrow = v0 + row;
        if (vrow <= NN)
            *(uint4*)(xsb + (size_t)vrow * DD + c8 * 8) = *(const uint4*)(&tile[row][c8 * 8]);
    }
}

// ---------- single-pass softmax-aggregation + fused LN/residual epilogue ----------
__global__ void __launch_bounds__(256) k_msg(
        const int* __restrict__ offs, const int2* __restrict__ sp,
        const unsigned short* __restrict__ edotL,
        const float* __restrict__ als, const float* __restrict__ ald,
        const unsigned short* __restrict__ xsb,
        const float* __restrict__ bias, const float* __restrict__ g,
        const float* __restrict__ bt, const float* __restrict__ hin,
        float* __restrict__ hout, unsigned short* __restrict__ hbout) {
    int v = blockIdx.x;
    if (v == NN) return;                         // virtual dst: k_vacc/k_vpost
    int t = threadIdx.x, lane = t & 63, w = t >> 6;
    int sub = lane >> 5, l32 = lane & 31, slot = w * 2 + sub;
    int hh = l32 >> 3;
    __shared__ float red[4][8][33];
    __shared__ float wsred[4][4];
    __shared__ float fin[4];
    __shared__ float sm4[4];
    int b0 = offs[v], deg = offs[v + 1] - b0;
    float adh = ald[v * 4 + hh];
    float acc[8];
#pragma unroll
    for (int q = 0; q < 8; q++) acc[q] = 0.f;
    float swt = 0.f;
    for (int i = slot; i < deg; i += 8) {
        int p = b0 + i;
        int src = sp[p].x;
        float a = als[src * 4 + hh] + bf2f(edotL[(size_t)p * 4 + hh]) + adh;
        a = a > 0.f ? a : 0.2f * a;
        float wt = __expf(a);
        uint4 xq = *(const uint4*)(xsb + (size_t)src * DD + l32 * 8);
        const unsigned short* xp = (const unsigned short*)&xq;
#pragma unroll
        for (int q = 0; q < 8; q++) acc[q] += wt * bf2f(xp[q]);
        if ((l32 & 7) == 0) swt += wt;
    }
#pragma unroll
    for (int q = 0; q < 8; q++) acc[q] += __shfl_xor(acc[q], 32, 64);
    swt += __shfl_xor(swt, 32, 64);
    if (sub == 0) {
#pragma unroll
        for (int q = 0; q < 8; q++) red[w][q][l32] = acc[q];   // conflict-free
        if ((l32 & 7) == 0) wsred[w][hh] = swt;
    }
    __syncthreads();
    if (t < 4) {
        float ws = wsred[0][t] + wsred[1][t] + wsred[2][t] + wsred[3][t];
        fin[t] = 1.f / (ws + 1e-16f);
    }
    __syncthreads();
    int c = t, q = c & 7, l = c >> 3;
    float o = (red[0][q][l] + red[1][q][l] + red[2][q][l] + red[3][q][l]) * fin[c >> 6];
    float tt = o + bias[c];
    float m = blk_sum256(tt, sm4) * (1.f / DD);
    float d = tt - m;
    float var = blk_sum256(d * d, sm4) * (1.f / DD);
    float y = d * rsqrtf(var + 1e-5f) * g[c] + bt[c];
    float r = fmaxf(y + hin[(size_t)v * DD + c], 0.f);
    hout[(size_t)v * DD + c] = r;
    hbout[(size_t)v * DD + c] = f2bf(r);
}

// ---------- virtual-node partial aggregation: 157 blocks x 64 rows, 8 slots ----------
__global__ void __launch_bounds__(256) k_vacc(
        const int* __restrict__ offs, const unsigned short* __restrict__ edotL,
        const float* __restrict__ als, const float* __restrict__ ald,
        const unsigned short* __restrict__ xsb,
        float* __restrict__ pvacc, float* __restrict__ pws) {
    int b = blockIdx.x, t = threadIdx.x, lane = t & 63, w = t >> 6;
    int sub = lane >> 5, l32 = lane & 31, slot = w * 2 + sub;
    int hh = l32 >> 3;
    __shared__ float red[4][8][33];
    __shared__ float wsred[4][4];
    int b0 = offs[NN];
    float adh = ald[NN * 4 + hh];
    int i0 = b * 64, i1 = i0 + 64;
    if (i1 > NN + 1) i1 = NN + 1;
    float acc[8];
#pragma unroll
    for (int q = 0; q < 8; q++) acc[q] = 0.f;
    float swt = 0.f;
    for (int i = i0 + slot; i < i1; i += 8) {
        // virtual segment entry i has src == i (self loop entry i==NN also)
        float a = als[i * 4 + hh] + bf2f(edotL[(size_t)(b0 + i) * 4 + hh]) + adh;
        a = a > 0.f ? a : 0.2f * a;
        float wt = __expf(a);
        uint4 xq = *(const uint4*)(xsb + (size_t)i * DD + l32 * 8);
        const unsigned short* xp = (const unsigned short*)&xq;
#pragma unroll
        for (int q = 0; q < 8; q++) acc[q] += wt * bf2f(xp[q]);
        if ((l32 & 7) == 0) swt += wt;
    }
#pragma unroll
    for (int q = 0; q < 8; q++) acc[q] += __shfl_xor(acc[q], 32, 64);
    swt += __shfl_xor(swt, 32, 64);
    if (sub == 0) {
#pragma unroll
        for (int q = 0; q < 8; q++) red[w][q][l32] = acc[q];
        if ((l32 & 7) == 0) wsred[w][hh] = swt;
    }
    __syncthreads();
    int c = t, q = c & 7, l = c >> 3;
    pvacc[(size_t)b * DD + c] = red[0][q][l] + red[1][q][l] + red[2][q][l] + red[3][q][l];
    if (t < 4) pws[b * 4 + t] = wsred[0][t] + wsred[1][t] + wsred[2][t] + wsred[3][t];
}

// ---------- virtual-node normalize + LN + residual ----------
__global__ void k_vpost(const float* __restrict__ pvacc, const float* __restrict__ pws,
                        const float* __restrict__ bias, const float* __restrict__ g,
                        const float* __restrict__ bt, const float* __restrict__ hin,
                        float* __restrict__ hout, unsigned short* __restrict__ hb,
                        float* __restrict__ jkslot) {
    __shared__ float sm4[4];
    int j = threadIdx.x, hh = j >> 6;
    float acc = 0.f;
    for (int b = 0; b < VB; b++) acc += pvacc[(size_t)b * DD + j];
    float ws = 0.f;
    for (int b = 0; b < VB; b++) ws += pws[b * 4 + hh];
    float o = acc / (ws + 1e-16f);
    float tt = o + bias[j];
    float m = blk_sum256(tt, sm4) * (1.f / DD);
    float d = tt - m;
    float var = blk_sum256(d * d, sm4) * (1.f / DD);
    float y = d * rsqrtf(var + 1e-5f) * g[j] + bt[j];
    float r = fmaxf(y + hin[(size_t)NN * DD + j], 0.f);
    hout[(size_t)NN * DD + j] = r;
    hb[(size_t)NN * DD + j] = f2bf(r);
    jkslot[j] = r;
}

// ---------- agent encoder ----------
__global__ void k_agent(const float* __restrict__ af, const float* __restrict__ w,
                        const float* __restrict__ b, const float* __restrict__ g,
                        const float* __restrict__ bt, float* __restrict__ comb) {
    __shared__ float sm4[4];
    __shared__ float xr[10];
    int j = threadIdx.x;
    if (j < 10) xr[j] = af[j];
    __syncthreads();
    float acc = b[j];
#pragma unroll
    for (int k = 0; k < 10; k++) acc += xr[k] * w[k * DD + j];
    float m = blk_sum256(acc, sm4) * (1.f / DD);
    float d = acc - m;
    float var = blk_sum256(d * d, sm4) * (1.f / DD);
    float y = d * rsqrtf(var + 1e-5f) * g[j] + bt[j];
    comb[1024 + j] = fmaxf(y, 0.f);
}

// ---------- dueling head, stage 1: 40-way k-sliced partial GEMMs ----------
__global__ void k_head1(const float* __restrict__ comb,
                        const float* __restrict__ vw1, const float* __restrict__ aw1,
                        float* __restrict__ pv, float* __restrict__ pa) {
    int j = threadIdx.x, s = blockIdx.x;
    int k0 = s * 32;
    float accv = 0.f, acca = 0.f;
#pragma unroll
    for (int kk = 0; kk < 32; kk++) {
        float c = comb[k0 + kk];
        accv += c * vw1[(k0 + kk) * DD + j];
        acca += c * aw1[(k0 + kk) * DD + j];
    }
    pv[s * DD + j] = accv;
    pa[s * DD + j] = acca;
}

// ---------- dueling head, stage 2 ----------
__global__ void k_head2(const float* __restrict__ pv, const float* __restrict__ pa,
                        const float* __restrict__ vb1, const float* __restrict__ vg,
                        const float* __restrict__ vbt, const float* __restrict__ vw2,
                        const float* __restrict__ vb2,
                        const float* __restrict__ ab1, const float* __restrict__ ag,
                        const float* __restrict__ abt, const float* __restrict__ aw2,
                        const float* __restrict__ ab2, float* __restrict__ out) {
    __shared__ float sm4[4];
    __shared__ float tl[DD];
    __shared__ float adv[9];
    __shared__ float valv;
    int j = threadIdx.x;
    float acc = vb1[j], acc2 = ab1[j];
    for (int s = 0; s < 40; s++) { acc += pv[s * DD + j]; acc2 += pa[s * DD + j]; }
    float m = blk_sum256(acc, sm4) * (1.f / DD);
    float d = acc - m;
    float var = blk_sum256(d * d, sm4) * (1.f / DD);
    float y = fmaxf(d * rsqrtf(var + 1e-5f) * vg[j] + vbt[j], 0.f);
    float vs = blk_sum256(y * vw2[j], sm4);
    if (j == 0) valv = vs + vb2[0];
    float m2 = blk_sum256(acc2, sm4) * (1.f / DD);
    float d2 = acc2 - m2;
    float var2 = blk_sum256(d2 * d2, sm4) * (1.f / DD);
    float y2 = fmaxf(d2 * rsqrtf(var2 + 1e-5f) * ag[j] + abt[j], 0.f);
    tl[j] = y2;
    __syncthreads();
    if (j < 9) {
        float s = ab2[j];
        for (int k = 0; k < DD; k++) s += tl[k] * aw2[k * 9 + j];
        adv[j] = s;
    }
    __syncthreads();
    if (j < 9) {
        float mean = 0.f;
        for (int o = 0; o < 9; o++) mean += adv[o];
        mean *= (1.f / 9.f);
        out[j] = valv + adv[j] - mean;
    }
}

extern "C" void kernel_launch(void* const* d_in, const int* in_sizes, int n_in,
                              void* d_out, int out_size, void* d_ws, size_t ws_size,
                              hipStream_t stream) {
    (void)in_sizes; (void)n_in; (void)out_size; (void)ws_size;
    const float* x      = (const float*)d_in[0];
    const int*   ei     = (const int*)d_in[1];
    const float* ea     = (const float*)d_in[2];
    const float* af     = (const float*)d_in[3];
    const float* enc_w  = (const float*)d_in[4];
    const float* enc_b  = (const float*)d_in[5];
    const float* enc_g  = (const float*)d_in[6];
    const float* enc_bt = (const float*)d_in[7];
    const float* vn_base= (const float*)d_in[8];
    const float* vn_w1  = (const float*)d_in[9];
    const float* vn_b1  = (const float*)d_in[10];
    const float* vn_g   = (const float*)d_in[11];
    const float* vn_bt  = (const float*)d_in[12];
    const float* vn_w2  = (const float*)d_in[13];
    const float* vn_b2  = (const float*)d_in[14];
    const float* gat_w  = (const float*)d_in[15];
    const float* att_src= (const float*)d_in[16];
    const float* att_dst= (const float*)d_in[17];
    const float* att_edge=(const float*)d_in[18];
    const float* edge_w = (const float*)d_in[19];
    const float* gat_b  = (const float*)d_in[20];
    const float* ln_g   = (const float*)d_in[21];
    const float* ln_b   = (const float*)d_in[22];
    const float* ag_w   = (const float*)d_in[23];
    const float* ag_b   = (const float*)d_in[24];
    const float* ag_g   = (const float*)d_in[25];
    const float* ag_bt  = (const float*)d_in[26];
    const float* v_w1   = (const float*)d_in[27];
    const float* v_b1   = (const float*)d_in[28];
    const float* v_g    = (const float*)d_in[29];
    const float* v_bt   = (const float*)d_in[30];
    const float* v_w2   = (const float*)d_in[31];
    const float* v_b2   = (const float*)d_in[32];
    const float* a_w1   = (const float*)d_in[33];
    const float* a_b1   = (const float*)d_in[34];
    const float* a_g    = (const float*)d_in[35];
    const float* a_bt   = (const float*)d_in[36];
    const float* a_w2   = (const float*)d_in[37];
    const float* a_b2   = (const float*)d_in[38];

    char* p = (char*)d_ws;
    auto alloc = [&](size_t bytes) {
        char* r = p;
        p += (bytes + 255) & ~(size_t)255;
        return r;
    };
    float* big0  = (float*)alloc((size_t)NT * DD * 4);
    float* big2  = (float*)alloc((size_t)NT * DD * 4);
    unsigned short* hb   = (unsigned short*)alloc((size_t)NT * DD * 2);
    unsigned short* xsb  = (unsigned short*)alloc((size_t)NT * DD * 2);
    unsigned short* wt   = (unsigned short*)alloc((size_t)3 * DD * DD * 2);
    unsigned short* edot = (unsigned short*)alloc((size_t)3 * ETC * 4 * 2);
    int2*  sp    = (int2*) alloc((size_t)ETC * 8);
    float* als   = (float*)alloc((size_t)NT * 4 * 4);
    float* ald   = (float*)alloc((size_t)NT * 4 * 4);
    float* ctx   = (float*)alloc(DD * 4);
    float* comb  = (float*)alloc(1280 * 4);
    float* lattr = (float*)alloc((size_t)NT * 3 * 4);
    float* wd    = (float*)alloc(36 * 4);
    float* pvacc = (float*)alloc((size_t)VB * DD * 4);
    float* pws   = (float*)alloc((size_t)VB * 4 * 4);
    float* pv    = (float*)alloc(40 * DD * 4);
    float* pa    = (float*)alloc(40 * DD * 4);
    int* degi    = (int*)alloc((size_t)NT * 4);
    int* offs    = (int*)alloc((size_t)(NT + 1) * 4);
    int* cursor  = (int*)alloc((size_t)NT * 4);

    hipMemsetAsync(ctx, 0, DD * 4, stream);
    hipMemsetAsync(degi, 0, (size_t)NT * 4, stream);

    k_enc<<<NN, 256, 0, stream>>>(x, enc_w, enc_b, enc_g, enc_bt, big0, hb);
    k_ctx<<<64, 256, 0, stream>>>(big0, ctx);
    k_vn<<<1, 256, 0, stream>>>(ctx, vn_w1, vn_b1, vn_g, vn_bt, vn_w2, vn_b2, vn_base, big0, hb, comb);
    k_deg<<<(EE + 255) / 256, 256, 0, stream>>>(ei, degi);
    k_scan<<<1, 1024, 0, stream>>>(degi, offs, cursor);
    k_scatter<<<(EE + 255) / 256, 256, 0, stream>>>(ei, cursor, sp);
    k_flattr<<<(NT + 3) / 4, 256, 0, stream>>>(offs, sp, ea, lattr);
    k_wedot<<<1, 64, 0, stream>>>(edge_w, att_edge, wd);
    k_edot<<<(ETC + 255) / 256, 256, 0, stream>>>(sp, ea, lattr, wd, edot);
    k_wconv<<<768, 256, 0, stream>>>(gat_w, wt);

    float* cur = big0;
    float* po  = big2;
    for (int l = 0; l < 3; l++) {
        const unsigned short* edotL = edot + (size_t)l * ETC * 4;
        k_gemm_mfma<<<(NT + 63) / 64, 256, 0, stream>>>(hb, wt + (size_t)l * DD * DD,
                                                        att_src + l * DD, att_dst + l * DD,
                                                        xsb, als, ald);
        k_msg<<<NT, 256, 0, stream>>>(offs, sp, edotL, als, ald, xsb,
                                      gat_b + l * DD, ln_g + l * DD, ln_b + l * DD,
                                      cur, po, hb);
        k_vacc<<<VB, 256, 0, stream>>>(offs, edotL, als, ald, xsb, pvacc, pws);
        k_vpost<<<1, 256, 0, stream>>>(pvacc, pws, gat_b + l * DD, ln_g + l * DD, ln_b + l * DD,
                                       cur, po, hb, comb + (l + 1) * DD);
        float* t = cur; cur = po; po = t;
    }
    k_agent<<<1, 256, 0, stream>>>(af, ag_w, ag_b, ag_g, ag_bt, comb);
    k_head1<<<40, 256, 0, stream>>>(comb, v_w1, a_w1, pv, pa);
    k_head2<<<1, 256, 0, stream>>>(pv, pa, v_b1, v_g, v_bt, v_w2, v_b2,
                                   a_b1, a_g, a_bt, a_w2, a_b2, (float*)d_out);
}

// Round 6
// 421.510 us; speedup vs baseline: 2.8990x; 1.0755x over previous
//
#include <hip/hip_runtime.h>
#include <math.h>

#define NN 10000
#define EE 320000
#define DD 256
#define NT 10001            // NN + virtual node
#define E1C (EE + NN)       // 330000
#define E2C (EE + 2 * NN)   // 340000
#define ETC (E2C + NT)      // 350001 (with self loops)
#define VB 157              // virtual-node partial blocks (64 rows each)

typedef __attribute__((ext_vector_type(8))) short s16x8;
typedef __attribute__((ext_vector_type(4))) float f32x4;

__device__ __forceinline__ unsigned short f2bf(float f) {
    unsigned u = __float_as_uint(f);
    return (unsigned short)((u + 0x7FFFu + ((u >> 16) & 1u)) >> 16);
}
__device__ __forceinline__ float bf2f(unsigned short u) {
    return __uint_as_float((unsigned)u << 16);
}

// ---------- reduction helpers ----------
__device__ __forceinline__ float wave_sum(float v) {
#pragma unroll
    for (int o = 32; o > 0; o >>= 1) v += __shfl_down(v, o, 64);
    return v;
}
__device__ __forceinline__ float wave_allsum(float v) {
#pragma unroll
    for (int o = 32; o > 0; o >>= 1) v += __shfl_xor(v, o, 64);
    return v;
}
__device__ __forceinline__ float blk_sum256(float v, float* sm4) {
    v = wave_sum(v);
    int lane = threadIdx.x & 63, w = threadIdx.x >> 6;
    __syncthreads();
    if (lane == 0) sm4[w] = v;
    __syncthreads();
    return sm4[0] + sm4[1] + sm4[2] + sm4[3];
}
// fused two-value block sum (one barrier pair)
__device__ __forceinline__ float2 blk_sum2(float a, float b, float2* sm4) {
#pragma unroll
    for (int o = 32; o > 0; o >>= 1) {
        a += __shfl_down(a, o, 64);
        b += __shfl_down(b, o, 64);
    }
    int lane = threadIdx.x & 63, w = threadIdx.x >> 6;
    __syncthreads();
    if (lane == 0) sm4[w] = make_float2(a, b);
    __syncthreads();
    float2 r;
    r.x = sm4[0].x + sm4[1].x + sm4[2].x + sm4[3].x;
    r.y = sm4[0].y + sm4[1].y + sm4[2].y + sm4[3].y;
    return r;
}

// ---------- node encoder: wave-per-row, no __syncthreads ----------
__global__ void __launch_bounds__(256) k_enc(
        const float* __restrict__ x, const float* __restrict__ wenc,
        const float* __restrict__ bia, const float* __restrict__ g,
        const float* __restrict__ bt, float* __restrict__ h,
        unsigned short* __restrict__ hb) {
    int t = threadIdx.x, lane = t & 63, wv = t >> 6;
    int v = blockIdx.x * 4 + wv;
    if (v >= NN) return;
    float xv = (lane < 10) ? x[v * 10 + lane] : 0.f;
    float4 acc = *(const float4*)(bia + lane * 4);
#pragma unroll
    for (int k = 0; k < 10; k++) {
        float xk = __shfl(xv, k, 64);
        float4 wk = *(const float4*)(wenc + k * DD + lane * 4);
        acc.x += xk * wk.x; acc.y += xk * wk.y; acc.z += xk * wk.z; acc.w += xk * wk.w;
    }
    float s1 = acc.x + acc.y + acc.z + acc.w;
    float s2 = acc.x * acc.x + acc.y * acc.y + acc.z * acc.z + acc.w * acc.w;
#pragma unroll
    for (int o = 32; o > 0; o >>= 1) {
        s1 += __shfl_xor(s1, o, 64);
        s2 += __shfl_xor(s2, o, 64);
    }
    float m = s1 * (1.f / DD);
    float var = s2 * (1.f / DD) - m * m;
    float rs = rsqrtf(var + 1e-5f);
    float4 g4 = *(const float4*)(g + lane * 4);
    float4 b4 = *(const float4*)(bt + lane * 4);
    float4 r4;
    r4.x = fmaxf((acc.x - m) * rs * g4.x + b4.x, 0.f);
    r4.y = fmaxf((acc.y - m) * rs * g4.y + b4.y, 0.f);
    r4.z = fmaxf((acc.z - m) * rs * g4.z + b4.z, 0.f);
    r4.w = fmaxf((acc.w - m) * rs * g4.w + b4.w, 0.f);
    *(float4*)(h + (size_t)v * DD + lane * 4) = r4;
    ushort4 u4;
    u4.x = f2bf(r4.x); u4.y = f2bf(r4.y); u4.z = f2bf(r4.z); u4.w = f2bf(r4.w);
    *(ushort4*)(hb + (size_t)v * DD + lane * 4) = u4;
}

// ---------- ctx stage 1: 256 blocks x 4 waves, float4 column partials ----------
__global__ void __launch_bounds__(256) k_ctx1(const float* __restrict__ h,
                                              float* __restrict__ part) {
    __shared__ float4 sm[4][64];
    int t = threadIdx.x, lane = t & 63, w = t >> 6;
    int b = blockIdx.x;
    float4 acc = make_float4(0.f, 0.f, 0.f, 0.f);
    for (int v = b * 4 + w; v < NN; v += 1024) {
        float4 hv = *(const float4*)(h + (size_t)v * DD + lane * 4);
        acc.x += hv.x; acc.y += hv.y; acc.z += hv.z; acc.w += hv.w;
    }
    sm[w][lane] = acc;
    __syncthreads();
    if (t < 64) {
        float4 a0 = sm[0][t], a1 = sm[1][t], a2 = sm[2][t], a3 = sm[3][t];
        float4 r;
        r.x = a0.x + a1.x + a2.x + a3.x;
        r.y = a0.y + a1.y + a2.y + a3.y;
        r.z = a0.z + a1.z + a2.z + a3.z;
        r.w = a0.w + a1.w + a2.w + a3.w;
        *(float4*)(part + (size_t)b * DD + t * 4) = r;
    }
}

// ---------- ctx stage 2: combine 256 partials ----------
__global__ void k_ctx2(const float* __restrict__ part, float* __restrict__ ctx) {
    int t = threadIdx.x;
    float acc = 0.f;
    for (int b = 0; b < 256; b++) acc += part[(size_t)b * DD + t];
    ctx[t] = acc;
}

// ---------- adaptive virtual node ----------
__global__ void k_vn(const float* __restrict__ ctx,
                     const float* __restrict__ w1, const float* __restrict__ b1,
                     const float* __restrict__ g, const float* __restrict__ bt,
                     const float* __restrict__ w2, const float* __restrict__ b2,
                     const float* __restrict__ vnb,
                     float* __restrict__ h, unsigned short* __restrict__ hb,
                     float* __restrict__ comb) {
    __shared__ float2 sm4[4];
    __shared__ float cs[DD];
    __shared__ float t[DD];
    int j = threadIdx.x;
    cs[j] = ctx[j] * (1.f / NN);
    __syncthreads();
    float acc = b1[j];
    for (int k = 0; k < DD; k++) acc += cs[k] * w1[k * DD + j];
    float2 mm = blk_sum2(acc, acc * acc, sm4);
    float m = mm.x * (1.f / DD);
    float var = mm.y * (1.f / DD) - m * m;
    float y = fmaxf((acc - m) * rsqrtf(var + 1e-5f) * g[j] + bt[j], 0.f);
    t[j] = y;
    __syncthreads();
    float a2 = b2[j];
    for (int k = 0; k < DD; k++) a2 += t[k] * w2[k * DD + j];
    float vn = vnb[j] + tanhf(a2);
    h[(size_t)NN * DD + j] = vn;
    hb[(size_t)NN * DD + j] = f2bf(vn);
    comb[j] = vn;   // jk slot 0 (virtual row of initial h)
}

// ---------- regular-edge in-degree histogram (1 atomic per edge) ----------
__global__ void k_deg(const int* __restrict__ ei, int* __restrict__ degi) {
    int e = blockIdx.x * 256 + threadIdx.x;
    if (e >= EE) return;
    atomicAdd(&degi[ei[EE + e]], 1);
}

// ---------- 1024-wide exclusive scan of (degR + virtual/self additions) ----------
__global__ void k_scan(const int* __restrict__ degi, int* __restrict__ offs,
                       int* __restrict__ cursor) {
    __shared__ int wsum[16];
    __shared__ int running_s;
    int t = threadIdx.x, lane = t & 63, w = t >> 6;
    if (t == 0) running_s = 0;
    __syncthreads();
    for (int base = 0; base < NT; base += 1024) {
        int v = base + t;
        int val = 0;
        if (v < NN) val = degi[v] + 2;          // + vn-edge + self-loop
        else if (v == NN) val = NN + 1;         // virtual: NN in-edges + self-loop
        int x = val;
#pragma unroll
        for (int o = 1; o < 64; o <<= 1) {
            int y = __shfl_up(x, o, 64);
            if (lane >= o) x += y;
        }
        if (lane == 63) wsum[w] = x;
        __syncthreads();
        int prefix = running_s;
        for (int ww = 0; ww < w; ww++) prefix += wsum[ww];
        if (v <= NN) { int e0 = prefix + x - val; offs[v] = e0; cursor[v] = e0; }
        __syncthreads();
        if (t == 0) {
            int s = 0;
            for (int i = 0; i < 16; i++) s += wsum[i];
            running_s += s;
        }
        __syncthreads();
    }
    if (threadIdx.x == 0) offs[NT] = running_s;
}

// ---------- scatter regular edges into CSR (packed {src, eid}) ----------
__global__ void k_scatter(const int* __restrict__ ei, int* __restrict__ cursor,
                          int2* __restrict__ sp) {
    int e = blockIdx.x * 256 + threadIdx.x;
    if (e >= EE) return;
    int src = ei[e], dst = ei[EE + e];
    int pos = atomicAdd(&cursor[dst], 1);
    sp[pos] = make_int2(src, e);
}

// ---------- fused: fill deterministic CSR slots + loop_attr segmented sums ----------
__global__ void k_flattr(const int* __restrict__ offs, int2* __restrict__ sp,
                         const float* __restrict__ ea, float* __restrict__ lattr) {
    int t = threadIdx.x, lane = t & 63, w = t >> 6;
    int v = blockIdx.x * 4 + w;
    if (v > NN) return;
    int bN = offs[NN];
    if (v == NN) {
        if (lane == 0) {
            lattr[v * 3] = 0.5f; lattr[v * 3 + 1] = 0.f; lattr[v * 3 + 2] = 0.f;
            sp[bN + NN] = make_int2(NN, E2C + NN);   // virtual self loop
        }
        return;
    }
    int b0 = offs[v], e1 = offs[v + 1];
    if (lane == 0) {
        sp[e1 - 2] = make_int2(NN, EE + v);      // vn -> v
        sp[e1 - 1] = make_int2(v, E2C + v);      // self loop
        sp[bN + v] = make_int2(v, E1C + v);      // v -> vn (virtual segment)
    }
    int cnt = e1 - b0 - 2;                       // regular in-edges
    float s0 = 0.f, s1 = 0.f, s2 = 0.f;
    for (int i = lane; i < cnt; i += 64) {
        int e = sp[b0 + i].y;
        s0 += ea[e * 3];
        s1 += ea[e * 3 + 1];
        s2 += ea[e * 3 + 2];
    }
    s0 = wave_sum(s0); s1 = wave_sum(s1); s2 = wave_sum(s2);
    if (lane == 0) {
        float inv = 1.f / (float)(cnt + 1);      // deg0 = regular + vn edge
        lattr[v * 3]     = (s0 + 0.5f) * inv;
        lattr[v * 3 + 1] = s1 * inv;
        lattr[v * 3 + 2] = s2 * inv;
    }
}

// ---------- we_dot[l][k][h] = sum_c e_w[l,k,h*64+c] * att_edge[l,h,c] ----------
__global__ void k_wedot(const float* __restrict__ ew, const float* __restrict__ ae,
                        float* __restrict__ wd) {
    int t = threadIdx.x;
    if (t >= 36) return;
    int l = t / 12, k = (t / 4) % 3, h = t % 4;
    float s = 0.f;
    for (int c = 0; c < 64; c++)
        s += ew[l * 768 + k * DD + h * 64 + c] * ae[l * DD + h * 64 + c];
    wd[t] = s;   // layout [l][k][h]
}

// ---------- per-edge, per-layer, per-head edge-attr dots, bf16 packed ----------
__global__ void k_edot(const int2* __restrict__ sp, const float* __restrict__ ea,
                       const float* __restrict__ lattr, const float* __restrict__ wd,
                       unsigned short* __restrict__ edot) {
    int p = blockIdx.x * 256 + threadIdx.x;
    if (p >= ETC) return;
    int e = sp[p].y;
    float a0, a1, a2;
    if (e < EE)       { a0 = ea[e * 3]; a1 = ea[e * 3 + 1]; a2 = ea[e * 3 + 2]; }
    else if (e < E2C) { a0 = 0.5f; a1 = 0.f; a2 = 0.f; }
    else              { int v = e - E2C; a0 = lattr[v * 3]; a1 = lattr[v * 3 + 1]; a2 = lattr[v * 3 + 2]; }
#pragma unroll
    for (int l = 0; l < 3; l++) {
        ushort4 o;
        o.x = f2bf(a0 * wd[l * 12 + 0] + a1 * wd[l * 12 + 4] + a2 * wd[l * 12 + 8]);
        o.y = f2bf(a0 * wd[l * 12 + 1] + a1 * wd[l * 12 + 5] + a2 * wd[l * 12 + 9]);
        o.z = f2bf(a0 * wd[l * 12 + 2] + a1 * wd[l * 12 + 6] + a2 * wd[l * 12 + 10]);
        o.w = f2bf(a0 * wd[l * 12 + 3] + a1 * wd[l * 12 + 7] + a2 * wd[l * 12 + 11]);
        *(ushort4*)(edot + (size_t)l * ETC * 4 + (size_t)p * 4) = o;
    }
}

// ---------- transpose gat_w to bf16 Wt[l][n][k] ----------
__global__ void k_wconv(const float* __restrict__ gw, unsigned short* __restrict__ wt) {
    int b = blockIdx.x;
    int l = b >> 8, k = b & 255, j = threadIdx.x;
    float v = gw[l * 65536 + k * 256 + j];
    wt[l * 65536 + j * 256 + k] = f2bf(v);
}

// ---------- xs = h @ W via bf16 MFMA (64 rows/block, 4 waves x 16 rows) ----------
__global__ void __launch_bounds__(256) k_gemm_mfma(
        const unsigned short* __restrict__ hb, const unsigned short* __restrict__ wt,
        const float* __restrict__ as_, const float* __restrict__ ad_,
        unsigned short* __restrict__ xsb, float* __restrict__ als, float* __restrict__ ald) {
    __shared__ unsigned short tile[64][256];
    int t = threadIdx.x, lane = t & 63, w = t >> 6;
    int v0 = blockIdx.x * 64;
    int rbase = v0 + w * 16;
    int li = lane & 15, g = lane >> 4;
    int arow = rbase + li; if (arow > NN) arow = NN;
    int koff = g * 8;
    const unsigned short* aptr = hb + (size_t)arow * DD + koff;
    const unsigned short* bptr = wt + (size_t)li * DD + koff;
    f32x4 acc[16];
#pragma unroll
    for (int n = 0; n < 16; n++) acc[n] = (f32x4){0.f, 0.f, 0.f, 0.f};
#pragma unroll
    for (int kb = 0; kb < 8; kb++) {
        s16x8 af = *(const s16x8*)(aptr + kb * 32);
#pragma unroll
        for (int n = 0; n < 16; n++) {
            s16x8 bf = *(const s16x8*)(bptr + (size_t)n * 16 * DD + kb * 32);
            acc[n] = __builtin_amdgcn_mfma_f32_16x16x32_bf16(af, bf, acc[n], 0, 0, 0);
        }
    }
    float asv[16], adv[16];
#pragma unroll
    for (int n = 0; n < 16; n++) { asv[n] = as_[n * 16 + li]; adv[n] = ad_[n * 16 + li]; }
#pragma unroll
    for (int r = 0; r < 4; r++) {
        int vrow = rbase + 4 * g + r;
#pragma unroll
        for (int h = 0; h < 4; h++) {
            float ps = acc[4 * h][r] * asv[4 * h] + acc[4 * h + 1][r] * asv[4 * h + 1]
                     + acc[4 * h + 2][r] * asv[4 * h + 2] + acc[4 * h + 3][r] * asv[4 * h + 3];
            float pd = acc[4 * h][r] * adv[4 * h] + acc[4 * h + 1][r] * adv[4 * h + 1]
                     + acc[4 * h + 2][r] * adv[4 * h + 2] + acc[4 * h + 3][r] * adv[4 * h + 3];
#pragma unroll
            for (int o = 1; o < 16; o <<= 1) {
                ps += __shfl_xor(ps, o, 64);
                pd += __shfl_xor(pd, o, 64);
            }
            if (li == 0 && vrow <= NN) { als[vrow * 4 + h] = ps; ald[vrow * 4 + h] = pd; }
        }
    }
#pragma unroll
    for (int n = 0; n < 16; n++)
#pragma unroll
        for (int r = 0; r < 4; r++)
            tile[w * 16 + 4 * g + r][n * 16 + li] = f2bf(acc[n][r]);
#pragma unroll
    for (int it = 0; it < 8; it++) {
        int flat = it * 64 + lane;
        int row = w * 16 + (flat >> 5);
        int c8 = flat & 31;
        int vrow = v0 + row;
        if (vrow <= NN)
            *(uint4*)(xsb + (size_t)vrow * DD + c8 * 8) = *(const uint4*)(&tile[row][c8 * 8]);
    }
}

// ---------- single-pass softmax-aggregation + fused LN/residual epilogue ----------
__global__ void __launch_bounds__(256) k_msg(
        const int* __restrict__ offs, const int2* __restrict__ sp,
        const unsigned short* __restrict__ edotL,
        const float* __restrict__ als, const float* __restrict__ ald,
        const unsigned short* __restrict__ xsb,
        const float* __restrict__ bias, const float* __restrict__ g,
        const float* __restrict__ bt, const float* __restrict__ hin,
        float* __restrict__ hout, unsigned short* __restrict__ hbout) {
    int v = blockIdx.x;
    if (v == NN) return;                         // virtual dst: k_vacc/k_vpost
    int t = threadIdx.x, lane = t & 63, w = t >> 6;
    int sub = lane >> 5, l32 = lane & 31, slot = w * 2 + sub;
    int hh = l32 >> 3;
    __shared__ float red[4][8][33];
    __shared__ float wsred[4][4];
    __shared__ float fin[4];
    __shared__ float2 sm4[4];
    int b0 = offs[v], deg = offs[v + 1] - b0;
    float adh = ald[v * 4 + hh];
    float acc[8];
#pragma unroll
    for (int q = 0; q < 8; q++) acc[q] = 0.f;
    float swt = 0.f;
    for (int i = slot; i < deg; i += 8) {
        int p = b0 + i;
        int src = sp[p].x;
        float a = als[src * 4 + hh] + bf2f(edotL[(size_t)p * 4 + hh]) + adh;
        a = a > 0.f ? a : 0.2f * a;
        float wt = __expf(a);
        uint4 xq = *(const uint4*)(xsb + (size_t)src * DD + l32 * 8);
        const unsigned short* xp = (const unsigned short*)&xq;
#pragma unroll
        for (int q = 0; q < 8; q++) acc[q] += wt * bf2f(xp[q]);
        if ((l32 & 7) == 0) swt += wt;
    }
#pragma unroll
    for (int q = 0; q < 8; q++) acc[q] += __shfl_xor(acc[q], 32, 64);
    swt += __shfl_xor(swt, 32, 64);
    if (sub == 0) {
#pragma unroll
        for (int q = 0; q < 8; q++) red[w][q][l32] = acc[q];   // conflict-free
        if ((l32 & 7) == 0) wsred[w][hh] = swt;
    }
    __syncthreads();
    if (t < 4) {
        float ws = wsred[0][t] + wsred[1][t] + wsred[2][t] + wsred[3][t];
        fin[t] = 1.f / (ws + 1e-16f);
    }
    __syncthreads();
    int c = t, q = c & 7, l = c >> 3;
    float o = (red[0][q][l] + red[1][q][l] + red[2][q][l] + red[3][q][l]) * fin[c >> 6];
    float tt = o + bias[c];
    float2 mm = blk_sum2(tt, tt * tt, sm4);
    float m = mm.x * (1.f / DD);
    float var = mm.y * (1.f / DD) - m * m;
    float y = (tt - m) * rsqrtf(var + 1e-5f) * g[c] + bt[c];
    float r = fmaxf(y + hin[(size_t)v * DD + c], 0.f);
    hout[(size_t)v * DD + c] = r;
    hbout[(size_t)v * DD + c] = f2bf(r);
}

// ---------- virtual-node partial aggregation: 157 blocks x 64 rows, 8 slots ----------
__global__ void __launch_bounds__(256) k_vacc(
        const int* __restrict__ offs, const unsigned short* __restrict__ edotL,
        const float* __restrict__ als, const float* __restrict__ ald,
        const unsigned short* __restrict__ xsb,
        float* __restrict__ pvacc, float* __restrict__ pws) {
    int b = blockIdx.x, t = threadIdx.x, lane = t & 63, w = t >> 6;
    int sub = lane >> 5, l32 = lane & 31, slot = w * 2 + sub;
    int hh = l32 >> 3;
    __shared__ float red[4][8][33];
    __shared__ float wsred[4][4];
    int b0 = offs[NN];
    float adh = ald[NN * 4 + hh];
    int i0 = b * 64, i1 = i0 + 64;
    if (i1 > NN + 1) i1 = NN + 1;
    float acc[8];
#pragma unroll
    for (int q = 0; q < 8; q++) acc[q] = 0.f;
    float swt = 0.f;
    for (int i = i0 + slot; i < i1; i += 8) {
        float a = als[i * 4 + hh] + bf2f(edotL[(size_t)(b0 + i) * 4 + hh]) + adh;
        a = a > 0.f ? a : 0.2f * a;
        float wt = __expf(a);
        uint4 xq = *(const uint4*)(xsb + (size_t)i * DD + l32 * 8);
        const unsigned short* xp = (const unsigned short*)&xq;
#pragma unroll
        for (int q = 0; q < 8; q++) acc[q] += wt * bf2f(xp[q]);
        if ((l32 & 7) == 0) swt += wt;
    }
#pragma unroll
    for (int q = 0; q < 8; q++) acc[q] += __shfl_xor(acc[q], 32, 64);
    swt += __shfl_xor(swt, 32, 64);
    if (sub == 0) {
#pragma unroll
        for (int q = 0; q < 8; q++) red[w][q][l32] = acc[q];
        if ((l32 & 7) == 0) wsred[w][hh] = swt;
    }
    __syncthreads();
    int c = t, q = c & 7, l = c >> 3;
    pvacc[(size_t)b * DD + c] = red[0][q][l] + red[1][q][l] + red[2][q][l] + red[3][q][l];
    if (t < 4) pws[b * 4 + t] = wsred[0][t] + wsred[1][t] + wsred[2][t] + wsred[3][t];
}

// ---------- virtual-node normalize + LN + residual ----------
__global__ void k_vpost(const float* __restrict__ pvacc, const float* __restrict__ pws,
                        const float* __restrict__ bias, const float* __restrict__ g,
                        const float* __restrict__ bt, const float* __restrict__ hin,
                        float* __restrict__ hout, unsigned short* __restrict__ hb,
                        float* __restrict__ jkslot) {
    __shared__ float2 sm4[4];
    int j = threadIdx.x, hh = j >> 6;
    float acc = 0.f;
    for (int b = 0; b < VB; b++) acc += pvacc[(size_t)b * DD + j];
    float ws = 0.f;
    for (int b = 0; b < VB; b++) ws += pws[b * 4 + hh];
    float o = acc / (ws + 1e-16f);
    float tt = o + bias[j];
    float2 mm = blk_sum2(tt, tt * tt, sm4);
    float m = mm.x * (1.f / DD);
    float var = mm.y * (1.f / DD) - m * m;
    float y = (tt - m) * rsqrtf(var + 1e-5f) * g[j] + bt[j];
    float r = fmaxf(y + hin[(size_t)NN * DD + j], 0.f);
    hout[(size_t)NN * DD + j] = r;
    hb[(size_t)NN * DD + j] = f2bf(r);
    jkslot[j] = r;
}

// ---------- agent encoder ----------
__global__ void k_agent(const float* __restrict__ af, const float* __restrict__ w,
                        const float* __restrict__ b, const float* __restrict__ g,
                        const float* __restrict__ bt, float* __restrict__ comb) {
    __shared__ float2 sm4[4];
    __shared__ float xr[10];
    int j = threadIdx.x;
    if (j < 10) xr[j] = af[j];
    __syncthreads();
    float acc = b[j];
#pragma unroll
    for (int k = 0; k < 10; k++) acc += xr[k] * w[k * DD + j];
    float2 mm = blk_sum2(acc, acc * acc, sm4);
    float m = mm.x * (1.f / DD);
    float var = mm.y * (1.f / DD) - m * m;
    float y = (acc - m) * rsqrtf(var + 1e-5f) * g[j] + bt[j];
    comb[1024 + j] = fmaxf(y, 0.f);
}

// ---------- dueling head, stage 1: 40-way k-sliced partial GEMMs ----------
__global__ void k_head1(const float* __restrict__ comb,
                        const float* __restrict__ vw1, const float* __restrict__ aw1,
                        float* __restrict__ pv, float* __restrict__ pa) {
    int j = threadIdx.x, s = blockIdx.x;
    int k0 = s * 32;
    float accv = 0.f, acca = 0.f;
#pragma unroll
    for (int kk = 0; kk < 32; kk++) {
        float c = comb[k0 + kk];
        accv += c * vw1[(k0 + kk) * DD + j];
        acca += c * aw1[(k0 + kk) * DD + j];
    }
    pv[s * DD + j] = accv;
    pa[s * DD + j] = acca;
}

// ---------- dueling head, stage 2 ----------
__global__ void k_head2(const float* __restrict__ pv, const float* __restrict__ pa,
                        const float* __restrict__ vb1, const float* __restrict__ vg,
                        const float* __restrict__ vbt, const float* __restrict__ vw2,
                        const float* __restrict__ vb2,
                        const float* __restrict__ ab1, const float* __restrict__ ag,
                        const float* __restrict__ abt, const float* __restrict__ aw2,
                        const float* __restrict__ ab2, float* __restrict__ out) {
    __shared__ float2 sm4[4];
    __shared__ float sm1[4];
    __shared__ float tl[DD];
    __shared__ float adv[9];
    __shared__ float valv;
    int j = threadIdx.x;
    float acc = vb1[j], acc2 = ab1[j];
    for (int s = 0; s < 40; s++) { acc += pv[s * DD + j]; acc2 += pa[s * DD + j]; }
    float2 mm = blk_sum2(acc, acc * acc, sm4);
    float m = mm.x * (1.f / DD);
    float var = mm.y * (1.f / DD) - m * m;
    float y = fmaxf((acc - m) * rsqrtf(var + 1e-5f) * vg[j] + vbt[j], 0.f);
    float vs = blk_sum256(y * vw2[j], sm1);
    if (j == 0) valv = vs + vb2[0];
    float2 mm2 = blk_sum2(acc2, acc2 * acc2, sm4);
    float m2 = mm2.x * (1.f / DD);
    float var2 = mm2.y * (1.f / DD) - m2 * m2;
    float y2 = fmaxf((acc2 - m2) * rsqrtf(var2 + 1e-5f) * ag[j] + abt[j], 0.f);
    tl[j] = y2;
    __syncthreads();
    if (j < 9) {
        float s = ab2[j];
        for (int k = 0; k < DD; k++) s += tl[k] * aw2[k * 9 + j];
        adv[j] = s;
    }
    __syncthreads();
    if (j < 9) {
        float mean = 0.f;
        for (int o = 0; o < 9; o++) mean += adv[o];
        mean *= (1.f / 9.f);
        out[j] = valv + adv[j] - mean;
    }
}

extern "C" void kernel_launch(void* const* d_in, const int* in_sizes, int n_in,
                              void* d_out, int out_size, void* d_ws, size_t ws_size,
                              hipStream_t stream) {
    (void)in_sizes; (void)n_in; (void)out_size; (void)ws_size;
    const float* x      = (const float*)d_in[0];
    const int*   ei     = (const int*)d_in[1];
    const float* ea     = (const float*)d_in[2];
    const float* af     = (const float*)d_in[3];
    const float* enc_w  = (const float*)d_in[4];
    const float* enc_b  = (const float*)d_in[5];
    const float* enc_g  = (const float*)d_in[6];
    const float* enc_bt = (const float*)d_in[7];
    const float* vn_base= (const float*)d_in[8];
    const float* vn_w1  = (const float*)d_in[9];
    const float* vn_b1  = (const float*)d_in[10];
    const float* vn_g   = (const float*)d_in[11];
    const float* vn_bt  = (const float*)d_in[12];
    const float* vn_w2  = (const float*)d_in[13];
    const float* vn_b2  = (const float*)d_in[14];
    const float* gat_w  = (const float*)d_in[15];
    const float* att_src= (const float*)d_in[16];
    const float* att_dst= (const float*)d_in[17];
    const float* att_edge=(const float*)d_in[18];
    const float* edge_w = (const float*)d_in[19];
    const float* gat_b  = (const float*)d_in[20];
    const float* ln_g   = (const float*)d_in[21];
    const float* ln_b   = (const float*)d_in[22];
    const float* ag_w   = (const float*)d_in[23];
    const float* ag_b   = (const float*)d_in[24];
    const float* ag_g   = (const float*)d_in[25];
    const float* ag_bt  = (const float*)d_in[26];
    const float* v_w1   = (const float*)d_in[27];
    const float* v_b1   = (const float*)d_in[28];
    const float* v_g    = (const float*)d_in[29];
    const float* v_bt   = (const float*)d_in[30];
    const float* v_w2   = (const float*)d_in[31];
    const float* v_b2   = (const float*)d_in[32];
    const float* a_w1   = (const float*)d_in[33];
    const float* a_b1   = (const float*)d_in[34];
    const float* a_g    = (const float*)d_in[35];
    const float* a_bt   = (const float*)d_in[36];
    const float* a_w2   = (const float*)d_in[37];
    const float* a_b2   = (const float*)d_in[38];

    char* p = (char*)d_ws;
    auto alloc = [&](size_t bytes) {
        char* r = p;
        p += (bytes + 255) & ~(size_t)255;
        return r;
    };
    float* big0  = (float*)alloc((size_t)NT * DD * 4);
    float* big2  = (float*)alloc((size_t)NT * DD * 4);
    unsigned short* hb   = (unsigned short*)alloc((size_t)NT * DD * 2);
    unsigned short* xsb  = (unsigned short*)alloc((size_t)NT * DD * 2);
    unsigned short* wt   = (unsigned short*)alloc((size_t)3 * DD * DD * 2);
    unsigned short* edot = (unsigned short*)alloc((size_t)3 * ETC * 4 * 2);
    int2*  sp    = (int2*) alloc((size_t)ETC * 8);
    float* als   = (float*)alloc((size_t)NT * 4 * 4);
    float* ald   = (float*)alloc((size_t)NT * 4 * 4);
    float* ctx   = (float*)alloc(DD * 4);
    float* part  = (float*)alloc((size_t)256 * DD * 4);
    float* comb  = (float*)alloc(1280 * 4);
    float* lattr = (float*)alloc((size_t)NT * 3 * 4);
    float* wd    = (float*)alloc(36 * 4);
    float* pvacc = (float*)alloc((size_t)VB * DD * 4);
    float* pws   = (float*)alloc((size_t)VB * 4 * 4);
    float* pv    = (float*)alloc(40 * DD * 4);
    float* pa    = (float*)alloc(40 * DD * 4);
    int* degi    = (int*)alloc((size_t)NT * 4);
    int* offs    = (int*)alloc((size_t)(NT + 1) * 4);
    int* cursor  = (int*)alloc((size_t)NT * 4);

    hipMemsetAsync(degi, 0, (size_t)NT * 4, stream);

    k_enc<<<2500, 256, 0, stream>>>(x, enc_w, enc_b, enc_g, enc_bt, big0, hb);
    k_ctx1<<<256, 256, 0, stream>>>(big0, part);
    k_ctx2<<<1, 256, 0, stream>>>(part, ctx);
    k_vn<<<1, 256, 0, stream>>>(ctx, vn_w1, vn_b1, vn_g, vn_bt, vn_w2, vn_b2, vn_base, big0, hb, comb);
    k_deg<<<(EE + 255) / 256, 256, 0, stream>>>(ei, degi);
    k_scan<<<1, 1024, 0, stream>>>(degi, offs, cursor);
    k_scatter<<<(EE + 255) / 256, 256, 0, stream>>>(ei, cursor, sp);
    k_flattr<<<(NT + 3) / 4, 256, 0, stream>>>(offs, sp, ea, lattr);
    k_wedot<<<1, 64, 0, stream>>>(edge_w, att_edge, wd);
    k_edot<<<(ETC + 255) / 256, 256, 0, stream>>>(sp, ea, lattr, wd, edot);
    k_wconv<<<768, 256, 0, stream>>>(gat_w, wt);

    float* cur = big0;
    float* po  = big2;
    for (int l = 0; l < 3; l++) {
        const unsigned short* edotL = edot + (size_t)l * ETC * 4;
        k_gemm_mfma<<<(NT + 63) / 64, 256, 0, stream>>>(hb, wt + (size_t)l * DD * DD,
                                                        att_src + l * DD, att_dst + l * DD,
                                                        xsb, als, ald);
        k_msg<<<NT, 256, 0, stream>>>(offs, sp, edotL, als, ald, xsb,
                                      gat_b + l * DD, ln_g + l * DD, ln_b + l * DD,
                                      cur, po, hb);
        k_vacc<<<VB, 256, 0, stream>>>(offs, edotL, als, ald, xsb, pvacc, pws);
        k_vpost<<<1, 256, 0, stream>>>(pvacc, pws, gat_b + l * DD, ln_g + l * DD, ln_b + l * DD,
                                       cur, po, hb, comb + (l + 1) * DD);
        float* t = cur; cur = po; po = t;
    }
    k_agent<<<1, 256, 0, stream>>>(af, ag_w, ag_b, ag_g, ag_bt, comb);
    k_head1<<<40, 256, 0, stream>>>(comb, v_w1, a_w1, pv, pa);
    k_head2<<<1, 256, 0, stream>>>(pv, pa, v_b1, v_g, v_bt, v_w2, v_b2,
                                   a_b1, a_g, a_bt, a_w2, a_b2, (float*)d_out);
}

// Round 7
// 405.256 us; speedup vs baseline: 3.0153x; 1.0401x over previous
//
#include <hip/hip_runtime.h>
#include <math.h>

#define NN 10000
#define EE 320000
#define DD 256
#define NT 10001            // NN + virtual node
#define E1C (EE + NN)       // 330000
#define E2C (EE + 2 * NN)   // 340000
#define ETC (E2C + NT)      // 350001 (with self loops)
#define VB 157              // virtual-node partial blocks (64 rows each)

typedef __attribute__((ext_vector_type(8))) short s16x8;
typedef __attribute__((ext_vector_type(4))) float f32x4;

__device__ __forceinline__ unsigned short f2bf(float f) {
    unsigned u = __float_as_uint(f);
    return (unsigned short)((u + 0x7FFFu + ((u >> 16) & 1u)) >> 16);
}
__device__ __forceinline__ float bf2f(unsigned short u) {
    return __uint_as_float((unsigned)u << 16);
}

// ---------- reduction helpers ----------
__device__ __forceinline__ float wave_sum(float v) {
#pragma unroll
    for (int o = 32; o > 0; o >>= 1) v += __shfl_down(v, o, 64);
    return v;
}
__device__ __forceinline__ float blk_sum256(float v, float* sm4) {
    v = wave_sum(v);
    int lane = threadIdx.x & 63, w = threadIdx.x >> 6;
    __syncthreads();
    if (lane == 0) sm4[w] = v;
    __syncthreads();
    return sm4[0] + sm4[1] + sm4[2] + sm4[3];
}
// fused two-value block sum (one barrier pair)
__device__ __forceinline__ float2 blk_sum2(float a, float b, float2* sm4) {
#pragma unroll
    for (int o = 32; o > 0; o >>= 1) {
        a += __shfl_down(a, o, 64);
        b += __shfl_down(b, o, 64);
    }
    int lane = threadIdx.x & 63, w = threadIdx.x >> 6;
    __syncthreads();
    if (lane == 0) sm4[w] = make_float2(a, b);
    __syncthreads();
    float2 r;
    r.x = sm4[0].x + sm4[1].x + sm4[2].x + sm4[3].x;
    r.y = sm4[0].y + sm4[1].y + sm4[2].y + sm4[3].y;
    return r;
}

// ---------- node encoder: wave-per-row, no __syncthreads ----------
__global__ void __launch_bounds__(256) k_enc(
        const float* __restrict__ x, const float* __restrict__ wenc,
        const float* __restrict__ bia, const float* __restrict__ g,
        const float* __restrict__ bt, float* __restrict__ h,
        unsigned short* __restrict__ hb) {
    int t = threadIdx.x, lane = t & 63, wv = t >> 6;
    int v = blockIdx.x * 4 + wv;
    if (v >= NN) return;
    float xv = (lane < 10) ? x[v * 10 + lane] : 0.f;
    float4 acc = *(const float4*)(bia + lane * 4);
#pragma unroll
    for (int k = 0; k < 10; k++) {
        float xk = __shfl(xv, k, 64);
        float4 wk = *(const float4*)(wenc + k * DD + lane * 4);
        acc.x += xk * wk.x; acc.y += xk * wk.y; acc.z += xk * wk.z; acc.w += xk * wk.w;
    }
    float s1 = acc.x + acc.y + acc.z + acc.w;
    float s2 = acc.x * acc.x + acc.y * acc.y + acc.z * acc.z + acc.w * acc.w;
#pragma unroll
    for (int o = 32; o > 0; o >>= 1) {
        s1 += __shfl_xor(s1, o, 64);
        s2 += __shfl_xor(s2, o, 64);
    }
    float m = s1 * (1.f / DD);
    float var = s2 * (1.f / DD) - m * m;
    float rs = rsqrtf(var + 1e-5f);
    float4 g4 = *(const float4*)(g + lane * 4);
    float4 b4 = *(const float4*)(bt + lane * 4);
    float4 r4;
    r4.x = fmaxf((acc.x - m) * rs * g4.x + b4.x, 0.f);
    r4.y = fmaxf((acc.y - m) * rs * g4.y + b4.y, 0.f);
    r4.z = fmaxf((acc.z - m) * rs * g4.z + b4.z, 0.f);
    r4.w = fmaxf((acc.w - m) * rs * g4.w + b4.w, 0.f);
    *(float4*)(h + (size_t)v * DD + lane * 4) = r4;
    ushort4 u4;
    u4.x = f2bf(r4.x); u4.y = f2bf(r4.y); u4.z = f2bf(r4.z); u4.w = f2bf(r4.w);
    *(ushort4*)(hb + (size_t)v * DD + lane * 4) = u4;
}

// ---------- ctx stage 1 (+ fused regular-edge degree histogram) ----------
__global__ void __launch_bounds__(256) k_ctx1deg(const float* __restrict__ h,
                                                 float* __restrict__ part,
                                                 const int* __restrict__ ei,
                                                 int* __restrict__ degi) {
    __shared__ float4 sm[4][64];
    int t = threadIdx.x, lane = t & 63, w = t >> 6;
    int b = blockIdx.x;
    float4 acc = make_float4(0.f, 0.f, 0.f, 0.f);
    for (int v = b * 4 + w; v < NN; v += 1024) {
        float4 hv = *(const float4*)(h + (size_t)v * DD + lane * 4);
        acc.x += hv.x; acc.y += hv.y; acc.z += hv.z; acc.w += hv.w;
    }
    sm[w][lane] = acc;
    __syncthreads();
    if (t < 64) {
        float4 a0 = sm[0][t], a1 = sm[1][t], a2 = sm[2][t], a3 = sm[3][t];
        float4 r;
        r.x = a0.x + a1.x + a2.x + a3.x;
        r.y = a0.y + a1.y + a2.y + a3.y;
        r.z = a0.z + a1.z + a2.z + a3.z;
        r.w = a0.w + a1.w + a2.w + a3.w;
        *(float4*)(part + (size_t)b * DD + t * 4) = r;
    }
    // fused: regular-edge in-degree histogram (independent work)
    for (int e = b * 256 + t; e < EE; e += 256 * 256)
        atomicAdd(&degi[ei[EE + e]], 1);
}

// ---------- adaptive virtual node (+ fused ctx partial combine) ----------
__global__ void k_vn(const float* __restrict__ part,
                     const float* __restrict__ w1, const float* __restrict__ b1,
                     const float* __restrict__ g, const float* __restrict__ bt,
                     const float* __restrict__ w2, const float* __restrict__ b2,
                     const float* __restrict__ vnb,
                     float* __restrict__ h, unsigned short* __restrict__ hb,
                     float* __restrict__ comb) {
    __shared__ float2 sm4[4];
    __shared__ float cs[DD];
    __shared__ float t[DD];
    int j = threadIdx.x;
    float c = 0.f;
    for (int b = 0; b < 256; b++) c += part[(size_t)b * DD + j];
    cs[j] = c * (1.f / NN);
    __syncthreads();
    float acc = b1[j];
    for (int k = 0; k < DD; k++) acc += cs[k] * w1[k * DD + j];
    float2 mm = blk_sum2(acc, acc * acc, sm4);
    float m = mm.x * (1.f / DD);
    float var = mm.y * (1.f / DD) - m * m;
    float y = fmaxf((acc - m) * rsqrtf(var + 1e-5f) * g[j] + bt[j], 0.f);
    t[j] = y;
    __syncthreads();
    float a2 = b2[j];
    for (int k = 0; k < DD; k++) a2 += t[k] * w2[k * DD + j];
    float vn = vnb[j] + tanhf(a2);
    h[(size_t)NN * DD + j] = vn;
    hb[(size_t)NN * DD + j] = f2bf(vn);
    comb[j] = vn;   // jk slot 0 (virtual row of initial h)
}

// ---------- 1024-wide exclusive scan of (degR + virtual/self additions) ----------
__global__ void k_scan(const int* __restrict__ degi, int* __restrict__ offs,
                       int* __restrict__ cursor) {
    __shared__ int wsum[16];
    __shared__ int running_s;
    int t = threadIdx.x, lane = t & 63, w = t >> 6;
    if (t == 0) running_s = 0;
    __syncthreads();
    for (int base = 0; base < NT; base += 1024) {
        int v = base + t;
        int val = 0;
        if (v < NN) val = degi[v] + 2;          // + vn-edge + self-loop
        else if (v == NN) val = NN + 1;         // virtual: NN in-edges + self-loop
        int x = val;
#pragma unroll
        for (int o = 1; o < 64; o <<= 1) {
            int y = __shfl_up(x, o, 64);
            if (lane >= o) x += y;
        }
        if (lane == 63) wsum[w] = x;
        __syncthreads();
        int prefix = running_s;
        for (int ww = 0; ww < w; ww++) prefix += wsum[ww];
        if (v <= NN) { int e0 = prefix + x - val; offs[v] = e0; cursor[v] = e0; }
        __syncthreads();
        if (t == 0) {
            int s = 0;
            for (int i = 0; i < 16; i++) s += wsum[i];
            running_s += s;
        }
        __syncthreads();
    }
    if (threadIdx.x == 0) offs[NT] = running_s;
}

// ---------- scatter regular edges into CSR (split src / eid arrays) ----------
__global__ void k_scatter(const int* __restrict__ ei, int* __restrict__ cursor,
                          int* __restrict__ ssrc, int* __restrict__ seid) {
    int e = blockIdx.x * 256 + threadIdx.x;
    if (e >= EE) return;
    int src = ei[e], dst = ei[EE + e];
    int pos = atomicAdd(&cursor[dst], 1);
    ssrc[pos] = src;
    seid[pos] = e;
}

// ---------- fused: fill deterministic CSR slots + loop_attr segmented sums ----------
__global__ void k_flattr(const int* __restrict__ offs, int* __restrict__ ssrc,
                         int* __restrict__ seid,
                         const float* __restrict__ ea, float* __restrict__ lattr) {
    int t = threadIdx.x, lane = t & 63, w = t >> 6;
    int v = blockIdx.x * 4 + w;
    if (v > NN) return;
    int bN = offs[NN];
    if (v == NN) {
        if (lane == 0) {
            lattr[v * 3] = 0.5f; lattr[v * 3 + 1] = 0.f; lattr[v * 3 + 2] = 0.f;
            ssrc[bN + NN] = NN; seid[bN + NN] = E2C + NN;   // virtual self loop
        }
        return;
    }
    int b0 = offs[v], e1 = offs[v + 1];
    if (lane == 0) {
        ssrc[e1 - 2] = NN; seid[e1 - 2] = EE + v;       // vn -> v
        ssrc[e1 - 1] = v;  seid[e1 - 1] = E2C + v;      // self loop
        ssrc[bN + v] = v;  seid[bN + v] = E1C + v;      // v -> vn (virtual segment)
    }
    int cnt = e1 - b0 - 2;                       // regular in-edges
    float s0 = 0.f, s1 = 0.f, s2 = 0.f;
    for (int i = lane; i < cnt; i += 64) {
        int e = seid[b0 + i];
        s0 += ea[e * 3];
        s1 += ea[e * 3 + 1];
        s2 += ea[e * 3 + 2];
    }
    s0 = wave_sum(s0); s1 = wave_sum(s1); s2 = wave_sum(s2);
    if (lane == 0) {
        float inv = 1.f / (float)(cnt + 1);      // deg0 = regular + vn edge
        lattr[v * 3]     = (s0 + 0.5f) * inv;
        lattr[v * 3 + 1] = s1 * inv;
        lattr[v * 3 + 2] = s2 * inv;
    }
}

// ---------- weight transpose (blocks 0..767) + we_dot (block 768) ----------
__global__ void k_wconv(const float* __restrict__ gw, unsigned short* __restrict__ wt,
                        const float* __restrict__ ew, const float* __restrict__ ae,
                        float* __restrict__ wd) {
    int b = blockIdx.x, j = threadIdx.x;
    if (b == 768) {
        if (j >= 36) return;
        int l = j / 12, k = (j / 4) % 3, h = j % 4;
        float s = 0.f;
        for (int c = 0; c < 64; c++)
            s += ew[l * 768 + k * DD + h * 64 + c] * ae[l * DD + h * 64 + c];
        wd[j] = s;   // layout [l][k][h]
        return;
    }
    int l = b >> 8, k = b & 255;
    float v = gw[l * 65536 + k * 256 + j];
    wt[l * 65536 + j * 256 + k] = f2bf(v);
}

// ---------- per-edge, per-layer, per-head edge-attr dots, bf16 packed ----------
__global__ void k_edot(const int* __restrict__ seid, const float* __restrict__ ea,
                       const float* __restrict__ lattr, const float* __restrict__ wd,
                       unsigned short* __restrict__ edot) {
    int p = blockIdx.x * 256 + threadIdx.x;
    if (p >= ETC) return;
    int e = seid[p];
    float a0, a1, a2;
    if (e < EE)       { a0 = ea[e * 3]; a1 = ea[e * 3 + 1]; a2 = ea[e * 3 + 2]; }
    else if (e < E2C) { a0 = 0.5f; a1 = 0.f; a2 = 0.f; }
    else              { int v = e - E2C; a0 = lattr[v * 3]; a1 = lattr[v * 3 + 1]; a2 = lattr[v * 3 + 2]; }
#pragma unroll
    for (int l = 0; l < 3; l++) {
        ushort4 o;
        o.x = f2bf(a0 * wd[l * 12 + 0] + a1 * wd[l * 12 + 4] + a2 * wd[l * 12 + 8]);
        o.y = f2bf(a0 * wd[l * 12 + 1] + a1 * wd[l * 12 + 5] + a2 * wd[l * 12 + 9]);
        o.z = f2bf(a0 * wd[l * 12 + 2] + a1 * wd[l * 12 + 6] + a2 * wd[l * 12 + 10]);
        o.w = f2bf(a0 * wd[l * 12 + 3] + a1 * wd[l * 12 + 7] + a2 * wd[l * 12 + 11]);
        *(ushort4*)(edot + (size_t)l * ETC * 4 + (size_t)p * 4) = o;
    }
}

// ---------- xs = h @ W via bf16 MFMA (64 rows/block, 4 waves x 16 rows) ----------
__global__ void __launch_bounds__(256) k_gemm_mfma(
        const unsigned short* __restrict__ hb, const unsigned short* __restrict__ wt,
        const float* __restrict__ as_, const float* __restrict__ ad_,
        unsigned short* __restrict__ xsb, float* __restrict__ als, float* __restrict__ ald) {
    __shared__ unsigned short tile[64][256];
    int t = threadIdx.x, lane = t & 63, w = t >> 6;
    int v0 = blockIdx.x * 64;
    int rbase = v0 + w * 16;
    int li = lane & 15, g = lane >> 4;
    int arow = rbase + li; if (arow > NN) arow = NN;
    int koff = g * 8;
    const unsigned short* aptr = hb + (size_t)arow * DD + koff;
    const unsigned short* bptr = wt + (size_t)li * DD + koff;
    f32x4 acc[16];
#pragma unroll
    for (int n = 0; n < 16; n++) acc[n] = (f32x4){0.f, 0.f, 0.f, 0.f};
#pragma unroll
    for (int kb = 0; kb < 8; kb++) {
        s16x8 af = *(const s16x8*)(aptr + kb * 32);
#pragma unroll
        for (int n = 0; n < 16; n++) {
            s16x8 bf = *(const s16x8*)(bptr + (size_t)n * 16 * DD + kb * 32);
            acc[n] = __builtin_amdgcn_mfma_f32_16x16x32_bf16(af, bf, acc[n], 0, 0, 0);
        }
    }
    float asv[16], adv[16];
#pragma unroll
    for (int n = 0; n < 16; n++) { asv[n] = as_[n * 16 + li]; adv[n] = ad_[n * 16 + li]; }
#pragma unroll
    for (int r = 0; r < 4; r++) {
        int vrow = rbase + 4 * g + r;
#pragma unroll
        for (int h = 0; h < 4; h++) {
            float ps = acc[4 * h][r] * asv[4 * h] + acc[4 * h + 1][r] * asv[4 * h + 1]
                     + acc[4 * h + 2][r] * asv[4 * h + 2] + acc[4 * h + 3][r] * asv[4 * h + 3];
            float pd = acc[4 * h][r] * adv[4 * h] + acc[4 * h + 1][r] * adv[4 * h + 1]
                     + acc[4 * h + 2][r] * adv[4 * h + 2] + acc[4 * h + 3][r] * adv[4 * h + 3];
#pragma unroll
            for (int o = 1; o < 16; o <<= 1) {
                ps += __shfl_xor(ps, o, 64);
                pd += __shfl_xor(pd, o, 64);
            }
            if (li == 0 && vrow <= NN) { als[vrow * 4 + h] = ps; ald[vrow * 4 + h] = pd; }
        }
    }
#pragma unroll
    for (int n = 0; n < 16; n++)
#pragma unroll
        for (int r = 0; r < 4; r++)
            tile[w * 16 + 4 * g + r][n * 16 + li] = f2bf(acc[n][r]);
#pragma unroll
    for (int it = 0; it < 8; it++) {
        int flat = it * 64 + lane;
        int row = w * 16 + (flat >> 5);
        int c8 = flat & 31;
        int vrow = v0 + row;
        if (vrow <= NN)
            *(uint4*)(xsb + (size_t)vrow * DD + c8 * 8) = *(const uint4*)(&tile[row][c8 * 8]);
    }
}

// ---------- single-pass softmax-aggregation + fused LN/residual epilogue ----------
// blocks [0..NN): regular dst; block NN: skip; blocks [NT..NT+VB): virtual partials
__global__ void __launch_bounds__(256) k_msg(
        const int* __restrict__ offs, const int* __restrict__ ssrc,
        const unsigned short* __restrict__ edotL,
        const float* __restrict__ als, const float* __restrict__ ald,
        const unsigned short* __restrict__ xsb,
        const float* __restrict__ bias, const float* __restrict__ g,
        const float* __restrict__ bt, const float* __restrict__ hin,
        float* __restrict__ hout, unsigned short* __restrict__ hbout,
        float* __restrict__ pvacc, float* __restrict__ pws) {
    int v = blockIdx.x;
    if (v == NN) return;
    int t = threadIdx.x, lane = t & 63, w = t >> 6;
    int sub = lane >> 5, l32 = lane & 31, slot = w * 2 + sub;
    int hh = l32 >> 3;
    __shared__ float red[4][8][33];
    __shared__ float wsred[4][4];
    __shared__ float fin[4];
    __shared__ float2 sm4[4];
    float acc[8];
#pragma unroll
    for (int q = 0; q < 8; q++) acc[q] = 0.f;
    float swt = 0.f;
    if (v >= NT) {
        // ---- virtual-node partial block b = v - NT over rows [b*64, b*64+64) ----
        int b = v - NT;
        int b0 = offs[NN];
        float adh = ald[NN * 4 + hh];
        int i0 = b * 64, i1 = i0 + 64;
        if (i1 > NN + 1) i1 = NN + 1;
        for (int i = i0 + slot; i < i1; i += 8) {
            float a = als[i * 4 + hh] + bf2f(edotL[(size_t)(b0 + i) * 4 + hh]) + adh;
            a = a > 0.f ? a : 0.2f * a;
            float wt = __expf(a);
            uint4 xq = *(const uint4*)(xsb + (size_t)i * DD + l32 * 8);
            const unsigned short* xp = (const unsigned short*)&xq;
#pragma unroll
            for (int q = 0; q < 8; q++) acc[q] += wt * bf2f(xp[q]);
            if ((l32 & 7) == 0) swt += wt;
        }
#pragma unroll
        for (int q = 0; q < 8; q++) acc[q] += __shfl_xor(acc[q], 32, 64);
        swt += __shfl_xor(swt, 32, 64);
        if (sub == 0) {
#pragma unroll
            for (int q = 0; q < 8; q++) red[w][q][l32] = acc[q];
            if ((l32 & 7) == 0) wsred[w][hh] = swt;
        }
        __syncthreads();
        int c = t, q = c & 7, l = c >> 3;
        pvacc[(size_t)b * DD + c] = red[0][q][l] + red[1][q][l] + red[2][q][l] + red[3][q][l];
        if (t < 4) pws[b * 4 + t] = wsred[0][t] + wsred[1][t] + wsred[2][t] + wsred[3][t];
        return;
    }
    // ---- regular dst ----
    int b0 = offs[v], deg = offs[v + 1] - b0;
    float adh = ald[v * 4 + hh];
    for (int i = slot; i < deg; i += 8) {
        int p = b0 + i;
        int src = ssrc[p];
        float a = als[src * 4 + hh] + bf2f(edotL[(size_t)p * 4 + hh]) + adh;
        a = a > 0.f ? a : 0.2f * a;
        float wt = __expf(a);
        uint4 xq = *(const uint4*)(xsb + (size_t)src * DD + l32 * 8);
        const unsigned short* xp = (const unsigned short*)&xq;
#pragma unroll
        for (int q = 0; q < 8; q++) acc[q] += wt * bf2f(xp[q]);
        if ((l32 & 7) == 0) swt += wt;
    }
#pragma unroll
    for (int q = 0; q < 8; q++) acc[q] += __shfl_xor(acc[q], 32, 64);
    swt += __shfl_xor(swt, 32, 64);
    if (sub == 0) {
#pragma unroll
        for (int q = 0; q < 8; q++) red[w][q][l32] = acc[q];   // conflict-free
        if ((l32 & 7) == 0) wsred[w][hh] = swt;
    }
    __syncthreads();
    if (t < 4) {
        float ws = wsred[0][t] + wsred[1][t] + wsred[2][t] + wsred[3][t];
        fin[t] = 1.f / (ws + 1e-16f);
    }
    __syncthreads();
    int c = t, q = c & 7, l = c >> 3;
    float o = (red[0][q][l] + red[1][q][l] + red[2][q][l] + red[3][q][l]) * fin[c >> 6];
    float tt = o + bias[c];
    float2 mm = blk_sum2(tt, tt * tt, sm4);
    float m = mm.x * (1.f / DD);
    float var = mm.y * (1.f / DD) - m * m;
    float y = (tt - m) * rsqrtf(var + 1e-5f) * g[c] + bt[c];
    float r = fmaxf(y + hin[(size_t)v * DD + c], 0.f);
    hout[(size_t)v * DD + c] = r;
    hbout[(size_t)v * DD + c] = f2bf(r);
}

// ---------- virtual-node normalize + LN + residual (+ agent encoder on last) ----------
__global__ void k_vpost(const float* __restrict__ pvacc, const float* __restrict__ pws,
                        const float* __restrict__ bias, const float* __restrict__ g,
                        const float* __restrict__ bt, const float* __restrict__ hin,
                        float* __restrict__ hout, unsigned short* __restrict__ hb,
                        float* __restrict__ jkslot,
                        int last, const float* __restrict__ af,
                        const float* __restrict__ agw, const float* __restrict__ agb,
                        const float* __restrict__ agg, const float* __restrict__ agbt,
                        float* __restrict__ comb) {
    __shared__ float2 sm4[4];
    int j = threadIdx.x, hh = j >> 6;
    float acc = 0.f;
    for (int b = 0; b < VB; b++) acc += pvacc[(size_t)b * DD + j];
    float ws = 0.f;
    for (int b = 0; b < VB; b++) ws += pws[b * 4 + hh];
    float o = acc / (ws + 1e-16f);
    float tt = o + bias[j];
    float2 mm = blk_sum2(tt, tt * tt, sm4);
    float m = mm.x * (1.f / DD);
    float var = mm.y * (1.f / DD) - m * m;
    float y = (tt - m) * rsqrtf(var + 1e-5f) * g[j] + bt[j];
    float r = fmaxf(y + hin[(size_t)NN * DD + j], 0.f);
    hout[(size_t)NN * DD + j] = r;
    hb[(size_t)NN * DD + j] = f2bf(r);
    jkslot[j] = r;
    if (last) {
        float a2 = agb[j];
#pragma unroll
        for (int k = 0; k < 10; k++) a2 += af[k] * agw[k * DD + j];
        float2 m2 = blk_sum2(a2, a2 * a2, sm4);
        float mu = m2.x * (1.f / DD);
        float vv = m2.y * (1.f / DD) - mu * mu;
        float ya = (a2 - mu) * rsqrtf(vv + 1e-5f) * agg[j] + agbt[j];
        comb[1024 + j] = fmaxf(ya, 0.f);
    }
}

// ---------- dueling head, stage 1: 40-way k-sliced partial GEMMs ----------
__global__ void k_head1(const float* __restrict__ comb,
                        const float* __restrict__ vw1, const float* __restrict__ aw1,
                        float* __restrict__ pv, float* __restrict__ pa) {
    int j = threadIdx.x, s = blockIdx.x;
    int k0 = s * 32;
    float accv = 0.f, acca = 0.f;
#pragma unroll
    for (int kk = 0; kk < 32; kk++) {
        float c = comb[k0 + kk];
        accv += c * vw1[(k0 + kk) * DD + j];
        acca += c * aw1[(k0 + kk) * DD + j];
    }
    pv[s * DD + j] = accv;
    pa[s * DD + j] = acca;
}

// ---------- dueling head, stage 2 ----------
__global__ void k_head2(const float* __restrict__ pv, const float* __restrict__ pa,
                        const float* __restrict__ vb1, const float* __restrict__ vg,
                        const float* __restrict__ vbt, const float* __restrict__ vw2,
                        const float* __restrict__ vb2,
                        const float* __restrict__ ab1, const float* __restrict__ ag,
                        const float* __restrict__ abt, const float* __restrict__ aw2,
                        const float* __restrict__ ab2, float* __restrict__ out) {
    __shared__ float2 sm4[4];
    __shared__ float sm1[4];
    __shared__ float tl[DD];
    __shared__ float adv[9];
    __shared__ float valv;
    int j = threadIdx.x;
    float acc = vb1[j], acc2 = ab1[j];
    for (int s = 0; s < 40; s++) { acc += pv[s * DD + j]; acc2 += pa[s * DD + j]; }
    float2 mm = blk_sum2(acc, acc * acc, sm4);
    float m = mm.x * (1.f / DD);
    float var = mm.y * (1.f / DD) - m * m;
    float y = fmaxf((acc - m) * rsqrtf(var + 1e-5f) * vg[j] + vbt[j], 0.f);
    float vs = blk_sum256(y * vw2[j], sm1);
    if (j == 0) valv = vs + vb2[0];
    float2 mm2 = blk_sum2(acc2, acc2 * acc2, sm4);
    float m2 = mm2.x * (1.f / DD);
    float var2 = mm2.y * (1.f / DD) - m2 * m2;
    float y2 = fmaxf((acc2 - m2) * rsqrtf(var2 + 1e-5f) * ag[j] + abt[j], 0.f);
    tl[j] = y2;
    __syncthreads();
    if (j < 9) {
        float s = ab2[j];
        for (int k = 0; k < DD; k++) s += tl[k] * aw2[k * 9 + j];
        adv[j] = s;
    }
    __syncthreads();
    if (j < 9) {
        float mean = 0.f;
        for (int o = 0; o < 9; o++) mean += adv[o];
        mean *= (1.f / 9.f);
        out[j] = valv + adv[j] - mean;
    }
}

extern "C" void kernel_launch(void* const* d_in, const int* in_sizes, int n_in,
                              void* d_out, int out_size, void* d_ws, size_t ws_size,
                              hipStream_t stream) {
    (void)in_sizes; (void)n_in; (void)out_size; (void)ws_size;
    const float* x      = (const float*)d_in[0];
    const int*   ei     = (const int*)d_in[1];
    const float* ea     = (const float*)d_in[2];
    const float* af     = (const float*)d_in[3];
    const float* enc_w  = (const float*)d_in[4];
    const float* enc_b  = (const float*)d_in[5];
    const float* enc_g  = (const float*)d_in[6];
    const float* enc_bt = (const float*)d_in[7];
    const float* vn_base= (const float*)d_in[8];
    const float* vn_w1  = (const float*)d_in[9];
    const float* vn_b1  = (const float*)d_in[10];
    const float* vn_g   = (const float*)d_in[11];
    const float* vn_bt  = (const float*)d_in[12];
    const float* vn_w2  = (const float*)d_in[13];
    const float* vn_b2  = (const float*)d_in[14];
    const float* gat_w  = (const float*)d_in[15];
    const float* att_src= (const float*)d_in[16];
    const float* att_dst= (const float*)d_in[17];
    const float* att_edge=(const float*)d_in[18];
    const float* edge_w = (const float*)d_in[19];
    const float* gat_b  = (const float*)d_in[20];
    const float* ln_g   = (const float*)d_in[21];
    const float* ln_b   = (const float*)d_in[22];
    const float* ag_w   = (const float*)d_in[23];
    const float* ag_b   = (const float*)d_in[24];
    const float* ag_g   = (const float*)d_in[25];
    const float* ag_bt  = (const float*)d_in[26];
    const float* v_w1   = (const float*)d_in[27];
    const float* v_b1   = (const float*)d_in[28];
    const float* v_g    = (const float*)d_in[29];
    const float* v_bt   = (const float*)d_in[30];
    const float* v_w2   = (const float*)d_in[31];
    const float* v_b2   = (const float*)d_in[32];
    const float* a_w1   = (const float*)d_in[33];
    const float* a_b1   = (const float*)d_in[34];
    const float* a_g    = (const float*)d_in[35];
    const float* a_bt   = (const float*)d_in[36];
    const float* a_w2   = (const float*)d_in[37];
    const float* a_b2   = (const float*)d_in[38];

    char* p = (char*)d_ws;
    auto alloc = [&](size_t bytes) {
        char* r = p;
        p += (bytes + 255) & ~(size_t)255;
        return r;
    };
    float* big0  = (float*)alloc((size_t)NT * DD * 4);
    float* big2  = (float*)alloc((size_t)NT * DD * 4);
    unsigned short* hb   = (unsigned short*)alloc((size_t)NT * DD * 2);
    unsigned short* xsb  = (unsigned short*)alloc((size_t)NT * DD * 2);
    unsigned short* wt   = (unsigned short*)alloc((size_t)3 * DD * DD * 2);
    unsigned short* edot = (unsigned short*)alloc((size_t)3 * ETC * 4 * 2);
    int* ssrc    = (int*)alloc((size_t)ETC * 4);
    int* seid    = (int*)alloc((size_t)ETC * 4);
    float* als   = (float*)alloc((size_t)NT * 4 * 4);
    float* ald   = (float*)alloc((size_t)NT * 4 * 4);
    float* part  = (float*)alloc((size_t)256 * DD * 4);
    float* comb  = (float*)alloc(1280 * 4);
    float* lattr = (float*)alloc((size_t)NT * 3 * 4);
    float* wd    = (float*)alloc(36 * 4);
    float* pvacc = (float*)alloc((size_t)VB * DD * 4);
    float* pws   = (float*)alloc((size_t)VB * 4 * 4);
    float* pv    = (float*)alloc(40 * DD * 4);
    float* pa    = (float*)alloc(40 * DD * 4);
    int* degi    = (int*)alloc((size_t)NT * 4);
    int* offs    = (int*)alloc((size_t)(NT + 1) * 4);
    int* cursor  = (int*)alloc((size_t)NT * 4);

    hipMemsetAsync(degi, 0, (size_t)NT * 4, stream);

    k_enc<<<2500, 256, 0, stream>>>(x, enc_w, enc_b, enc_g, enc_bt, big0, hb);
    k_ctx1deg<<<256, 256, 0, stream>>>(big0, part, ei, degi);
    k_vn<<<1, 256, 0, stream>>>(part, vn_w1, vn_b1, vn_g, vn_bt, vn_w2, vn_b2, vn_base, big0, hb, comb);
    k_scan<<<1, 1024, 0, stream>>>(degi, offs, cursor);
    k_scatter<<<(EE + 255) / 256, 256, 0, stream>>>(ei, cursor, ssrc, seid);
    k_flattr<<<(NT + 3) / 4, 256, 0, stream>>>(offs, ssrc, seid, ea, lattr);
    k_wconv<<<769, 256, 0, stream>>>(gat_w, wt, edge_w, att_edge, wd);
    k_edot<<<(ETC + 255) / 256, 256, 0, stream>>>(seid, ea, lattr, wd, edot);

    float* cur = big0;
    float* po  = big2;
    for (int l = 0; l < 3; l++) {
        const unsigned short* edotL = edot + (size_t)l * ETC * 4;
        k_gemm_mfma<<<(NT + 63) / 64, 256, 0, stream>>>(hb, wt + (size_t)l * DD * DD,
                                                        att_src + l * DD, att_dst + l * DD,
                                                        xsb, als, ald);
        k_msg<<<NT + VB, 256, 0, stream>>>(offs, ssrc, edotL, als, ald, xsb,
                                           gat_b + l * DD, ln_g + l * DD, ln_b + l * DD,
                                           cur, po, hb, pvacc, pws);
        k_vpost<<<1, 256, 0, stream>>>(pvacc, pws, gat_b + l * DD, ln_g + l * DD, ln_b + l * DD,
                                       cur, po, hb, comb + (l + 1) * DD,
                                       (l == 2) ? 1 : 0, af, ag_w, ag_b, ag_g, ag_bt, comb);
        float* t = cur; cur = po; po = t;
    }
    k_head1<<<40, 256, 0, stream>>>(comb, v_w1, a_w1, pv, pa);
    k_head2<<<1, 256, 0, stream>>>(pv, pa, v_b1, v_g, v_bt, v_w2, v_b2,
                                   a_b1, a_g, a_bt, a_w2, a_b2, (float*)d_out);
}

// Round 8
// 404.535 us; speedup vs baseline: 3.0207x; 1.0018x over previous
//
#include <hip/hip_runtime.h>
#include <math.h>

#define NN 10000
#define EE 320000
#define DD 256
#define NT 10001            // NN + virtual node
#define E1C (EE + NN)       // 330000
#define E2C (EE + 2 * NN)   // 340000
#define ETC (E2C + NT)      // 350001 (with self loops)
#define VB 157              // virtual-node partial blocks (64 rows each)

typedef __attribute__((ext_vector_type(8))) short s16x8;
typedef __attribute__((ext_vector_type(4))) float f32x4;

__device__ __forceinline__ unsigned short f2bf(float f) {
    unsigned u = __float_as_uint(f);
    return (unsigned short)((u + 0x7FFFu + ((u >> 16) & 1u)) >> 16);
}
__device__ __forceinline__ float bf2f(unsigned short u) {
    return __uint_as_float((unsigned)u << 16);
}

// ---------- reduction helpers ----------
__device__ __forceinline__ float wave_sum(float v) {
#pragma unroll
    for (int o = 32; o > 0; o >>= 1) v += __shfl_down(v, o, 64);
    return v;
}
__device__ __forceinline__ float blk_sum256(float v, float* sm4) {
    v = wave_sum(v);
    int lane = threadIdx.x & 63, w = threadIdx.x >> 6;
    __syncthreads();
    if (lane == 0) sm4[w] = v;
    __syncthreads();
    return sm4[0] + sm4[1] + sm4[2] + sm4[3];
}
// fused two-value block sum (one barrier pair)
__device__ __forceinline__ float2 blk_sum2(float a, float b, float2* sm4) {
#pragma unroll
    for (int o = 32; o > 0; o >>= 1) {
        a += __shfl_down(a, o, 64);
        b += __shfl_down(b, o, 64);
    }
    int lane = threadIdx.x & 63, w = threadIdx.x >> 6;
    __syncthreads();
    if (lane == 0) sm4[w] = make_float2(a, b);
    __syncthreads();
    float2 r;
    r.x = sm4[0].x + sm4[1].x + sm4[2].x + sm4[3].x;
    r.y = sm4[0].y + sm4[1].y + sm4[2].y + sm4[3].y;
    return r;
}

// ---------- node encoder: wave-per-row, no __syncthreads ----------
__global__ void __launch_bounds__(256) k_enc(
        const float* __restrict__ x, const float* __restrict__ wenc,
        const float* __restrict__ bia, const float* __restrict__ g,
        const float* __restrict__ bt, float* __restrict__ h,
        unsigned short* __restrict__ hb) {
    int t = threadIdx.x, lane = t & 63, wv = t >> 6;
    int v = blockIdx.x * 4 + wv;
    if (v >= NN) return;
    float xv = (lane < 10) ? x[v * 10 + lane] : 0.f;
    float4 acc = *(const float4*)(bia + lane * 4);
#pragma unroll
    for (int k = 0; k < 10; k++) {
        float xk = __shfl(xv, k, 64);
        float4 wk = *(const float4*)(wenc + k * DD + lane * 4);
        acc.x += xk * wk.x; acc.y += xk * wk.y; acc.z += xk * wk.z; acc.w += xk * wk.w;
    }
    float s1 = acc.x + acc.y + acc.z + acc.w;
    float s2 = acc.x * acc.x + acc.y * acc.y + acc.z * acc.z + acc.w * acc.w;
#pragma unroll
    for (int o = 32; o > 0; o >>= 1) {
        s1 += __shfl_xor(s1, o, 64);
        s2 += __shfl_xor(s2, o, 64);
    }
    float m = s1 * (1.f / DD);
    float var = s2 * (1.f / DD) - m * m;
    float rs = rsqrtf(var + 1e-5f);
    float4 g4 = *(const float4*)(g + lane * 4);
    float4 b4 = *(const float4*)(bt + lane * 4);
    float4 r4;
    r4.x = fmaxf((acc.x - m) * rs * g4.x + b4.x, 0.f);
    r4.y = fmaxf((acc.y - m) * rs * g4.y + b4.y, 0.f);
    r4.z = fmaxf((acc.z - m) * rs * g4.z + b4.z, 0.f);
    r4.w = fmaxf((acc.w - m) * rs * g4.w + b4.w, 0.f);
    *(float4*)(h + (size_t)v * DD + lane * 4) = r4;
    ushort4 u4;
    u4.x = f2bf(r4.x); u4.y = f2bf(r4.y); u4.z = f2bf(r4.z); u4.w = f2bf(r4.w);
    *(ushort4*)(hb + (size_t)v * DD + lane * 4) = u4;
}

// ---------- ctx stage 1 (+ fused regular-edge degree histogram) ----------
__global__ void __launch_bounds__(256) k_ctx1deg(const float* __restrict__ h,
                                                 float* __restrict__ part,
                                                 const int* __restrict__ ei,
                                                 int* __restrict__ degi) {
    __shared__ float4 sm[4][64];
    int t = threadIdx.x, lane = t & 63, w = t >> 6;
    int b = blockIdx.x;
    float4 acc = make_float4(0.f, 0.f, 0.f, 0.f);
    for (int v = b * 4 + w; v < NN; v += 1024) {
        float4 hv = *(const float4*)(h + (size_t)v * DD + lane * 4);
        acc.x += hv.x; acc.y += hv.y; acc.z += hv.z; acc.w += hv.w;
    }
    sm[w][lane] = acc;
    __syncthreads();
    if (t < 64) {
        float4 a0 = sm[0][t], a1 = sm[1][t], a2 = sm[2][t], a3 = sm[3][t];
        float4 r;
        r.x = a0.x + a1.x + a2.x + a3.x;
        r.y = a0.y + a1.y + a2.y + a3.y;
        r.z = a0.z + a1.z + a2.z + a3.z;
        r.w = a0.w + a1.w + a2.w + a3.w;
        *(float4*)(part + (size_t)b * DD + t * 4) = r;
    }
    // fused: regular-edge in-degree histogram (independent work)
    for (int e = b * 256 + t; e < EE; e += 256 * 256)
        atomicAdd(&degi[ei[EE + e]], 1);
}

// ---------- adaptive virtual node (+ fused ctx partial combine) ----------
__global__ void k_vn(const float* __restrict__ part,
                     const float* __restrict__ w1, const float* __restrict__ b1,
                     const float* __restrict__ g, const float* __restrict__ bt,
                     const float* __restrict__ w2, const float* __restrict__ b2,
                     const float* __restrict__ vnb,
                     float* __restrict__ h, unsigned short* __restrict__ hb,
                     float* __restrict__ comb) {
    __shared__ float2 sm4[4];
    __shared__ float cs[DD];
    __shared__ float t[DD];
    int j = threadIdx.x;
    float c = 0.f;
    for (int b = 0; b < 256; b++) c += part[(size_t)b * DD + j];
    cs[j] = c * (1.f / NN);
    __syncthreads();
    float acc = b1[j];
    for (int k = 0; k < DD; k++) acc += cs[k] * w1[k * DD + j];
    float2 mm = blk_sum2(acc, acc * acc, sm4);
    float m = mm.x * (1.f / DD);
    float var = mm.y * (1.f / DD) - m * m;
    float y = fmaxf((acc - m) * rsqrtf(var + 1e-5f) * g[j] + bt[j], 0.f);
    t[j] = y;
    __syncthreads();
    float a2 = b2[j];
    for (int k = 0; k < DD; k++) a2 += t[k] * w2[k * DD + j];
    float vn = vnb[j] + tanhf(a2);
    h[(size_t)NN * DD + j] = vn;
    hb[(size_t)NN * DD + j] = f2bf(vn);
    comb[j] = vn;   // jk slot 0 (virtual row of initial h)
}

// ---------- 1024-wide exclusive scan of (degR + virtual/self additions) ----------
__global__ void k_scan(const int* __restrict__ degi, int* __restrict__ offs,
                       int* __restrict__ cursor) {
    __shared__ int wsum[16];
    __shared__ int running_s;
    int t = threadIdx.x, lane = t & 63, w = t >> 6;
    if (t == 0) running_s = 0;
    __syncthreads();
    for (int base = 0; base < NT; base += 1024) {
        int v = base + t;
        int val = 0;
        if (v < NN) val = degi[v] + 2;          // + vn-edge + self-loop
        else if (v == NN) val = NN + 1;         // virtual: NN in-edges + self-loop
        int x = val;
#pragma unroll
        for (int o = 1; o < 64; o <<= 1) {
            int y = __shfl_up(x, o, 64);
            if (lane >= o) x += y;
        }
        if (lane == 63) wsum[w] = x;
        __syncthreads();
        int prefix = running_s;
        for (int ww = 0; ww < w; ww++) prefix += wsum[ww];
        if (v <= NN) { int e0 = prefix + x - val; offs[v] = e0; cursor[v] = e0; }
        __syncthreads();
        if (t == 0) {
            int s = 0;
            for (int i = 0; i < 16; i++) s += wsum[i];
            running_s += s;
        }
        __syncthreads();
    }
    if (threadIdx.x == 0) offs[NT] = running_s;
}

// ---------- scatter regular edges into CSR (split src / eid arrays) ----------
__global__ void k_scatter(const int* __restrict__ ei, int* __restrict__ cursor,
                          int* __restrict__ ssrc, int* __restrict__ seid) {
    int e = blockIdx.x * 256 + threadIdx.x;
    if (e >= EE) return;
    int src = ei[e], dst = ei[EE + e];
    int pos = atomicAdd(&cursor[dst], 1);
    ssrc[pos] = src;
    seid[pos] = e;
}

// ---------- fused: fill deterministic CSR slots + loop_attr segmented sums ----------
__global__ void k_flattr(const int* __restrict__ offs, int* __restrict__ ssrc,
                         int* __restrict__ seid,
                         const float* __restrict__ ea, float* __restrict__ lattr) {
    int t = threadIdx.x, lane = t & 63, w = t >> 6;
    int v = blockIdx.x * 4 + w;
    if (v > NN) return;
    int bN = offs[NN];
    if (v == NN) {
        if (lane == 0) {
            lattr[v * 3] = 0.5f; lattr[v * 3 + 1] = 0.f; lattr[v * 3 + 2] = 0.f;
            ssrc[bN + NN] = NN; seid[bN + NN] = E2C + NN;   // virtual self loop
        }
        return;
    }
    int b0 = offs[v], e1 = offs[v + 1];
    if (lane == 0) {
        ssrc[e1 - 2] = NN; seid[e1 - 2] = EE + v;       // vn -> v
        ssrc[e1 - 1] = v;  seid[e1 - 1] = E2C + v;      // self loop
        ssrc[bN + v] = v;  seid[bN + v] = E1C + v;      // v -> vn (virtual segment)
    }
    int cnt = e1 - b0 - 2;                       // regular in-edges
    float s0 = 0.f, s1 = 0.f, s2 = 0.f;
    for (int i = lane; i < cnt; i += 64) {
        int e = seid[b0 + i];
        s0 += ea[e * 3];
        s1 += ea[e * 3 + 1];
        s2 += ea[e * 3 + 2];
    }
    s0 = wave_sum(s0); s1 = wave_sum(s1); s2 = wave_sum(s2);
    if (lane == 0) {
        float inv = 1.f / (float)(cnt + 1);      // deg0 = regular + vn edge
        lattr[v * 3]     = (s0 + 0.5f) * inv;
        lattr[v * 3 + 1] = s1 * inv;
        lattr[v * 3 + 2] = s2 * inv;
    }
}

// ---------- weight transpose (blocks 0..767) + we_dot (block 768) ----------
__global__ void k_wconv(const float* __restrict__ gw, unsigned short* __restrict__ wt,
                        const float* __restrict__ ew, const float* __restrict__ ae,
                        float* __restrict__ wd) {
    int b = blockIdx.x, j = threadIdx.x;
    if (b == 768) {
        if (j >= 36) return;
        int l = j / 12, k = (j / 4) % 3, h = j % 4;
        float s = 0.f;
        for (int c = 0; c < 64; c++)
            s += ew[l * 768 + k * DD + h * 64 + c] * ae[l * DD + h * 64 + c];
        wd[j] = s;   // layout [l][k][h]
        return;
    }
    int l = b >> 8, k = b & 255;
    float v = gw[l * 65536 + k * 256 + j];
    wt[l * 65536 + j * 256 + k] = f2bf(v);
}

// ---------- per-edge, per-layer, per-head edge-attr dots, bf16 packed ----------
__global__ void k_edot(const int* __restrict__ seid, const float* __restrict__ ea,
                       const float* __restrict__ lattr, const float* __restrict__ wd,
                       unsigned short* __restrict__ edot) {
    int p = blockIdx.x * 256 + threadIdx.x;
    if (p >= ETC) return;
    int e = seid[p];
    float a0, a1, a2;
    if (e < EE)       { a0 = ea[e * 3]; a1 = ea[e * 3 + 1]; a2 = ea[e * 3 + 2]; }
    else if (e < E2C) { a0 = 0.5f; a1 = 0.f; a2 = 0.f; }
    else              { int v = e - E2C; a0 = lattr[v * 3]; a1 = lattr[v * 3 + 1]; a2 = lattr[v * 3 + 2]; }
#pragma unroll
    for (int l = 0; l < 3; l++) {
        ushort4 o;
        o.x = f2bf(a0 * wd[l * 12 + 0] + a1 * wd[l * 12 + 4] + a2 * wd[l * 12 + 8]);
        o.y = f2bf(a0 * wd[l * 12 + 1] + a1 * wd[l * 12 + 5] + a2 * wd[l * 12 + 9]);
        o.z = f2bf(a0 * wd[l * 12 + 2] + a1 * wd[l * 12 + 6] + a2 * wd[l * 12 + 10]);
        o.w = f2bf(a0 * wd[l * 12 + 3] + a1 * wd[l * 12 + 7] + a2 * wd[l * 12 + 11]);
        *(ushort4*)(edot + (size_t)l * ETC * 4 + (size_t)p * 4) = o;
    }
}

// ---------- xs = h @ W via bf16 MFMA, N-split: 314 blocks (64 rows x 128 cols) ----------
__global__ void __launch_bounds__(256) k_gemm_mfma(
        const unsigned short* __restrict__ hb, const unsigned short* __restrict__ wt,
        const float* __restrict__ as_, const float* __restrict__ ad_,
        unsigned short* __restrict__ xsb, float* __restrict__ als, float* __restrict__ ald) {
    __shared__ unsigned short tile[64][128];
    int bx = blockIdx.x;
    int v0 = (bx >> 1) * 64;
    int n0 = (bx & 1) * 128;          // column offset; heads hg0 = n0/64 .. +1
    int t = threadIdx.x, lane = t & 63, w = t >> 6;
    int rbase = v0 + w * 16;
    int li = lane & 15, g = lane >> 4;
    int arow = rbase + li; if (arow > NN) arow = NN;
    int koff = g * 8;
    const unsigned short* aptr = hb + (size_t)arow * DD + koff;
    const unsigned short* bptr = wt + (size_t)(n0 + li) * DD + koff;
    f32x4 acc[8];
#pragma unroll
    for (int n = 0; n < 8; n++) acc[n] = (f32x4){0.f, 0.f, 0.f, 0.f};
#pragma unroll
    for (int kb = 0; kb < 8; kb++) {
        s16x8 af = *(const s16x8*)(aptr + kb * 32);
#pragma unroll
        for (int n = 0; n < 8; n++) {
            s16x8 bf = *(const s16x8*)(bptr + (size_t)n * 16 * DD + kb * 32);
            acc[n] = __builtin_amdgcn_mfma_f32_16x16x32_bf16(af, bf, acc[n], 0, 0, 0);
        }
    }
    float asv[8], adv[8];
#pragma unroll
    for (int n = 0; n < 8; n++) { asv[n] = as_[n0 + n * 16 + li]; adv[n] = ad_[n0 + n * 16 + li]; }
    int hg0 = n0 >> 6;
#pragma unroll
    for (int r = 0; r < 4; r++) {
        int vrow = rbase + 4 * g + r;
#pragma unroll
        for (int h = 0; h < 2; h++) {
            float ps = acc[4 * h][r] * asv[4 * h] + acc[4 * h + 1][r] * asv[4 * h + 1]
                     + acc[4 * h + 2][r] * asv[4 * h + 2] + acc[4 * h + 3][r] * asv[4 * h + 3];
            float pd = acc[4 * h][r] * adv[4 * h] + acc[4 * h + 1][r] * adv[4 * h + 1]
                     + acc[4 * h + 2][r] * adv[4 * h + 2] + acc[4 * h + 3][r] * adv[4 * h + 3];
#pragma unroll
            for (int o = 1; o < 16; o <<= 1) {
                ps += __shfl_xor(ps, o, 64);
                pd += __shfl_xor(pd, o, 64);
            }
            if (li == 0 && vrow <= NN) { als[vrow * 4 + hg0 + h] = ps; ald[vrow * 4 + hg0 + h] = pd; }
        }
    }
#pragma unroll
    for (int n = 0; n < 8; n++)
#pragma unroll
        for (int r = 0; r < 4; r++)
            tile[w * 16 + 4 * g + r][n * 16 + li] = f2bf(acc[n][r]);
    // wave-local rows: 16 rows x 16 c8-slots = 256 slots, 4 iters of 64 lanes
#pragma unroll
    for (int it = 0; it < 4; it++) {
        int flat = it * 64 + lane;
        int row = w * 16 + (flat >> 4);
        int c8 = flat & 15;
        int vrow = v0 + row;
        if (vrow <= NN)
            *(uint4*)(xsb + (size_t)vrow * DD + n0 + c8 * 8) = *(const uint4*)(&tile[row][c8 * 8]);
    }
}

// ---------- single-pass softmax-aggregation + fused LN/residual epilogue ----------
// blocks [0..NN): regular dst; block NN: skip; blocks [NT..NT+VB): virtual partials
// last virtual block (fan-in) performs vpost (+ agent encoder on last layer)
__global__ void __launch_bounds__(256) k_msg(
        const int* __restrict__ offs, const int* __restrict__ ssrc,
        const unsigned short* __restrict__ edotL,
        const float* __restrict__ als, const float* __restrict__ ald,
        const unsigned short* __restrict__ xsb,
        const float* __restrict__ bias, const float* __restrict__ g,
        const float* __restrict__ bt, const float* __restrict__ hin,
        float* __restrict__ hout, unsigned short* __restrict__ hbout,
        float* __restrict__ pvacc, float* __restrict__ pws,
        int* __restrict__ cnt, float* __restrict__ jkslot,
        int last, const float* __restrict__ af,
        const float* __restrict__ agw, const float* __restrict__ agb,
        const float* __restrict__ agg, const float* __restrict__ agbt,
        float* __restrict__ comb) {
    int v = blockIdx.x;
    if (v == NN) return;
    int t = threadIdx.x, lane = t & 63, w = t >> 6;
    int sub = lane >> 5, l32 = lane & 31, slot = w * 2 + sub;
    int hh = l32 >> 3;
    __shared__ float red[4][8][33];
    __shared__ float wsred[4][4];
    __shared__ float fin[4];
    __shared__ float2 sm4[4];
    __shared__ int islast;
    float acc[8];
#pragma unroll
    for (int q = 0; q < 8; q++) acc[q] = 0.f;
    float swt = 0.f;
    if (v >= NT) {
        // ---- virtual-node partial block b = v - NT over rows [b*64, b*64+64) ----
        int b = v - NT;
        int b0 = offs[NN];
        float adh = ald[NN * 4 + hh];
        int i0 = b * 64, i1 = i0 + 64;
        if (i1 > NN + 1) i1 = NN + 1;
        for (int i = i0 + slot; i < i1; i += 8) {
            float a = als[i * 4 + hh] + bf2f(edotL[(size_t)(b0 + i) * 4 + hh]) + adh;
            a = a > 0.f ? a : 0.2f * a;
            float wt = __expf(a);
            uint4 xq = *(const uint4*)(xsb + (size_t)i * DD + l32 * 8);
            const unsigned short* xp = (const unsigned short*)&xq;
#pragma unroll
            for (int q = 0; q < 8; q++) acc[q] += wt * bf2f(xp[q]);
            if ((l32 & 7) == 0) swt += wt;
        }
#pragma unroll
        for (int q = 0; q < 8; q++) acc[q] += __shfl_xor(acc[q], 32, 64);
        swt += __shfl_xor(swt, 32, 64);
        if (sub == 0) {
#pragma unroll
            for (int q = 0; q < 8; q++) red[w][q][l32] = acc[q];
            if ((l32 & 7) == 0) wsred[w][hh] = swt;
        }
        __syncthreads();
        int c = t, q = c & 7, l = c >> 3;
        pvacc[(size_t)b * DD + c] = red[0][q][l] + red[1][q][l] + red[2][q][l] + red[3][q][l];
        if (t < 4) pws[b * 4 + t] = wsred[0][t] + wsred[1][t] + wsred[2][t] + wsred[3][t];
        // ---- fan-in: last-finished virtual block performs vpost ----
        __threadfence();
        if (t == 0) islast = (atomicAdd(cnt, 1) == VB - 1) ? 1 : 0;
        __syncthreads();
        if (!islast) return;
        __threadfence();
        int j = t, hh4 = j >> 6;
        float va = 0.f;
        for (int bb = 0; bb < VB; bb++) va += pvacc[(size_t)bb * DD + j];
        float ws = 0.f;
        for (int bb = 0; bb < VB; bb++) ws += pws[bb * 4 + hh4];
        float o = va / (ws + 1e-16f);
        float tt = o + bias[j];
        float2 mm = blk_sum2(tt, tt * tt, sm4);
        float m = mm.x * (1.f / DD);
        float var = mm.y * (1.f / DD) - m * m;
        float y = (tt - m) * rsqrtf(var + 1e-5f) * g[j] + bt[j];
        float r = fmaxf(y + hin[(size_t)NN * DD + j], 0.f);
        hout[(size_t)NN * DD + j] = r;
        hbout[(size_t)NN * DD + j] = f2bf(r);
        jkslot[j] = r;
        if (last) {
            float a2 = agb[j];
#pragma unroll
            for (int k = 0; k < 10; k++) a2 += af[k] * agw[k * DD + j];
            float2 m2 = blk_sum2(a2, a2 * a2, sm4);
            float mu = m2.x * (1.f / DD);
            float vv = m2.y * (1.f / DD) - mu * mu;
            float ya = (a2 - mu) * rsqrtf(vv + 1e-5f) * agg[j] + agbt[j];
            comb[1024 + j] = fmaxf(ya, 0.f);
        }
        return;
    }
    // ---- regular dst ----
    int b0 = offs[v], deg = offs[v + 1] - b0;
    float adh = ald[v * 4 + hh];
    for (int i = slot; i < deg; i += 8) {
        int p = b0 + i;
        int src = ssrc[p];
        float a = als[src * 4 + hh] + bf2f(edotL[(size_t)p * 4 + hh]) + adh;
        a = a > 0.f ? a : 0.2f * a;
        float wt = __expf(a);
        uint4 xq = *(const uint4*)(xsb + (size_t)src * DD + l32 * 8);
        const unsigned short* xp = (const unsigned short*)&xq;
#pragma unroll
        for (int q = 0; q < 8; q++) acc[q] += wt * bf2f(xp[q]);
        if ((l32 & 7) == 0) swt += wt;
    }
#pragma unroll
    for (int q = 0; q < 8; q++) acc[q] += __shfl_xor(acc[q], 32, 64);
    swt += __shfl_xor(swt, 32, 64);
    if (sub == 0) {
#pragma unroll
        for (int q = 0; q < 8; q++) red[w][q][l32] = acc[q];   // conflict-free
        if ((l32 & 7) == 0) wsred[w][hh] = swt;
    }
    __syncthreads();
    if (t < 4) {
        float ws = wsred[0][t] + wsred[1][t] + wsred[2][t] + wsred[3][t];
        fin[t] = 1.f / (ws + 1e-16f);
    }
    __syncthreads();
    int c = t, q = c & 7, l = c >> 3;
    float o = (red[0][q][l] + red[1][q][l] + red[2][q][l] + red[3][q][l]) * fin[c >> 6];
    float tt = o + bias[c];
    float2 mm = blk_sum2(tt, tt * tt, sm4);
    float m = mm.x * (1.f / DD);
    float var = mm.y * (1.f / DD) - m * m;
    float y = (tt - m) * rsqrtf(var + 1e-5f) * g[c] + bt[c];
    float r = fmaxf(y + hin[(size_t)v * DD + c], 0.f);
    hout[(size_t)v * DD + c] = r;
    hbout[(size_t)v * DD + c] = f2bf(r);
}

// ---------- dueling head: 40 k-slice blocks + fan-in final block ----------
__global__ void k_head(const float* __restrict__ comb,
                       const float* __restrict__ vw1, const float* __restrict__ aw1,
                       float* __restrict__ pv, float* __restrict__ pa,
                       int* __restrict__ cnt,
                       const float* __restrict__ vb1, const float* __restrict__ vg,
                       const float* __restrict__ vbt, const float* __restrict__ vw2,
                       const float* __restrict__ vb2,
                       const float* __restrict__ ab1, const float* __restrict__ ag,
                       const float* __restrict__ abt, const float* __restrict__ aw2,
                       const float* __restrict__ ab2, float* __restrict__ out) {
    __shared__ float2 sm4[4];
    __shared__ float sm1[4];
    __shared__ float tl[DD];
    __shared__ float adv[9];
    __shared__ float valv;
    __shared__ int islast;
    int j = threadIdx.x, s = blockIdx.x;
    int k0 = s * 32;
    float accv = 0.f, acca = 0.f;
#pragma unroll
    for (int kk = 0; kk < 32; kk++) {
        float c = comb[k0 + kk];
        accv += c * vw1[(k0 + kk) * DD + j];
        acca += c * aw1[(k0 + kk) * DD + j];
    }
    pv[s * DD + j] = accv;
    pa[s * DD + j] = acca;
    __threadfence();
    if (j == 0) islast = (atomicAdd(cnt, 1) == 39) ? 1 : 0;
    __syncthreads();
    if (!islast) return;
    __threadfence();
    float acc = vb1[j], acc2 = ab1[j];
    for (int ss = 0; ss < 40; ss++) { acc += pv[ss * DD + j]; acc2 += pa[ss * DD + j]; }
    float2 mm = blk_sum2(acc, acc * acc, sm4);
    float m = mm.x * (1.f / DD);
    float var = mm.y * (1.f / DD) - m * m;
    float y = fmaxf((acc - m) * rsqrtf(var + 1e-5f) * vg[j] + vbt[j], 0.f);
    float vs = blk_sum256(y * vw2[j], sm1);
    if (j == 0) valv = vs + vb2[0];
    float2 mm2 = blk_sum2(acc2, acc2 * acc2, sm4);
    float m2 = mm2.x * (1.f / DD);
    float var2 = mm2.y * (1.f / DD) - m2 * m2;
    float y2 = fmaxf((acc2 - m2) * rsqrtf(var2 + 1e-5f) * ag[j] + abt[j], 0.f);
    tl[j] = y2;
    __syncthreads();
    if (j < 9) {
        float ss = ab2[j];
        for (int k = 0; k < DD; k++) ss += tl[k] * aw2[k * 9 + j];
        adv[j] = ss;
    }
    __syncthreads();
    if (j < 9) {
        float mean = 0.f;
        for (int o = 0; o < 9; o++) mean += adv[o];
        mean *= (1.f / 9.f);
        out[j] = valv + adv[j] - mean;
    }
}

extern "C" void kernel_launch(void* const* d_in, const int* in_sizes, int n_in,
                              void* d_out, int out_size, void* d_ws, size_t ws_size,
                              hipStream_t stream) {
    (void)in_sizes; (void)n_in; (void)out_size; (void)ws_size;
    const float* x      = (const float*)d_in[0];
    const int*   ei     = (const int*)d_in[1];
    const float* ea     = (const float*)d_in[2];
    const float* af     = (const float*)d_in[3];
    const float* enc_w  = (const float*)d_in[4];
    const float* enc_b  = (const float*)d_in[5];
    const float* enc_g  = (const float*)d_in[6];
    const float* enc_bt = (const float*)d_in[7];
    const float* vn_base= (const float*)d_in[8];
    const float* vn_w1  = (const float*)d_in[9];
    const float* vn_b1  = (const float*)d_in[10];
    const float* vn_g   = (const float*)d_in[11];
    const float* vn_bt  = (const float*)d_in[12];
    const float* vn_w2  = (const float*)d_in[13];
    const float* vn_b2  = (const float*)d_in[14];
    const float* gat_w  = (const float*)d_in[15];
    const float* att_src= (const float*)d_in[16];
    const float* att_dst= (const float*)d_in[17];
    const float* att_edge=(const float*)d_in[18];
    const float* edge_w = (const float*)d_in[19];
    const float* gat_b  = (const float*)d_in[20];
    const float* ln_g   = (const float*)d_in[21];
    const float* ln_b   = (const float*)d_in[22];
    const float* ag_w   = (const float*)d_in[23];
    const float* ag_b   = (const float*)d_in[24];
    const float* ag_g   = (const float*)d_in[25];
    const float* ag_bt  = (const float*)d_in[26];
    const float* v_w1   = (const float*)d_in[27];
    const float* v_b1   = (const float*)d_in[28];
    const float* v_g    = (const float*)d_in[29];
    const float* v_bt   = (const float*)d_in[30];
    const float* v_w2   = (const float*)d_in[31];
    const float* v_b2   = (const float*)d_in[32];
    const float* a_w1   = (const float*)d_in[33];
    const float* a_b1   = (const float*)d_in[34];
    const float* a_g    = (const float*)d_in[35];
    const float* a_bt   = (const float*)d_in[36];
    const float* a_w2   = (const float*)d_in[37];
    const float* a_b2   = (const float*)d_in[38];

    char* p = (char*)d_ws;
    auto alloc = [&](size_t bytes) {
        char* r = p;
        p += (bytes + 255) & ~(size_t)255;
        return r;
    };
    float* big0  = (float*)alloc((size_t)NT * DD * 4);
    float* big2  = (float*)alloc((size_t)NT * DD * 4);
    unsigned short* hb   = (unsigned short*)alloc((size_t)NT * DD * 2);
    unsigned short* xsb  = (unsigned short*)alloc((size_t)NT * DD * 2);
    unsigned short* wt   = (unsigned short*)alloc((size_t)3 * DD * DD * 2);
    unsigned short* edot = (unsigned short*)alloc((size_t)3 * ETC * 4 * 2);
    int* ssrc    = (int*)alloc((size_t)ETC * 4);
    int* seid    = (int*)alloc((size_t)ETC * 4);
    float* als   = (float*)alloc((size_t)NT * 4 * 4);
    float* ald   = (float*)alloc((size_t)NT * 4 * 4);
    float* part  = (float*)alloc((size_t)256 * DD * 4);
    float* comb  = (float*)alloc(1280 * 4);
    float* lattr = (float*)alloc((size_t)NT * 3 * 4);
    float* wd    = (float*)alloc(36 * 4);
    float* pvacc = (float*)alloc((size_t)VB * DD * 4);
    float* pws   = (float*)alloc((size_t)VB * 4 * 4);
    float* pv    = (float*)alloc(40 * DD * 4);
    float* pa    = (float*)alloc(40 * DD * 4);
    int* degi    = (int*)alloc((size_t)(NT + 16) * 4);   // degi[NT] then 4 fan-in counters
    int* cnt     = degi + NT;
    int* offs    = (int*)alloc((size_t)(NT + 1) * 4);
    int* cursor  = (int*)alloc((size_t)NT * 4);

    hipMemsetAsync(degi, 0, (size_t)(NT + 16) * 4, stream);

    k_enc<<<2500, 256, 0, stream>>>(x, enc_w, enc_b, enc_g, enc_bt, big0, hb);
    k_ctx1deg<<<256, 256, 0, stream>>>(big0, part, ei, degi);
    k_vn<<<1, 256, 0, stream>>>(part, vn_w1, vn_b1, vn_g, vn_bt, vn_w2, vn_b2, vn_base, big0, hb, comb);
    k_scan<<<1, 1024, 0, stream>>>(degi, offs, cursor);
    k_scatter<<<(EE + 255) / 256, 256, 0, stream>>>(ei, cursor, ssrc, seid);
    k_flattr<<<(NT + 3) / 4, 256, 0, stream>>>(offs, ssrc, seid, ea, lattr);
    k_wconv<<<769, 256, 0, stream>>>(gat_w, wt, edge_w, att_edge, wd);
    k_edot<<<(ETC + 255) / 256, 256, 0, stream>>>(seid, ea, lattr, wd, edot);

    float* cur = big0;
    float* po  = big2;
    for (int l = 0; l < 3; l++) {
        const unsigned short* edotL = edot + (size_t)l * ETC * 4;
        k_gemm_mfma<<<((NT + 63) / 64) * 2, 256, 0, stream>>>(hb, wt + (size_t)l * DD * DD,
                                                              att_src + l * DD, att_dst + l * DD,
                                                              xsb, als, ald);
        k_msg<<<NT + VB, 256, 0, stream>>>(offs, ssrc, edotL, als, ald, xsb,
                                           gat_b + l * DD, ln_g + l * DD, ln_b + l * DD,
                                           cur, po, hb, pvacc, pws, cnt + l,
                                           comb + (l + 1) * DD, (l == 2) ? 1 : 0,
                                           af, ag_w, ag_b, ag_g, ag_bt, comb);
        float* t = cur; cur = po; po = t;
    }
    k_head<<<40, 256, 0, stream>>>(comb, v_w1, a_w1, pv, pa, cnt + 3,
                                   v_b1, v_g, v_bt, v_w2, v_b2,
                                   a_b1, a_g, a_bt, a_w2, a_b2, (float*)d_out);
}

// Round 9
// 368.289 us; speedup vs baseline: 3.3180x; 1.0984x over previous
//
#include <hip/hip_runtime.h>
#include <math.h>

#define NN 10000
#define EE 320000
#define DD 256
#define NT 10001            // NN + virtual node
#define E1C (EE + NN)       // 330000
#define E2C (EE + 2 * NN)   // 340000
#define ETC (E2C + NT)      // 350001 (with self loops)
#define VB 157              // virtual-node partial blocks (64 rows each)

typedef __attribute__((ext_vector_type(8))) short s16x8;
typedef __attribute__((ext_vector_type(4))) float f32x4;

__device__ __forceinline__ unsigned short f2bf(float f) {
    unsigned u = __float_as_uint(f);
    return (unsigned short)((u + 0x7FFFu + ((u >> 16) & 1u)) >> 16);
}
__device__ __forceinline__ float bf2f(unsigned short u) {
    return __uint_as_float((unsigned)u << 16);
}

// ---------- reduction helpers ----------
__device__ __forceinline__ float wave_sum(float v) {
#pragma unroll
    for (int o = 32; o > 0; o >>= 1) v += __shfl_down(v, o, 64);
    return v;
}
__device__ __forceinline__ float blk_sum256(float v, float* sm4) {
    v = wave_sum(v);
    int lane = threadIdx.x & 63, w = threadIdx.x >> 6;
    __syncthreads();
    if (lane == 0) sm4[w] = v;
    __syncthreads();
    return sm4[0] + sm4[1] + sm4[2] + sm4[3];
}
// fused two-value block sum (one barrier pair)
__device__ __forceinline__ float2 blk_sum2(float a, float b, float2* sm4) {
#pragma unroll
    for (int o = 32; o > 0; o >>= 1) {
        a += __shfl_down(a, o, 64);
        b += __shfl_down(b, o, 64);
    }
    int lane = threadIdx.x & 63, w = threadIdx.x >> 6;
    __syncthreads();
    if (lane == 0) sm4[w] = make_float2(a, b);
    __syncthreads();
    float2 r;
    r.x = sm4[0].x + sm4[1].x + sm4[2].x + sm4[3].x;
    r.y = sm4[0].y + sm4[1].y + sm4[2].y + sm4[3].y;
    return r;
}

// ---------- node encoder: wave-per-row, no __syncthreads ----------
__global__ void __launch_bounds__(256) k_enc(
        const float* __restrict__ x, const float* __restrict__ wenc,
        const float* __restrict__ bia, const float* __restrict__ g,
        const float* __restrict__ bt, float* __restrict__ h,
        unsigned short* __restrict__ hb) {
    int t = threadIdx.x, lane = t & 63, wv = t >> 6;
    int v = blockIdx.x * 4 + wv;
    if (v >= NN) return;
    float xv = (lane < 10) ? x[v * 10 + lane] : 0.f;
    float4 acc = *(const float4*)(bia + lane * 4);
#pragma unroll
    for (int k = 0; k < 10; k++) {
        float xk = __shfl(xv, k, 64);
        float4 wk = *(const float4*)(wenc + k * DD + lane * 4);
        acc.x += xk * wk.x; acc.y += xk * wk.y; acc.z += xk * wk.z; acc.w += xk * wk.w;
    }
    float s1 = acc.x + acc.y + acc.z + acc.w;
    float s2 = acc.x * acc.x + acc.y * acc.y + acc.z * acc.z + acc.w * acc.w;
#pragma unroll
    for (int o = 32; o > 0; o >>= 1) {
        s1 += __shfl_xor(s1, o, 64);
        s2 += __shfl_xor(s2, o, 64);
    }
    float m = s1 * (1.f / DD);
    float var = s2 * (1.f / DD) - m * m;
    float rs = rsqrtf(var + 1e-5f);
    float4 g4 = *(const float4*)(g + lane * 4);
    float4 b4 = *(const float4*)(bt + lane * 4);
    float4 r4;
    r4.x = fmaxf((acc.x - m) * rs * g4.x + b4.x, 0.f);
    r4.y = fmaxf((acc.y - m) * rs * g4.y + b4.y, 0.f);
    r4.z = fmaxf((acc.z - m) * rs * g4.z + b4.z, 0.f);
    r4.w = fmaxf((acc.w - m) * rs * g4.w + b4.w, 0.f);
    *(float4*)(h + (size_t)v * DD + lane * 4) = r4;
    ushort4 u4;
    u4.x = f2bf(r4.x); u4.y = f2bf(r4.y); u4.z = f2bf(r4.z); u4.w = f2bf(r4.w);
    *(ushort4*)(hb + (size_t)v * DD + lane * 4) = u4;
}

// ---------- ctx stage 1 (+ fused regular-edge degree histogram) ----------
__global__ void __launch_bounds__(256) k_ctx1deg(const float* __restrict__ h,
                                                 float* __restrict__ part,
                                                 const int* __restrict__ ei,
                                                 int* __restrict__ degi) {
    __shared__ float4 sm[4][64];
    int t = threadIdx.x, lane = t & 63, w = t >> 6;
    int b = blockIdx.x;
    float4 acc = make_float4(0.f, 0.f, 0.f, 0.f);
    for (int v = b * 4 + w; v < NN; v += 1024) {
        float4 hv = *(const float4*)(h + (size_t)v * DD + lane * 4);
        acc.x += hv.x; acc.y += hv.y; acc.z += hv.z; acc.w += hv.w;
    }
    sm[w][lane] = acc;
    __syncthreads();
    if (t < 64) {
        float4 a0 = sm[0][t], a1 = sm[1][t], a2 = sm[2][t], a3 = sm[3][t];
        float4 r;
        r.x = a0.x + a1.x + a2.x + a3.x;
        r.y = a0.y + a1.y + a2.y + a3.y;
        r.z = a0.z + a1.z + a2.z + a3.z;
        r.w = a0.w + a1.w + a2.w + a3.w;
        *(float4*)(part + (size_t)b * DD + t * 4) = r;
    }
    // fused: regular-edge in-degree histogram (independent work)
    for (int e = b * 256 + t; e < EE; e += 256 * 256)
        atomicAdd(&degi[ei[EE + e]], 1);
}

// ---------- adaptive virtual node (+ fused ctx partial combine) ----------
__global__ void k_vn(const float* __restrict__ part,
                     const float* __restrict__ w1, const float* __restrict__ b1,
                     const float* __restrict__ g, const float* __restrict__ bt,
                     const float* __restrict__ w2, const float* __restrict__ b2,
                     const float* __restrict__ vnb,
                     float* __restrict__ h, unsigned short* __restrict__ hb,
                     float* __restrict__ comb) {
    __shared__ float2 sm4[4];
    __shared__ float cs[DD];
    __shared__ float t[DD];
    int j = threadIdx.x;
    float c = 0.f;
    for (int b = 0; b < 256; b++) c += part[(size_t)b * DD + j];
    cs[j] = c * (1.f / NN);
    __syncthreads();
    float acc = b1[j];
    for (int k = 0; k < DD; k++) acc += cs[k] * w1[k * DD + j];
    float2 mm = blk_sum2(acc, acc * acc, sm4);
    float m = mm.x * (1.f / DD);
    float var = mm.y * (1.f / DD) - m * m;
    float y = fmaxf((acc - m) * rsqrtf(var + 1e-5f) * g[j] + bt[j], 0.f);
    t[j] = y;
    __syncthreads();
    float a2 = b2[j];
    for (int k = 0; k < DD; k++) a2 += t[k] * w2[k * DD + j];
    float vn = vnb[j] + tanhf(a2);
    h[(size_t)NN * DD + j] = vn;
    hb[(size_t)NN * DD + j] = f2bf(vn);
    comb[j] = vn;   // jk slot 0 (virtual row of initial h)
}

// ---------- 1024-wide exclusive scan of (degR + virtual/self additions) ----------
__global__ void k_scan(const int* __restrict__ degi, int* __restrict__ offs,
                       int* __restrict__ cursor) {
    __shared__ int wsum[16];
    __shared__ int running_s;
    int t = threadIdx.x, lane = t & 63, w = t >> 6;
    if (t == 0) running_s = 0;
    __syncthreads();
    for (int base = 0; base < NT; base += 1024) {
        int v = base + t;
        int val = 0;
        if (v < NN) val = degi[v] + 2;          // + vn-edge + self-loop
        else if (v == NN) val = NN + 1;         // virtual: NN in-edges + self-loop
        int x = val;
#pragma unroll
        for (int o = 1; o < 64; o <<= 1) {
            int y = __shfl_up(x, o, 64);
            if (lane >= o) x += y;
        }
        if (lane == 63) wsum[w] = x;
        __syncthreads();
        int prefix = running_s;
        for (int ww = 0; ww < w; ww++) prefix += wsum[ww];
        if (v <= NN) { int e0 = prefix + x - val; offs[v] = e0; cursor[v] = e0; }
        __syncthreads();
        if (t == 0) {
            int s = 0;
            for (int i = 0; i < 16; i++) s += wsum[i];
            running_s += s;
        }
        __syncthreads();
    }
    if (threadIdx.x == 0) offs[NT] = running_s;
}

// ---------- scatter regular edges into CSR (split src / eid arrays) ----------
__global__ void k_scatter(const int* __restrict__ ei, int* __restrict__ cursor,
                          int* __restrict__ ssrc, int* __restrict__ seid) {
    int e = blockIdx.x * 256 + threadIdx.x;
    if (e >= EE) return;
    int src = ei[e], dst = ei[EE + e];
    int pos = atomicAdd(&cursor[dst], 1);
    ssrc[pos] = src;
    seid[pos] = e;
}

// ---------- fused: fill deterministic CSR slots + loop_attr segmented sums ----------
__global__ void k_flattr(const int* __restrict__ offs, int* __restrict__ ssrc,
                         int* __restrict__ seid,
                         const float* __restrict__ ea, float* __restrict__ lattr) {
    int t = threadIdx.x, lane = t & 63, w = t >> 6;
    int v = blockIdx.x * 4 + w;
    if (v > NN) return;
    int bN = offs[NN];
    if (v == NN) {
        if (lane == 0) {
            lattr[v * 3] = 0.5f; lattr[v * 3 + 1] = 0.f; lattr[v * 3 + 2] = 0.f;
            ssrc[bN + NN] = NN; seid[bN + NN] = E2C + NN;   // virtual self loop
        }
        return;
    }
    int b0 = offs[v], e1 = offs[v + 1];
    if (lane == 0) {
        ssrc[e1 - 2] = NN; seid[e1 - 2] = EE + v;       // vn -> v
        ssrc[e1 - 1] = v;  seid[e1 - 1] = E2C + v;      // self loop
        ssrc[bN + v] = v;  seid[bN + v] = E1C + v;      // v -> vn (virtual segment)
    }
    int cnt = e1 - b0 - 2;                       // regular in-edges
    float s0 = 0.f, s1 = 0.f, s2 = 0.f;
    for (int i = lane; i < cnt; i += 64) {
        int e = seid[b0 + i];
        s0 += ea[e * 3];
        s1 += ea[e * 3 + 1];
        s2 += ea[e * 3 + 2];
    }
    s0 = wave_sum(s0); s1 = wave_sum(s1); s2 = wave_sum(s2);
    if (lane == 0) {
        float inv = 1.f / (float)(cnt + 1);      // deg0 = regular + vn edge
        lattr[v * 3]     = (s0 + 0.5f) * inv;
        lattr[v * 3 + 1] = s1 * inv;
        lattr[v * 3 + 2] = s2 * inv;
    }
}

// ---------- weight transpose (blocks 0..767) + we_dot (block 768) ----------
__global__ void k_wconv(const float* __restrict__ gw, unsigned short* __restrict__ wt,
                        const float* __restrict__ ew, const float* __restrict__ ae,
                        float* __restrict__ wd) {
    int b = blockIdx.x, j = threadIdx.x;
    if (b == 768) {
        if (j >= 36) return;
        int l = j / 12, k = (j / 4) % 3, h = j % 4;
        float s = 0.f;
        for (int c = 0; c < 64; c++)
            s += ew[l * 768 + k * DD + h * 64 + c] * ae[l * DD + h * 64 + c];
        wd[j] = s;   // layout [l][k][h]
        return;
    }
    int l = b >> 8, k = b & 255;
    float v = gw[l * 65536 + k * 256 + j];
    wt[l * 65536 + j * 256 + k] = f2bf(v);
}

// ---------- per-edge, per-layer, per-head edge-attr dots, bf16 packed ----------
__global__ void k_edot(const int* __restrict__ seid, const float* __restrict__ ea,
                       const float* __restrict__ lattr, const float* __restrict__ wd,
                       unsigned short* __restrict__ edot) {
    int p = blockIdx.x * 256 + threadIdx.x;
    if (p >= ETC) return;
    int e = seid[p];
    float a0, a1, a2;
    if (e < EE)       { a0 = ea[e * 3]; a1 = ea[e * 3 + 1]; a2 = ea[e * 3 + 2]; }
    else if (e < E2C) { a0 = 0.5f; a1 = 0.f; a2 = 0.f; }
    else              { int v = e - E2C; a0 = lattr[v * 3]; a1 = lattr[v * 3 + 1]; a2 = lattr[v * 3 + 2]; }
#pragma unroll
    for (int l = 0; l < 3; l++) {
        ushort4 o;
        o.x = f2bf(a0 * wd[l * 12 + 0] + a1 * wd[l * 12 + 4] + a2 * wd[l * 12 + 8]);
        o.y = f2bf(a0 * wd[l * 12 + 1] + a1 * wd[l * 12 + 5] + a2 * wd[l * 12 + 9]);
        o.z = f2bf(a0 * wd[l * 12 + 2] + a1 * wd[l * 12 + 6] + a2 * wd[l * 12 + 10]);
        o.w = f2bf(a0 * wd[l * 12 + 3] + a1 * wd[l * 12 + 7] + a2 * wd[l * 12 + 11]);
        *(ushort4*)(edot + (size_t)l * ETC * 4 + (size_t)p * 4) = o;
    }
}

// ---------- xs = h @ W via bf16 MFMA, N-split: 314 blocks (64 rows x 128 cols) ----------
__global__ void __launch_bounds__(256) k_gemm_mfma(
        const unsigned short* __restrict__ hb, const unsigned short* __restrict__ wt,
        const float* __restrict__ as_, const float* __restrict__ ad_,
        unsigned short* __restrict__ xsb, float* __restrict__ als, float* __restrict__ ald) {
    __shared__ unsigned short tile[64][128];
    int bx = blockIdx.x;
    int v0 = (bx >> 1) * 64;
    int n0 = (bx & 1) * 128;          // column offset; heads hg0 = n0/64 .. +1
    int t = threadIdx.x, lane = t & 63, w = t >> 6;
    int rbase = v0 + w * 16;
    int li = lane & 15, g = lane >> 4;
    int arow = rbase + li; if (arow > NN) arow = NN;
    int koff = g * 8;
    const unsigned short* aptr = hb + (size_t)arow * DD + koff;
    const unsigned short* bptr = wt + (size_t)(n0 + li) * DD + koff;
    f32x4 acc[8];
#pragma unroll
    for (int n = 0; n < 8; n++) acc[n] = (f32x4){0.f, 0.f, 0.f, 0.f};
#pragma unroll
    for (int kb = 0; kb < 8; kb++) {
        s16x8 af = *(const s16x8*)(aptr + kb * 32);
#pragma unroll
        for (int n = 0; n < 8; n++) {
            s16x8 bf = *(const s16x8*)(bptr + (size_t)n * 16 * DD + kb * 32);
            acc[n] = __builtin_amdgcn_mfma_f32_16x16x32_bf16(af, bf, acc[n], 0, 0, 0);
        }
    }
    float asv[8], adv[8];
#pragma unroll
    for (int n = 0; n < 8; n++) { asv[n] = as_[n0 + n * 16 + li]; adv[n] = ad_[n0 + n * 16 + li]; }
    int hg0 = n0 >> 6;
#pragma unroll
    for (int r = 0; r < 4; r++) {
        int vrow = rbase + 4 * g + r;
#pragma unroll
        for (int h = 0; h < 2; h++) {
            float ps = acc[4 * h][r] * asv[4 * h] + acc[4 * h + 1][r] * asv[4 * h + 1]
                     + acc[4 * h + 2][r] * asv[4 * h + 2] + acc[4 * h + 3][r] * asv[4 * h + 3];
            float pd = acc[4 * h][r] * adv[4 * h] + acc[4 * h + 1][r] * adv[4 * h + 1]
                     + acc[4 * h + 2][r] * adv[4 * h + 2] + acc[4 * h + 3][r] * adv[4 * h + 3];
#pragma unroll
            for (int o = 1; o < 16; o <<= 1) {
                ps += __shfl_xor(ps, o, 64);
                pd += __shfl_xor(pd, o, 64);
            }
            if (li == 0 && vrow <= NN) { als[vrow * 4 + hg0 + h] = ps; ald[vrow * 4 + hg0 + h] = pd; }
        }
    }
#pragma unroll
    for (int n = 0; n < 8; n++)
#pragma unroll
        for (int r = 0; r < 4; r++)
            tile[w * 16 + 4 * g + r][n * 16 + li] = f2bf(acc[n][r]);
    // wave-local rows: 16 rows x 16 c8-slots = 256 slots, 4 iters of 64 lanes
#pragma unroll
    for (int it = 0; it < 4; it++) {
        int flat = it * 64 + lane;
        int row = w * 16 + (flat >> 4);
        int c8 = flat & 15;
        int vrow = v0 + row;
        if (vrow <= NN)
            *(uint4*)(xsb + (size_t)vrow * DD + n0 + c8 * 8) = *(const uint4*)(&tile[row][c8 * 8]);
    }
}

// ---------- single-pass softmax-aggregation + fused LN/residual epilogue ----------
// blocks [0..NN): regular dst; block NN: skip; blocks [NT..NT+VB): virtual partials
// (NO device-scope fan-in here: agent fences flush per-XCD L2 and poison the gather locality)
__global__ void __launch_bounds__(256) k_msg(
        const int* __restrict__ offs, const int* __restrict__ ssrc,
        const unsigned short* __restrict__ edotL,
        const float* __restrict__ als, const float* __restrict__ ald,
        const unsigned short* __restrict__ xsb,
        const float* __restrict__ bias, const float* __restrict__ g,
        const float* __restrict__ bt, const float* __restrict__ hin,
        float* __restrict__ hout, unsigned short* __restrict__ hbout,
        float* __restrict__ pvacc, float* __restrict__ pws) {
    int v = blockIdx.x;
    if (v == NN) return;
    int t = threadIdx.x, lane = t & 63, w = t >> 6;
    int sub = lane >> 5, l32 = lane & 31, slot = w * 2 + sub;
    int hh = l32 >> 3;
    __shared__ float red[4][8][33];
    __shared__ float wsred[4][4];
    __shared__ float fin[4];
    __shared__ float2 sm4[4];
    float acc[8];
#pragma unroll
    for (int q = 0; q < 8; q++) acc[q] = 0.f;
    float swt = 0.f;
    if (v >= NT) {
        // ---- virtual-node partial block b = v - NT over rows [b*64, b*64+64) ----
        int b = v - NT;
        int b0 = offs[NN];
        float adh = ald[NN * 4 + hh];
        int i0 = b * 64, i1 = i0 + 64;
        if (i1 > NN + 1) i1 = NN + 1;
        for (int i = i0 + slot; i < i1; i += 8) {
            float a = als[i * 4 + hh] + bf2f(edotL[(size_t)(b0 + i) * 4 + hh]) + adh;
            a = a > 0.f ? a : 0.2f * a;
            float wt = __expf(a);
            uint4 xq = *(const uint4*)(xsb + (size_t)i * DD + l32 * 8);
            const unsigned short* xp = (const unsigned short*)&xq;
#pragma unroll
            for (int q = 0; q < 8; q++) acc[q] += wt * bf2f(xp[q]);
            if ((l32 & 7) == 0) swt += wt;
        }
#pragma unroll
        for (int q = 0; q < 8; q++) acc[q] += __shfl_xor(acc[q], 32, 64);
        swt += __shfl_xor(swt, 32, 64);
        if (sub == 0) {
#pragma unroll
            for (int q = 0; q < 8; q++) red[w][q][l32] = acc[q];
            if ((l32 & 7) == 0) wsred[w][hh] = swt;
        }
        __syncthreads();
        int c = t, q = c & 7, l = c >> 3;
        pvacc[(size_t)b * DD + c] = red[0][q][l] + red[1][q][l] + red[2][q][l] + red[3][q][l];
        if (t < 4) pws[b * 4 + t] = wsred[0][t] + wsred[1][t] + wsred[2][t] + wsred[3][t];
        return;
    }
    // ---- regular dst ----
    int b0 = offs[v], deg = offs[v + 1] - b0;
    float adh = ald[v * 4 + hh];
    for (int i = slot; i < deg; i += 8) {
        int p = b0 + i;
        int src = ssrc[p];
        float a = als[src * 4 + hh] + bf2f(edotL[(size_t)p * 4 + hh]) + adh;
        a = a > 0.f ? a : 0.2f * a;
        float wt = __expf(a);
        uint4 xq = *(const uint4*)(xsb + (size_t)src * DD + l32 * 8);
        const unsigned short* xp = (const unsigned short*)&xq;
#pragma unroll
        for (int q = 0; q < 8; q++) acc[q] += wt * bf2f(xp[q]);
        if ((l32 & 7) == 0) swt += wt;
    }
#pragma unroll
    for (int q = 0; q < 8; q++) acc[q] += __shfl_xor(acc[q], 32, 64);
    swt += __shfl_xor(swt, 32, 64);
    if (sub == 0) {
#pragma unroll
        for (int q = 0; q < 8; q++) red[w][q][l32] = acc[q];   // conflict-free
        if ((l32 & 7) == 0) wsred[w][hh] = swt;
    }
    __syncthreads();
    if (t < 4) {
        float ws = wsred[0][t] + wsred[1][t] + wsred[2][t] + wsred[3][t];
        fin[t] = 1.f / (ws + 1e-16f);
    }
    __syncthreads();
    int c = t, q = c & 7, l = c >> 3;
    float o = (red[0][q][l] + red[1][q][l] + red[2][q][l] + red[3][q][l]) * fin[c >> 6];
    float tt = o + bias[c];
    float2 mm = blk_sum2(tt, tt * tt, sm4);
    float m = mm.x * (1.f / DD);
    float var = mm.y * (1.f / DD) - m * m;
    float y = (tt - m) * rsqrtf(var + 1e-5f) * g[c] + bt[c];
    float r = fmaxf(y + hin[(size_t)v * DD + c], 0.f);
    hout[(size_t)v * DD + c] = r;
    hbout[(size_t)v * DD + c] = f2bf(r);
}

// ---------- virtual-node normalize + LN + residual (+ agent encoder on last) ----------
__global__ void k_vpost(const float* __restrict__ pvacc, const float* __restrict__ pws,
                        const float* __restrict__ bias, const float* __restrict__ g,
                        const float* __restrict__ bt, const float* __restrict__ hin,
                        float* __restrict__ hout, unsigned short* __restrict__ hb,
                        float* __restrict__ jkslot,
                        int last, const float* __restrict__ af,
                        const float* __restrict__ agw, const float* __restrict__ agb,
                        const float* __restrict__ agg, const float* __restrict__ agbt,
                        float* __restrict__ comb) {
    __shared__ float2 sm4[4];
    int j = threadIdx.x, hh = j >> 6;
    float acc = 0.f;
    for (int b = 0; b < VB; b++) acc += pvacc[(size_t)b * DD + j];
    float ws = 0.f;
    for (int b = 0; b < VB; b++) ws += pws[b * 4 + hh];
    float o = acc / (ws + 1e-16f);
    float tt = o + bias[j];
    float2 mm = blk_sum2(tt, tt * tt, sm4);
    float m = mm.x * (1.f / DD);
    float var = mm.y * (1.f / DD) - m * m;
    float y = (tt - m) * rsqrtf(var + 1e-5f) * g[j] + bt[j];
    float r = fmaxf(y + hin[(size_t)NN * DD + j], 0.f);
    hout[(size_t)NN * DD + j] = r;
    hb[(size_t)NN * DD + j] = f2bf(r);
    jkslot[j] = r;
    if (last) {
        float a2 = agb[j];
#pragma unroll
        for (int k = 0; k < 10; k++) a2 += af[k] * agw[k * DD + j];
        float2 m2 = blk_sum2(a2, a2 * a2, sm4);
        float mu = m2.x * (1.f / DD);
        float vv = m2.y * (1.f / DD) - mu * mu;
        float ya = (a2 - mu) * rsqrtf(vv + 1e-5f) * agg[j] + agbt[j];
        comb[1024 + j] = fmaxf(ya, 0.f);
    }
}

// ---------- dueling head: 40 k-slice blocks + fan-in final block ----------
// (fan-in is safe here: nothing else runs concurrently at the tail)
__global__ void k_head(const float* __restrict__ comb,
                       const float* __restrict__ vw1, const float* __restrict__ aw1,
                       float* __restrict__ pv, float* __restrict__ pa,
                       int* __restrict__ cnt,
                       const float* __restrict__ vb1, const float* __restrict__ vg,
                       const float* __restrict__ vbt, const float* __restrict__ vw2,
                       const float* __restrict__ vb2,
                       const float* __restrict__ ab1, const float* __restrict__ ag,
                       const float* __restrict__ abt, const float* __restrict__ aw2,
                       const float* __restrict__ ab2, float* __restrict__ out) {
    __shared__ float2 sm4[4];
    __shared__ float sm1[4];
    __shared__ float tl[DD];
    __shared__ float adv[9];
    __shared__ float valv;
    __shared__ int islast;
    int j = threadIdx.x, s = blockIdx.x;
    int k0 = s * 32;
    float accv = 0.f, acca = 0.f;
#pragma unroll
    for (int kk = 0; kk < 32; kk++) {
        float c = comb[k0 + kk];
        accv += c * vw1[(k0 + kk) * DD + j];
        acca += c * aw1[(k0 + kk) * DD + j];
    }
    pv[s * DD + j] = accv;
    pa[s * DD + j] = acca;
    __threadfence();
    if (j == 0) islast = (atomicAdd(cnt, 1) == 39) ? 1 : 0;
    __syncthreads();
    if (!islast) return;
    __threadfence();
    float acc = vb1[j], acc2 = ab1[j];
    for (int ss = 0; ss < 40; ss++) { acc += pv[ss * DD + j]; acc2 += pa[ss * DD + j]; }
    float2 mm = blk_sum2(acc, acc * acc, sm4);
    float m = mm.x * (1.f / DD);
    float var = mm.y * (1.f / DD) - m * m;
    float y = fmaxf((acc - m) * rsqrtf(var + 1e-5f) * vg[j] + vbt[j], 0.f);
    float vs = blk_sum256(y * vw2[j], sm1);
    if (j == 0) valv = vs + vb2[0];
    float2 mm2 = blk_sum2(acc2, acc2 * acc2, sm4);
    float m2 = mm2.x * (1.f / DD);
    float var2 = mm2.y * (1.f / DD) - m2 * m2;
    float y2 = fmaxf((acc2 - m2) * rsqrtf(var2 + 1e-5f) * ag[j] + abt[j], 0.f);
    tl[j] = y2;
    __syncthreads();
    if (j < 9) {
        float ss = ab2[j];
        for (int k = 0; k < DD; k++) ss += tl[k] * aw2[k * 9 + j];
        adv[j] = ss;
    }
    __syncthreads();
    if (j < 9) {
        float mean = 0.f;
        for (int o = 0; o < 9; o++) mean += adv[o];
        mean *= (1.f / 9.f);
        out[j] = valv + adv[j] - mean;
    }
}

extern "C" void kernel_launch(void* const* d_in, const int* in_sizes, int n_in,
                              void* d_out, int out_size, void* d_ws, size_t ws_size,
                              hipStream_t stream) {
    (void)in_sizes; (void)n_in; (void)out_size; (void)ws_size;
    const float* x      = (const float*)d_in[0];
    const int*   ei     = (const int*)d_in[1];
    const float* ea     = (const float*)d_in[2];
    const float* af     = (const float*)d_in[3];
    const float* enc_w  = (const float*)d_in[4];
    const float* enc_b  = (const float*)d_in[5];
    const float* enc_g  = (const float*)d_in[6];
    const float* enc_bt = (const float*)d_in[7];
    const float* vn_base= (const float*)d_in[8];
    const float* vn_w1  = (const float*)d_in[9];
    const float* vn_b1  = (const float*)d_in[10];
    const float* vn_g   = (const float*)d_in[11];
    const float* vn_bt  = (const float*)d_in[12];
    const float* vn_w2  = (const float*)d_in[13];
    const float* vn_b2  = (const float*)d_in[14];
    const float* gat_w  = (const float*)d_in[15];
    const float* att_src= (const float*)d_in[16];
    const float* att_dst= (const float*)d_in[17];
    const float* att_edge=(const float*)d_in[18];
    const float* edge_w = (const float*)d_in[19];
    const float* gat_b  = (const float*)d_in[20];
    const float* ln_g   = (const float*)d_in[21];
    const float* ln_b   = (const float*)d_in[22];
    const float* ag_w   = (const float*)d_in[23];
    const float* ag_b   = (const float*)d_in[24];
    const float* ag_g   = (const float*)d_in[25];
    const float* ag_bt  = (const float*)d_in[26];
    const float* v_w1   = (const float*)d_in[27];
    const float* v_b1   = (const float*)d_in[28];
    const float* v_g    = (const float*)d_in[29];
    const float* v_bt   = (const float*)d_in[30];
    const float* v_w2   = (const float*)d_in[31];
    const float* v_b2   = (const float*)d_in[32];
    const float* a_w1   = (const float*)d_in[33];
    const float* a_b1   = (const float*)d_in[34];
    const float* a_g    = (const float*)d_in[35];
    const float* a_bt   = (const float*)d_in[36];
    const float* a_w2   = (const float*)d_in[37];
    const float* a_b2   = (const float*)d_in[38];

    char* p = (char*)d_ws;
    auto alloc = [&](size_t bytes) {
        char* r = p;
        p += (bytes + 255) & ~(size_t)255;
        return r;
    };
    float* big0  = (float*)alloc((size_t)NT * DD * 4);
    float* big2  = (float*)alloc((size_t)NT * DD * 4);
    unsigned short* hb   = (unsigned short*)alloc((size_t)NT * DD * 2);
    unsigned short* xsb  = (unsigned short*)alloc((size_t)NT * DD * 2);
    unsigned short* wt   = (unsigned short*)alloc((size_t)3 * DD * DD * 2);
    unsigned short* edot = (unsigned short*)alloc((size_t)3 * ETC * 4 * 2);
    int* ssrc    = (int*)alloc((size_t)ETC * 4);
    int* seid    = (int*)alloc((size_t)ETC * 4);
    float* als   = (float*)alloc((size_t)NT * 4 * 4);
    float* ald   = (float*)alloc((size_t)NT * 4 * 4);
    float* part  = (float*)alloc((size_t)256 * DD * 4);
    float* comb  = (float*)alloc(1280 * 4);
    float* lattr = (float*)alloc((size_t)NT * 3 * 4);
    float* wd    = (float*)alloc(36 * 4);
    float* pvacc = (float*)alloc((size_t)VB * DD * 4);
    float* pws   = (float*)alloc((size_t)VB * 4 * 4);
    float* pv    = (float*)alloc(40 * DD * 4);
    float* pa    = (float*)alloc(40 * DD * 4);
    int* degi    = (int*)alloc((size_t)(NT + 16) * 4);   // degi[NT] then fan-in counter
    int* cnt     = degi + NT;
    int* offs    = (int*)alloc((size_t)(NT + 1) * 4);
    int* cursor  = (int*)alloc((size_t)NT * 4);

    hipMemsetAsync(degi, 0, (size_t)(NT + 16) * 4, stream);

    k_enc<<<2500, 256, 0, stream>>>(x, enc_w, enc_b, enc_g, enc_bt, big0, hb);
    k_ctx1deg<<<256, 256, 0, stream>>>(big0, part, ei, degi);
    k_vn<<<1, 256, 0, stream>>>(part, vn_w1, vn_b1, vn_g, vn_bt, vn_w2, vn_b2, vn_base, big0, hb, comb);
    k_scan<<<1, 1024, 0, stream>>>(degi, offs, cursor);
    k_scatter<<<(EE + 255) / 256, 256, 0, stream>>>(ei, cursor, ssrc, seid);
    k_flattr<<<(NT + 3) / 4, 256, 0, stream>>>(offs, ssrc, seid, ea, lattr);
    k_wconv<<<769, 256, 0, stream>>>(gat_w, wt, edge_w, att_edge, wd);
    k_edot<<<(ETC + 255) / 256, 256, 0, stream>>>(seid, ea, lattr, wd, edot);

    float* cur = big0;
    float* po  = big2;
    for (int l = 0; l < 3; l++) {
        const unsigned short* edotL = edot + (size_t)l * ETC * 4;
        k_gemm_mfma<<<((NT + 63) / 64) * 2, 256, 0, stream>>>(hb, wt + (size_t)l * DD * DD,
                                                              att_src + l * DD, att_dst + l * DD,
                                                              xsb, als, ald);
        k_msg<<<NT + VB, 256, 0, stream>>>(offs, ssrc, edotL, als, ald, xsb,
                                           gat_b + l * DD, ln_g + l * DD, ln_b + l * DD,
                                           cur, po, hb, pvacc, pws);
        k_vpost<<<1, 256, 0, stream>>>(pvacc, pws, gat_b + l * DD, ln_g + l * DD, ln_b + l * DD,
                                       cur, po, hb, comb + (l + 1) * DD,
                                       (l == 2) ? 1 : 0, af, ag_w, ag_b, ag_g, ag_bt, comb);
        float* t = cur; cur = po; po = t;
    }
    k_head<<<40, 256, 0, stream>>>(comb, v_w1, a_w1, pv, pa, cnt,
                                   v_b1, v_g, v_bt, v_w2, v_b2,
                                   a_b1, a_g, a_bt, a_w2, a_b2, (float*)d_out);
}

// Round 10
// 367.289 us; speedup vs baseline: 3.3270x; 1.0027x over previous
//
#include <hip/hip_runtime.h>
#include <math.h>

#define NN 10000
#define EE 320000
#define DD 256
#define NT 10001            // NN + virtual node
#define E1C (EE + NN)       // 330000
#define E2C (EE + 2 * NN)   // 340000
#define ETC (E2C + NT)      // 350001 (with self loops)
#define VB 157              // virtual-node partial blocks (64 rows each)

typedef __attribute__((ext_vector_type(8))) short s16x8;
typedef __attribute__((ext_vector_type(4))) float f32x4;

__device__ __forceinline__ unsigned short f2bf(float f) {
    unsigned u = __float_as_uint(f);
    return (unsigned short)((u + 0x7FFFu + ((u >> 16) & 1u)) >> 16);
}
__device__ __forceinline__ float bf2f(unsigned short u) {
    return __uint_as_float((unsigned)u << 16);
}

// ---------- reduction helpers ----------
__device__ __forceinline__ float wave_sum(float v) {
#pragma unroll
    for (int o = 32; o > 0; o >>= 1) v += __shfl_down(v, o, 64);
    return v;
}
__device__ __forceinline__ float blk_sum256(float v, float* sm4) {
    v = wave_sum(v);
    int lane = threadIdx.x & 63, w = threadIdx.x >> 6;
    __syncthreads();
    if (lane == 0) sm4[w] = v;
    __syncthreads();
    return sm4[0] + sm4[1] + sm4[2] + sm4[3];
}
// fused two-value block sum (one barrier pair)
__device__ __forceinline__ float2 blk_sum2(float a, float b, float2* sm4) {
#pragma unroll
    for (int o = 32; o > 0; o >>= 1) {
        a += __shfl_down(a, o, 64);
        b += __shfl_down(b, o, 64);
    }
    int lane = threadIdx.x & 63, w = threadIdx.x >> 6;
    __syncthreads();
    if (lane == 0) sm4[w] = make_float2(a, b);
    __syncthreads();
    float2 r;
    r.x = sm4[0].x + sm4[1].x + sm4[2].x + sm4[3].x;
    r.y = sm4[0].y + sm4[1].y + sm4[2].y + sm4[3].y;
    return r;
}

// ---------- node encoder: wave-per-row, no __syncthreads ----------
__global__ void __launch_bounds__(256) k_enc(
        const float* __restrict__ x, const float* __restrict__ wenc,
        const float* __restrict__ bia, const float* __restrict__ g,
        const float* __restrict__ bt, float* __restrict__ h,
        unsigned short* __restrict__ hb) {
    int t = threadIdx.x, lane = t & 63, wv = t >> 6;
    int v = blockIdx.x * 4 + wv;
    if (v >= NN) return;
    float xv = (lane < 10) ? x[v * 10 + lane] : 0.f;
    float4 acc = *(const float4*)(bia + lane * 4);
#pragma unroll
    for (int k = 0; k < 10; k++) {
        float xk = __shfl(xv, k, 64);
        float4 wk = *(const float4*)(wenc + k * DD + lane * 4);
        acc.x += xk * wk.x; acc.y += xk * wk.y; acc.z += xk * wk.z; acc.w += xk * wk.w;
    }
    float s1 = acc.x + acc.y + acc.z + acc.w;
    float s2 = acc.x * acc.x + acc.y * acc.y + acc.z * acc.z + acc.w * acc.w;
#pragma unroll
    for (int o = 32; o > 0; o >>= 1) {
        s1 += __shfl_xor(s1, o, 64);
        s2 += __shfl_xor(s2, o, 64);
    }
    float m = s1 * (1.f / DD);
    float var = s2 * (1.f / DD) - m * m;
    float rs = rsqrtf(var + 1e-5f);
    float4 g4 = *(const float4*)(g + lane * 4);
    float4 b4 = *(const float4*)(bt + lane * 4);
    float4 r4;
    r4.x = fmaxf((acc.x - m) * rs * g4.x + b4.x, 0.f);
    r4.y = fmaxf((acc.y - m) * rs * g4.y + b4.y, 0.f);
    r4.z = fmaxf((acc.z - m) * rs * g4.z + b4.z, 0.f);
    r4.w = fmaxf((acc.w - m) * rs * g4.w + b4.w, 0.f);
    *(float4*)(h + (size_t)v * DD + lane * 4) = r4;
    ushort4 u4;
    u4.x = f2bf(r4.x); u4.y = f2bf(r4.y); u4.z = f2bf(r4.z); u4.w = f2bf(r4.w);
    *(ushort4*)(hb + (size_t)v * DD + lane * 4) = u4;
}

// ---------- ctx stage 1 (+ fused regular-edge degree histogram) ----------
__global__ void __launch_bounds__(256) k_ctx1deg(const float* __restrict__ h,
                                                 float* __restrict__ part,
                                                 const int* __restrict__ ei,
                                                 int* __restrict__ degi) {
    __shared__ float4 sm[4][64];
    int t = threadIdx.x, lane = t & 63, w = t >> 6;
    int b = blockIdx.x;
    float4 acc = make_float4(0.f, 0.f, 0.f, 0.f);
    for (int v = b * 4 + w; v < NN; v += 1024) {
        float4 hv = *(const float4*)(h + (size_t)v * DD + lane * 4);
        acc.x += hv.x; acc.y += hv.y; acc.z += hv.z; acc.w += hv.w;
    }
    sm[w][lane] = acc;
    __syncthreads();
    if (t < 64) {
        float4 a0 = sm[0][t], a1 = sm[1][t], a2 = sm[2][t], a3 = sm[3][t];
        float4 r;
        r.x = a0.x + a1.x + a2.x + a3.x;
        r.y = a0.y + a1.y + a2.y + a3.y;
        r.z = a0.z + a1.z + a2.z + a3.z;
        r.w = a0.w + a1.w + a2.w + a3.w;
        *(float4*)(part + (size_t)b * DD + t * 4) = r;
    }
    // fused: regular-edge in-degree histogram (independent work)
    for (int e = b * 256 + t; e < EE; e += 256 * 256)
        atomicAdd(&degi[ei[EE + e]], 1);
}

// ---------- adaptive virtual node (+ fused ctx partial combine) ----------
__global__ void k_vn(const float* __restrict__ part,
                     const float* __restrict__ w1, const float* __restrict__ b1,
                     const float* __restrict__ g, const float* __restrict__ bt,
                     const float* __restrict__ w2, const float* __restrict__ b2,
                     const float* __restrict__ vnb,
                     float* __restrict__ h, unsigned short* __restrict__ hb,
                     float* __restrict__ comb) {
    __shared__ float2 sm4[4];
    __shared__ float cs[DD];
    __shared__ float t[DD];
    int j = threadIdx.x;
    float c = 0.f;
    for (int b = 0; b < 256; b++) c += part[(size_t)b * DD + j];
    cs[j] = c * (1.f / NN);
    __syncthreads();
    float acc = b1[j];
    for (int k = 0; k < DD; k++) acc += cs[k] * w1[k * DD + j];
    float2 mm = blk_sum2(acc, acc * acc, sm4);
    float m = mm.x * (1.f / DD);
    float var = mm.y * (1.f / DD) - m * m;
    float y = fmaxf((acc - m) * rsqrtf(var + 1e-5f) * g[j] + bt[j], 0.f);
    t[j] = y;
    __syncthreads();
    float a2 = b2[j];
    for (int k = 0; k < DD; k++) a2 += t[k] * w2[k * DD + j];
    float vn = vnb[j] + tanhf(a2);
    h[(size_t)NN * DD + j] = vn;
    hb[(size_t)NN * DD + j] = f2bf(vn);
    comb[j] = vn;   // jk slot 0 (virtual row of initial h)
}

// ---------- 1024-wide exclusive scan of (degR + virtual/self additions) ----------
__global__ void k_scan(const int* __restrict__ degi, int* __restrict__ offs,
                       int* __restrict__ cursor) {
    __shared__ int wsum[16];
    __shared__ int running_s;
    int t = threadIdx.x, lane = t & 63, w = t >> 6;
    if (t == 0) running_s = 0;
    __syncthreads();
    for (int base = 0; base < NT; base += 1024) {
        int v = base + t;
        int val = 0;
        if (v < NN) val = degi[v] + 2;          // + vn-edge + self-loop
        else if (v == NN) val = NN + 1;         // virtual: NN in-edges + self-loop
        int x = val;
#pragma unroll
        for (int o = 1; o < 64; o <<= 1) {
            int y = __shfl_up(x, o, 64);
            if (lane >= o) x += y;
        }
        if (lane == 63) wsum[w] = x;
        __syncthreads();
        int prefix = running_s;
        for (int ww = 0; ww < w; ww++) prefix += wsum[ww];
        if (v <= NN) { int e0 = prefix + x - val; offs[v] = e0; cursor[v] = e0; }
        __syncthreads();
        if (t == 0) {
            int s = 0;
            for (int i = 0; i < 16; i++) s += wsum[i];
            running_s += s;
        }
        __syncthreads();
    }
    if (threadIdx.x == 0) offs[NT] = running_s;
}

// ---------- scatter regular edges into CSR (split src / eid arrays) ----------
__global__ void k_scatter(const int* __restrict__ ei, int* __restrict__ cursor,
                          int* __restrict__ ssrc, int* __restrict__ seid) {
    int e = blockIdx.x * 256 + threadIdx.x;
    if (e >= EE) return;
    int src = ei[e], dst = ei[EE + e];
    int pos = atomicAdd(&cursor[dst], 1);
    ssrc[pos] = src;
    seid[pos] = e;
}

// ---------- fused: fill deterministic CSR slots + loop_attr segmented sums ----------
__global__ void k_flattr(const int* __restrict__ offs, int* __restrict__ ssrc,
                         int* __restrict__ seid,
                         const float* __restrict__ ea, float* __restrict__ lattr) {
    int t = threadIdx.x, lane = t & 63, w = t >> 6;
    int v = blockIdx.x * 4 + w;
    if (v > NN) return;
    int bN = offs[NN];
    if (v == NN) {
        if (lane == 0) {
            lattr[v * 3] = 0.5f; lattr[v * 3 + 1] = 0.f; lattr[v * 3 + 2] = 0.f;
            ssrc[bN + NN] = NN; seid[bN + NN] = E2C + NN;   // virtual self loop
        }
        return;
    }
    int b0 = offs[v], e1 = offs[v + 1];
    if (lane == 0) {
        ssrc[e1 - 2] = NN; seid[e1 - 2] = EE + v;       // vn -> v
        ssrc[e1 - 1] = v;  seid[e1 - 1] = E2C + v;      // self loop
        ssrc[bN + v] = v;  seid[bN + v] = E1C + v;      // v -> vn (virtual segment)
    }
    int cnt = e1 - b0 - 2;                       // regular in-edges
    float s0 = 0.f, s1 = 0.f, s2 = 0.f;
    for (int i = lane; i < cnt; i += 64) {
        int e = seid[b0 + i];
        s0 += ea[e * 3];
        s1 += ea[e * 3 + 1];
        s2 += ea[e * 3 + 2];
    }
    s0 = wave_sum(s0); s1 = wave_sum(s1); s2 = wave_sum(s2);
    if (lane == 0) {
        float inv = 1.f / (float)(cnt + 1);      // deg0 = regular + vn edge
        lattr[v * 3]     = (s0 + 0.5f) * inv;
        lattr[v * 3 + 1] = s1 * inv;
        lattr[v * 3 + 2] = s2 * inv;
    }
}

// ---------- weight transpose (blocks 0..767) + we_dot (block 768) ----------
__global__ void k_wconv(const float* __restrict__ gw, unsigned short* __restrict__ wt,
                        const float* __restrict__ ew, const float* __restrict__ ae,
                        float* __restrict__ wd) {
    int b = blockIdx.x, j = threadIdx.x;
    if (b == 768) {
        if (j >= 36) return;
        int l = j / 12, k = (j / 4) % 3, h = j % 4;
        float s = 0.f;
        for (int c = 0; c < 64; c++)
            s += ew[l * 768 + k * DD + h * 64 + c] * ae[l * DD + h * 64 + c];
        wd[j] = s;   // layout [l][k][h]
        return;
    }
    int l = b >> 8, k = b & 255;
    float v = gw[l * 65536 + k * 256 + j];
    wt[l * 65536 + j * 256 + k] = f2bf(v);
}

// ---------- per-edge, per-layer, per-head edge-attr dots, bf16 packed ----------
__global__ void k_edot(const int* __restrict__ seid, const float* __restrict__ ea,
                       const float* __restrict__ lattr, const float* __restrict__ wd,
                       unsigned short* __restrict__ edot) {
    int p = blockIdx.x * 256 + threadIdx.x;
    if (p >= ETC) return;
    int e = seid[p];
    float a0, a1, a2;
    if (e < EE)       { a0 = ea[e * 3]; a1 = ea[e * 3 + 1]; a2 = ea[e * 3 + 2]; }
    else if (e < E2C) { a0 = 0.5f; a1 = 0.f; a2 = 0.f; }
    else              { int v = e - E2C; a0 = lattr[v * 3]; a1 = lattr[v * 3 + 1]; a2 = lattr[v * 3 + 2]; }
#pragma unroll
    for (int l = 0; l < 3; l++) {
        ushort4 o;
        o.x = f2bf(a0 * wd[l * 12 + 0] + a1 * wd[l * 12 + 4] + a2 * wd[l * 12 + 8]);
        o.y = f2bf(a0 * wd[l * 12 + 1] + a1 * wd[l * 12 + 5] + a2 * wd[l * 12 + 9]);
        o.z = f2bf(a0 * wd[l * 12 + 2] + a1 * wd[l * 12 + 6] + a2 * wd[l * 12 + 10]);
        o.w = f2bf(a0 * wd[l * 12 + 3] + a1 * wd[l * 12 + 7] + a2 * wd[l * 12 + 11]);
        *(ushort4*)(edot + (size_t)l * ETC * 4 + (size_t)p * 4) = o;
    }
}

// ---------- xs = h @ W via bf16 MFMA, N-split: 314 blocks (64 rows x 128 cols) ----------
__global__ void __launch_bounds__(256) k_gemm_mfma(
        const unsigned short* __restrict__ hb, const unsigned short* __restrict__ wt,
        const float* __restrict__ as_, const float* __restrict__ ad_,
        unsigned short* __restrict__ xsb, float* __restrict__ als, float* __restrict__ ald) {
    __shared__ unsigned short tile[64][128];
    int bx = blockIdx.x;
    int v0 = (bx >> 1) * 64;
    int n0 = (bx & 1) * 128;          // column offset; heads hg0 = n0/64 .. +1
    int t = threadIdx.x, lane = t & 63, w = t >> 6;
    int rbase = v0 + w * 16;
    int li = lane & 15, g = lane >> 4;
    int arow = rbase + li; if (arow > NN) arow = NN;
    int koff = g * 8;
    const unsigned short* aptr = hb + (size_t)arow * DD + koff;
    const unsigned short* bptr = wt + (size_t)(n0 + li) * DD + koff;
    f32x4 acc[8];
#pragma unroll
    for (int n = 0; n < 8; n++) acc[n] = (f32x4){0.f, 0.f, 0.f, 0.f};
#pragma unroll
    for (int kb = 0; kb < 8; kb++) {
        s16x8 af = *(const s16x8*)(aptr + kb * 32);
#pragma unroll
        for (int n = 0; n < 8; n++) {
            s16x8 bf = *(const s16x8*)(bptr + (size_t)n * 16 * DD + kb * 32);
            acc[n] = __builtin_amdgcn_mfma_f32_16x16x32_bf16(af, bf, acc[n], 0, 0, 0);
        }
    }
    float asv[8], adv[8];
#pragma unroll
    for (int n = 0; n < 8; n++) { asv[n] = as_[n0 + n * 16 + li]; adv[n] = ad_[n0 + n * 16 + li]; }
    int hg0 = n0 >> 6;
#pragma unroll
    for (int r = 0; r < 4; r++) {
        int vrow = rbase + 4 * g + r;
#pragma unroll
        for (int h = 0; h < 2; h++) {
            float ps = acc[4 * h][r] * asv[4 * h] + acc[4 * h + 1][r] * asv[4 * h + 1]
                     + acc[4 * h + 2][r] * asv[4 * h + 2] + acc[4 * h + 3][r] * asv[4 * h + 3];
            float pd = acc[4 * h][r] * adv[4 * h] + acc[4 * h + 1][r] * adv[4 * h + 1]
                     + acc[4 * h + 2][r] * adv[4 * h + 2] + acc[4 * h + 3][r] * adv[4 * h + 3];
#pragma unroll
            for (int o = 1; o < 16; o <<= 1) {
                ps += __shfl_xor(ps, o, 64);
                pd += __shfl_xor(pd, o, 64);
            }
            if (li == 0 && vrow <= NN) { als[vrow * 4 + hg0 + h] = ps; ald[vrow * 4 + hg0 + h] = pd; }
        }
    }
#pragma unroll
    for (int n = 0; n < 8; n++)
#pragma unroll
        for (int r = 0; r < 4; r++)
            tile[w * 16 + 4 * g + r][n * 16 + li] = f2bf(acc[n][r]);
    // wave-local rows: 16 rows x 16 c8-slots = 256 slots, 4 iters of 64 lanes
#pragma unroll
    for (int it = 0; it < 4; it++) {
        int flat = it * 64 + lane;
        int row = w * 16 + (flat >> 4);
        int c8 = flat & 15;
        int vrow = v0 + row;
        if (vrow <= NN)
            *(uint4*)(xsb + (size_t)vrow * DD + n0 + c8 * 8) = *(const uint4*)(&tile[row][c8 * 8]);
    }
}

// ---------- single-pass softmax-aggregation + fused LN/residual epilogue ----------
// blocks [0..NN): regular dst; block NN: skip; blocks [NT..NT+VB): virtual partials
// regular path: phase A resolves {src, w[4]} per edge in parallel (256 threads),
// phase B is a pure pipelined xsb row-gather with LDS-resident addresses/weights.
__global__ void __launch_bounds__(256) k_msg(
        const int* __restrict__ offs, const int* __restrict__ ssrc,
        const unsigned short* __restrict__ edotL,
        const float* __restrict__ als, const float* __restrict__ ald,
        const unsigned short* __restrict__ xsb,
        const float* __restrict__ bias, const float* __restrict__ g,
        const float* __restrict__ bt, const float* __restrict__ hin,
        float* __restrict__ hout, unsigned short* __restrict__ hbout,
        float* __restrict__ pvacc, float* __restrict__ pws) {
    int v = blockIdx.x;
    if (v == NN) return;
    int t = threadIdx.x, lane = t & 63, w = t >> 6;
    int sub = lane >> 5, l32 = lane & 31, slot = w * 2 + sub;
    int hh = l32 >> 3;
    __shared__ float red[4][8][33];
    __shared__ float wsred[4][4];
    __shared__ float fin[4];
    __shared__ float2 sm4[4];
    __shared__ int   lsrc[256];
    __shared__ float lw[256][4];
    float acc[8];
#pragma unroll
    for (int q = 0; q < 8; q++) acc[q] = 0.f;
    float swt = 0.f;
    if (v >= NT) {
        // ---- virtual-node partial block b = v - NT over rows [b*64, b*64+64) ----
        int b = v - NT;
        int b0 = offs[NN];
        float adh = ald[NN * 4 + hh];
        int i0 = b * 64, i1 = i0 + 64;
        if (i1 > NN + 1) i1 = NN + 1;
        for (int i = i0 + slot; i < i1; i += 8) {
            float a = als[i * 4 + hh] + bf2f(edotL[(size_t)(b0 + i) * 4 + hh]) + adh;
            a = a > 0.f ? a : 0.2f * a;
            float wt = __expf(a);
            uint4 xq = *(const uint4*)(xsb + (size_t)i * DD + l32 * 8);
            const unsigned short* xp = (const unsigned short*)&xq;
#pragma unroll
            for (int q = 0; q < 8; q++) acc[q] += wt * bf2f(xp[q]);
            if ((l32 & 7) == 0) swt += wt;
        }
#pragma unroll
        for (int q = 0; q < 8; q++) acc[q] += __shfl_xor(acc[q], 32, 64);
        swt += __shfl_xor(swt, 32, 64);
        if (sub == 0) {
#pragma unroll
            for (int q = 0; q < 8; q++) red[w][q][l32] = acc[q];
            if ((l32 & 7) == 0) wsred[w][hh] = swt;
        }
        __syncthreads();
        int c = t, q = c & 7, l = c >> 3;
        pvacc[(size_t)b * DD + c] = red[0][q][l] + red[1][q][l] + red[2][q][l] + red[3][q][l];
        if (t < 4) pws[b * 4 + t] = wsred[0][t] + wsred[1][t] + wsred[2][t] + wsred[3][t];
        return;
    }
    // ---- regular dst ----
    int b0 = offs[v], deg = offs[v + 1] - b0;
    float4 ad4 = *(const float4*)(ald + v * 4);
    for (int base = 0; base < deg; base += 256) {
        int rem = deg - base; if (rem > 256) rem = 256;
        // phase A: one thread per edge — resolve src + all 4 head weights
        if (t < rem) {
            int p = b0 + base + t;
            int src = ssrc[p];
            lsrc[t] = src;
            ushort4 ed = *(const ushort4*)(edotL + (size_t)p * 4);
            float4 a4 = *(const float4*)(als + src * 4);
            float f0 = a4.x + bf2f(ed.x) + ad4.x; f0 = f0 > 0.f ? f0 : 0.2f * f0;
            float f1 = a4.y + bf2f(ed.y) + ad4.y; f1 = f1 > 0.f ? f1 : 0.2f * f1;
            float f2 = a4.z + bf2f(ed.z) + ad4.z; f2 = f2 > 0.f ? f2 : 0.2f * f2;
            float f3 = a4.w + bf2f(ed.w) + ad4.w; f3 = f3 > 0.f ? f3 : 0.2f * f3;
            lw[t][0] = __expf(f0);
            lw[t][1] = __expf(f1);
            lw[t][2] = __expf(f2);
            lw[t][3] = __expf(f3);
        }
        __syncthreads();
        // phase B: pure gather — addresses/weights from LDS, loads pipeline freely
        for (int i = slot; i < rem; i += 8) {
            float wt = lw[i][hh];
            int src = lsrc[i];
            uint4 xq = *(const uint4*)(xsb + (size_t)src * DD + l32 * 8);
            const unsigned short* xp = (const unsigned short*)&xq;
#pragma unroll
            for (int q = 0; q < 8; q++) acc[q] += wt * bf2f(xp[q]);
            if ((l32 & 7) == 0) swt += wt;
        }
        __syncthreads();
    }
#pragma unroll
    for (int q = 0; q < 8; q++) acc[q] += __shfl_xor(acc[q], 32, 64);
    swt += __shfl_xor(swt, 32, 64);
    if (sub == 0) {
#pragma unroll
        for (int q = 0; q < 8; q++) red[w][q][l32] = acc[q];   // conflict-free
        if ((l32 & 7) == 0) wsred[w][hh] = swt;
    }
    __syncthreads();
    if (t < 4) {
        float ws = wsred[0][t] + wsred[1][t] + wsred[2][t] + wsred[3][t];
        fin[t] = 1.f / (ws + 1e-16f);
    }
    __syncthreads();
    int c = t, q = c & 7, l = c >> 3;
    float o = (red[0][q][l] + red[1][q][l] + red[2][q][l] + red[3][q][l]) * fin[c >> 6];
    float tt = o + bias[c];
    float2 mm = blk_sum2(tt, tt * tt, sm4);
    float m = mm.x * (1.f / DD);
    float var = mm.y * (1.f / DD) - m * m;
    float y = (tt - m) * rsqrtf(var + 1e-5f) * g[c] + bt[c];
    float r = fmaxf(y + hin[(size_t)v * DD + c], 0.f);
    hout[(size_t)v * DD + c] = r;
    hbout[(size_t)v * DD + c] = f2bf(r);
}

// ---------- virtual-node normalize + LN + residual (+ agent encoder on last) ----------
__global__ void k_vpost(const float* __restrict__ pvacc, const float* __restrict__ pws,
                        const float* __restrict__ bias, const float* __restrict__ g,
                        const float* __restrict__ bt, const float* __restrict__ hin,
                        float* __restrict__ hout, unsigned short* __restrict__ hb,
                        float* __restrict__ jkslot,
                        int last, const float* __restrict__ af,
                        const float* __restrict__ agw, const float* __restrict__ agb,
                        const float* __restrict__ agg, const float* __restrict__ agbt,
                        float* __restrict__ comb) {
    __shared__ float2 sm4[4];
    int j = threadIdx.x, hh = j >> 6;
    float acc = 0.f;
    for (int b = 0; b < VB; b++) acc += pvacc[(size_t)b * DD + j];
    float ws = 0.f;
    for (int b = 0; b < VB; b++) ws += pws[b * 4 + hh];
    float o = acc / (ws + 1e-16f);
    float tt = o + bias[j];
    float2 mm = blk_sum2(tt, tt * tt, sm4);
    float m = mm.x * (1.f / DD);
    float var = mm.y * (1.f / DD) - m * m;
    float y = (tt - m) * rsqrtf(var + 1e-5f) * g[j] + bt[j];
    float r = fmaxf(y + hin[(size_t)NN * DD + j], 0.f);
    hout[(size_t)NN * DD + j] = r;
    hb[(size_t)NN * DD + j] = f2bf(r);
    jkslot[j] = r;
    if (last) {
        float a2 = agb[j];
#pragma unroll
        for (int k = 0; k < 10; k++) a2 += af[k] * agw[k * DD + j];
        float2 m2 = blk_sum2(a2, a2 * a2, sm4);
        float mu = m2.x * (1.f / DD);
        float vv = m2.y * (1.f / DD) - mu * mu;
        float ya = (a2 - mu) * rsqrtf(vv + 1e-5f) * agg[j] + agbt[j];
        comb[1024 + j] = fmaxf(ya, 0.f);
    }
}

// ---------- dueling head: 40 k-slice blocks + fan-in final block ----------
// (fan-in is safe here: nothing else runs concurrently at the tail)
__global__ void k_head(const float* __restrict__ comb,
                       const float* __restrict__ vw1, const float* __restrict__ aw1,
                       float* __restrict__ pv, float* __restrict__ pa,
                       int* __restrict__ cnt,
                       const float* __restrict__ vb1, const float* __restrict__ vg,
                       const float* __restrict__ vbt, const float* __restrict__ vw2,
                       const float* __restrict__ vb2,
                       const float* __restrict__ ab1, const float* __restrict__ ag,
                       const float* __restrict__ abt, const float* __restrict__ aw2,
                       const float* __restrict__ ab2, float* __restrict__ out) {
    __shared__ float2 sm4[4];
    __shared__ float sm1[4];
    __shared__ float tl[DD];
    __shared__ float adv[9];
    __shared__ float valv;
    __shared__ int islast;
    int j = threadIdx.x, s = blockIdx.x;
    int k0 = s * 32;
    float accv = 0.f, acca = 0.f;
#pragma unroll
    for (int kk = 0; kk < 32; kk++) {
        float c = comb[k0 + kk];
        accv += c * vw1[(k0 + kk) * DD + j];
        acca += c * aw1[(k0 + kk) * DD + j];
    }
    pv[s * DD + j] = accv;
    pa[s * DD + j] = acca;
    __threadfence();
    if (j == 0) islast = (atomicAdd(cnt, 1) == 39) ? 1 : 0;
    __syncthreads();
    if (!islast) return;
    __threadfence();
    float acc = vb1[j], acc2 = ab1[j];
    for (int ss = 0; ss < 40; ss++) { acc += pv[ss * DD + j]; acc2 += pa[ss * DD + j]; }
    float2 mm = blk_sum2(acc, acc * acc, sm4);
    float m = mm.x * (1.f / DD);
    float var = mm.y * (1.f / DD) - m * m;
    float y = fmaxf((acc - m) * rsqrtf(var + 1e-5f) * vg[j] + vbt[j], 0.f);
    float vs = blk_sum256(y * vw2[j], sm1);
    if (j == 0) valv = vs + vb2[0];
    float2 mm2 = blk_sum2(acc2, acc2 * acc2, sm4);
    float m2 = mm2.x * (1.f / DD);
    float var2 = mm2.y * (1.f / DD) - m2 * m2;
    float y2 = fmaxf((acc2 - m2) * rsqrtf(var2 + 1e-5f) * ag[j] + abt[j], 0.f);
    tl[j] = y2;
    __syncthreads();
    if (j < 9) {
        float ss = ab2[j];
        for (int k = 0; k < DD; k++) ss += tl[k] * aw2[k * 9 + j];
        adv[j] = ss;
    }
    __syncthreads();
    if (j < 9) {
        float mean = 0.f;
        for (int o = 0; o < 9; o++) mean += adv[o];
        mean *= (1.f / 9.f);
        out[j] = valv + adv[j] - mean;
    }
}

extern "C" void kernel_launch(void* const* d_in, const int* in_sizes, int n_in,
                              void* d_out, int out_size, void* d_ws, size_t ws_size,
                              hipStream_t stream) {
    (void)in_sizes; (void)n_in; (void)out_size; (void)ws_size;
    const float* x      = (const float*)d_in[0];
    const int*   ei     = (const int*)d_in[1];
    const float* ea     = (const float*)d_in[2];
    const float* af     = (const float*)d_in[3];
    const float* enc_w  = (const float*)d_in[4];
    const float* enc_b  = (const float*)d_in[5];
    const float* enc_g  = (const float*)d_in[6];
    const float* enc_bt = (const float*)d_in[7];
    const float* vn_base= (const float*)d_in[8];
    const float* vn_w1  = (const float*)d_in[9];
    const float* vn_b1  = (const float*)d_in[10];
    const float* vn_g   = (const float*)d_in[11];
    const float* vn_bt  = (const float*)d_in[12];
    const float* vn_w2  = (const float*)d_in[13];
    const float* vn_b2  = (const float*)d_in[14];
    const float* gat_w  = (const float*)d_in[15];
    const float* att_src= (const float*)d_in[16];
    const float* att_dst= (const float*)d_in[17];
    const float* att_edge=(const float*)d_in[18];
    const float* edge_w = (const float*)d_in[19];
    const float* gat_b  = (const float*)d_in[20];
    const float* ln_g   = (const float*)d_in[21];
    const float* ln_b   = (const float*)d_in[22];
    const float* ag_w   = (const float*)d_in[23];
    const float* ag_b   = (const float*)d_in[24];
    const float* ag_g   = (const float*)d_in[25];
    const float* ag_bt  = (const float*)d_in[26];
    const float* v_w1   = (const float*)d_in[27];
    const float* v_b1   = (const float*)d_in[28];
    const float* v_g    = (const float*)d_in[29];
    const float* v_bt   = (const float*)d_in[30];
    const float* v_w2   = (const float*)d_in[31];
    const float* v_b2   = (const float*)d_in[32];
    const float* a_w1   = (const float*)d_in[33];
    const float* a_b1   = (const float*)d_in[34];
    const float* a_g    = (const float*)d_in[35];
    const float* a_bt   = (const float*)d_in[36];
    const float* a_w2   = (const float*)d_in[37];
    const float* a_b2   = (const float*)d_in[38];

    char* p = (char*)d_ws;
    auto alloc = [&](size_t bytes) {
        char* r = p;
        p += (bytes + 255) & ~(size_t)255;
        return r;
    };
    float* big0  = (float*)alloc((size_t)NT * DD * 4);
    float* big2  = (float*)alloc((size_t)NT * DD * 4);
    unsigned short* hb   = (unsigned short*)alloc((size_t)NT * DD * 2);
    unsigned short* xsb  = (unsigned short*)alloc((size_t)NT * DD * 2);
    unsigned short* wt   = (unsigned short*)alloc((size_t)3 * DD * DD * 2);
    unsigned short* edot = (unsigned short*)alloc((size_t)3 * ETC * 4 * 2);
    int* ssrc    = (int*)alloc((size_t)ETC * 4);
    int* seid    = (int*)alloc((size_t)ETC * 4);
    float* als   = (float*)alloc((size_t)NT * 4 * 4);
    float* ald   = (float*)alloc((size_t)NT * 4 * 4);
    float* part  = (float*)alloc((size_t)256 * DD * 4);
    float* comb  = (float*)alloc(1280 * 4);
    float* lattr = (float*)alloc((size_t)NT * 3 * 4);
    float* wd    = (float*)alloc(36 * 4);
    float* pvacc = (float*)alloc((size_t)VB * DD * 4);
    float* pws   = (float*)alloc((size_t)VB * 4 * 4);
    float* pv    = (float*)alloc(40 * DD * 4);
    float* pa    = (float*)alloc(40 * DD * 4);
    int* degi    = (int*)alloc((size_t)(NT + 16) * 4);   // degi[NT] then fan-in counter
    int* cnt     = degi + NT;
    int* offs    = (int*)alloc((size_t)(NT + 1) * 4);
    int* cursor  = (int*)alloc((size_t)NT * 4);

    hipMemsetAsync(degi, 0, (size_t)(NT + 16) * 4, stream);

    k_enc<<<2500, 256, 0, stream>>>(x, enc_w, enc_b, enc_g, enc_bt, big0, hb);
    k_ctx1deg<<<256, 256, 0, stream>>>(big0, part, ei, degi);
    k_vn<<<1, 256, 0, stream>>>(part, vn_w1, vn_b1, vn_g, vn_bt, vn_w2, vn_b2, vn_base, big0, hb, comb);
    k_scan<<<1, 1024, 0, stream>>>(degi, offs, cursor);
    k_scatter<<<(EE + 255) / 256, 256, 0, stream>>>(ei, cursor, ssrc, seid);
    k_flattr<<<(NT + 3) / 4, 256, 0, stream>>>(offs, ssrc, seid, ea, lattr);
    k_wconv<<<769, 256, 0, stream>>>(gat_w, wt, edge_w, att_edge, wd);
    k_edot<<<(ETC + 255) / 256, 256, 0, stream>>>(seid, ea, lattr, wd, edot);

    float* cur = big0;
    float* po  = big2;
    for (int l = 0; l < 3; l++) {
        const unsigned short* edotL = edot + (size_t)l * ETC * 4;
        k_gemm_mfma<<<((NT + 63) / 64) * 2, 256, 0, stream>>>(hb, wt + (size_t)l * DD * DD,
                                                              att_src + l * DD, att_dst + l * DD,
                                                              xsb, als, ald);
        k_msg<<<NT + VB, 256, 0, stream>>>(offs, ssrc, edotL, als, ald, xsb,
                                           gat_b + l * DD, ln_g + l * DD, ln_b + l * DD,
                                           cur, po, hb, pvacc, pws);
        k_vpost<<<1, 256, 0, stream>>>(pvacc, pws, gat_b + l * DD, ln_g + l * DD, ln_b + l * DD,
                                       cur, po, hb, comb + (l + 1) * DD,
                                       (l == 2) ? 1 : 0, af, ag_w, ag_b, ag_g, ag_bt, comb);
        float* t = cur; cur = po; po = t;
    }
    k_head<<<40, 256, 0, stream>>>(comb, v_w1, a_w1, pv, pa, cnt,
                                   v_b1, v_g, v_bt, v_w2, v_b2,
                                   a_b1, a_g, a_bt, a_w2, a_b2, (float*)d_out);
}

// Round 11
// 335.556 us; speedup vs baseline: 3.6416x; 1.0946x over previous
//
#include <hip/hip_runtime.h>
#include <math.h>

#define NN 10000
#define EE 320000
#define DD 256
#define NT 10001            // NN + virtual node
#define E1C (EE + NN)       // 330000
#define E2C (EE + 2 * NN)   // 340000
#define ETC (E2C + NT)      // 350001 (with self loops)
#define VB 157              // virtual-node partial blocks (64 rows each)
#define RB 2500             // regular-dst blocks (4 dst/block, wave-per-dst)

typedef __attribute__((ext_vector_type(8))) short s16x8;
typedef __attribute__((ext_vector_type(4))) float f32x4;

__device__ __forceinline__ unsigned short f2bf(float f) {
    unsigned u = __float_as_uint(f);
    return (unsigned short)((u + 0x7FFFu + ((u >> 16) & 1u)) >> 16);
}
__device__ __forceinline__ float bf2f(unsigned short u) {
    return __uint_as_float((unsigned)u << 16);
}

// ---------- reduction helpers ----------
__device__ __forceinline__ float wave_sum(float v) {
#pragma unroll
    for (int o = 32; o > 0; o >>= 1) v += __shfl_down(v, o, 64);
    return v;
}
__device__ __forceinline__ float blk_sum256(float v, float* sm4) {
    v = wave_sum(v);
    int lane = threadIdx.x & 63, w = threadIdx.x >> 6;
    __syncthreads();
    if (lane == 0) sm4[w] = v;
    __syncthreads();
    return sm4[0] + sm4[1] + sm4[2] + sm4[3];
}
// fused two-value block sum (one barrier pair)
__device__ __forceinline__ float2 blk_sum2(float a, float b, float2* sm4) {
#pragma unroll
    for (int o = 32; o > 0; o >>= 1) {
        a += __shfl_down(a, o, 64);
        b += __shfl_down(b, o, 64);
    }
    int lane = threadIdx.x & 63, w = threadIdx.x >> 6;
    __syncthreads();
    if (lane == 0) sm4[w] = make_float2(a, b);
    __syncthreads();
    float2 r;
    r.x = sm4[0].x + sm4[1].x + sm4[2].x + sm4[3].x;
    r.y = sm4[0].y + sm4[1].y + sm4[2].y + sm4[3].y;
    return r;
}

// ---------- node encoder: wave-per-row, no __syncthreads ----------
__global__ void __launch_bounds__(256) k_enc(
        const float* __restrict__ x, const float* __restrict__ wenc,
        const float* __restrict__ bia, const float* __restrict__ g,
        const float* __restrict__ bt, float* __restrict__ h,
        unsigned short* __restrict__ hb) {
    int t = threadIdx.x, lane = t & 63, wv = t >> 6;
    int v = blockIdx.x * 4 + wv;
    if (v >= NN) return;
    float xv = (lane < 10) ? x[v * 10 + lane] : 0.f;
    float4 acc = *(const float4*)(bia + lane * 4);
#pragma unroll
    for (int k = 0; k < 10; k++) {
        float xk = __shfl(xv, k, 64);
        float4 wk = *(const float4*)(wenc + k * DD + lane * 4);
        acc.x += xk * wk.x; acc.y += xk * wk.y; acc.z += xk * wk.z; acc.w += xk * wk.w;
    }
    float s1 = acc.x + acc.y + acc.z + acc.w;
    float s2 = acc.x * acc.x + acc.y * acc.y + acc.z * acc.z + acc.w * acc.w;
#pragma unroll
    for (int o = 32; o > 0; o >>= 1) {
        s1 += __shfl_xor(s1, o, 64);
        s2 += __shfl_xor(s2, o, 64);
    }
    float m = s1 * (1.f / DD);
    float var = s2 * (1.f / DD) - m * m;
    float rs = rsqrtf(var + 1e-5f);
    float4 g4 = *(const float4*)(g + lane * 4);
    float4 b4 = *(const float4*)(bt + lane * 4);
    float4 r4;
    r4.x = fmaxf((acc.x - m) * rs * g4.x + b4.x, 0.f);
    r4.y = fmaxf((acc.y - m) * rs * g4.y + b4.y, 0.f);
    r4.z = fmaxf((acc.z - m) * rs * g4.z + b4.z, 0.f);
    r4.w = fmaxf((acc.w - m) * rs * g4.w + b4.w, 0.f);
    *(float4*)(h + (size_t)v * DD + lane * 4) = r4;
    ushort4 u4;
    u4.x = f2bf(r4.x); u4.y = f2bf(r4.y); u4.z = f2bf(r4.z); u4.w = f2bf(r4.w);
    *(ushort4*)(hb + (size_t)v * DD + lane * 4) = u4;
}

// ---------- ctx stage 1 (+ fused regular-edge degree histogram) ----------
__global__ void __launch_bounds__(256) k_ctx1deg(const float* __restrict__ h,
                                                 float* __restrict__ part,
                                                 const int* __restrict__ ei,
                                                 int* __restrict__ degi) {
    __shared__ float4 sm[4][64];
    int t = threadIdx.x, lane = t & 63, w = t >> 6;
    int b = blockIdx.x;
    float4 acc = make_float4(0.f, 0.f, 0.f, 0.f);
    for (int v = b * 4 + w; v < NN; v += 1024) {
        float4 hv = *(const float4*)(h + (size_t)v * DD + lane * 4);
        acc.x += hv.x; acc.y += hv.y; acc.z += hv.z; acc.w += hv.w;
    }
    sm[w][lane] = acc;
    __syncthreads();
    if (t < 64) {
        float4 a0 = sm[0][t], a1 = sm[1][t], a2 = sm[2][t], a3 = sm[3][t];
        float4 r;
        r.x = a0.x + a1.x + a2.x + a3.x;
        r.y = a0.y + a1.y + a2.y + a3.y;
        r.z = a0.z + a1.z + a2.z + a3.z;
        r.w = a0.w + a1.w + a2.w + a3.w;
        *(float4*)(part + (size_t)b * DD + t * 4) = r;
    }
    // fused: regular-edge in-degree histogram (independent work)
    for (int e = b * 256 + t; e < EE; e += 256 * 256)
        atomicAdd(&degi[ei[EE + e]], 1);
}

// ---------- adaptive virtual node (+ fused ctx partial combine) ----------
__global__ void k_vn(const float* __restrict__ part,
                     const float* __restrict__ w1, const float* __restrict__ b1,
                     const float* __restrict__ g, const float* __restrict__ bt,
                     const float* __restrict__ w2, const float* __restrict__ b2,
                     const float* __restrict__ vnb,
                     float* __restrict__ h, unsigned short* __restrict__ hb,
                     float* __restrict__ comb) {
    __shared__ float2 sm4[4];
    __shared__ float cs[DD];
    __shared__ float t[DD];
    int j = threadIdx.x;
    float c = 0.f;
    for (int b = 0; b < 256; b++) c += part[(size_t)b * DD + j];
    cs[j] = c * (1.f / NN);
    __syncthreads();
    float acc = b1[j];
    for (int k = 0; k < DD; k++) acc += cs[k] * w1[k * DD + j];
    float2 mm = blk_sum2(acc, acc * acc, sm4);
    float m = mm.x * (1.f / DD);
    float var = mm.y * (1.f / DD) - m * m;
    float y = fmaxf((acc - m) * rsqrtf(var + 1e-5f) * g[j] + bt[j], 0.f);
    t[j] = y;
    __syncthreads();
    float a2 = b2[j];
    for (int k = 0; k < DD; k++) a2 += t[k] * w2[k * DD + j];
    float vn = vnb[j] + tanhf(a2);
    h[(size_t)NN * DD + j] = vn;
    hb[(size_t)NN * DD + j] = f2bf(vn);
    comb[j] = vn;   // jk slot 0 (virtual row of initial h)
}

// ---------- 1024-wide exclusive scan of (degR + virtual/self additions) ----------
__global__ void k_scan(const int* __restrict__ degi, int* __restrict__ offs,
                       int* __restrict__ cursor) {
    __shared__ int wsum[16];
    __shared__ int running_s;
    int t = threadIdx.x, lane = t & 63, w = t >> 6;
    if (t == 0) running_s = 0;
    __syncthreads();
    for (int base = 0; base < NT; base += 1024) {
        int v = base + t;
        int val = 0;
        if (v < NN) val = degi[v] + 2;          // + vn-edge + self-loop
        else if (v == NN) val = NN + 1;         // virtual: NN in-edges + self-loop
        int x = val;
#pragma unroll
        for (int o = 1; o < 64; o <<= 1) {
            int y = __shfl_up(x, o, 64);
            if (lane >= o) x += y;
        }
        if (lane == 63) wsum[w] = x;
        __syncthreads();
        int prefix = running_s;
        for (int ww = 0; ww < w; ww++) prefix += wsum[ww];
        if (v <= NN) { int e0 = prefix + x - val; offs[v] = e0; cursor[v] = e0; }
        __syncthreads();
        if (t == 0) {
            int s = 0;
            for (int i = 0; i < 16; i++) s += wsum[i];
            running_s += s;
        }
        __syncthreads();
    }
    if (threadIdx.x == 0) offs[NT] = running_s;
}

// ---------- scatter regular edges into CSR (split src / eid arrays) ----------
__global__ void k_scatter(const int* __restrict__ ei, int* __restrict__ cursor,
                          int* __restrict__ ssrc, int* __restrict__ seid) {
    int e = blockIdx.x * 256 + threadIdx.x;
    if (e >= EE) return;
    int src = ei[e], dst = ei[EE + e];
    int pos = atomicAdd(&cursor[dst], 1);
    ssrc[pos] = src;
    seid[pos] = e;
}

// ---------- fused: fill deterministic CSR slots + loop_attr segmented sums ----------
__global__ void k_flattr(const int* __restrict__ offs, int* __restrict__ ssrc,
                         int* __restrict__ seid,
                         const float* __restrict__ ea, float* __restrict__ lattr) {
    int t = threadIdx.x, lane = t & 63, w = t >> 6;
    int v = blockIdx.x * 4 + w;
    if (v > NN) return;
    int bN = offs[NN];
    if (v == NN) {
        if (lane == 0) {
            lattr[v * 3] = 0.5f; lattr[v * 3 + 1] = 0.f; lattr[v * 3 + 2] = 0.f;
            ssrc[bN + NN] = NN; seid[bN + NN] = E2C + NN;   // virtual self loop
        }
        return;
    }
    int b0 = offs[v], e1 = offs[v + 1];
    if (lane == 0) {
        ssrc[e1 - 2] = NN; seid[e1 - 2] = EE + v;       // vn -> v
        ssrc[e1 - 1] = v;  seid[e1 - 1] = E2C + v;      // self loop
        ssrc[bN + v] = v;  seid[bN + v] = E1C + v;      // v -> vn (virtual segment)
    }
    int cnt = e1 - b0 - 2;                       // regular in-edges
    float s0 = 0.f, s1 = 0.f, s2 = 0.f;
    for (int i = lane; i < cnt; i += 64) {
        int e = seid[b0 + i];
        s0 += ea[e * 3];
        s1 += ea[e * 3 + 1];
        s2 += ea[e * 3 + 2];
    }
    s0 = wave_sum(s0); s1 = wave_sum(s1); s2 = wave_sum(s2);
    if (lane == 0) {
        float inv = 1.f / (float)(cnt + 1);      // deg0 = regular + vn edge
        lattr[v * 3]     = (s0 + 0.5f) * inv;
        lattr[v * 3 + 1] = s1 * inv;
        lattr[v * 3 + 2] = s2 * inv;
    }
}

// ---------- weight transpose (blocks 0..767) + we_dot (block 768) ----------
__global__ void k_wconv(const float* __restrict__ gw, unsigned short* __restrict__ wt,
                        const float* __restrict__ ew, const float* __restrict__ ae,
                        float* __restrict__ wd) {
    int b = blockIdx.x, j = threadIdx.x;
    if (b == 768) {
        if (j >= 36) return;
        int l = j / 12, k = (j / 4) % 3, h = j % 4;
        float s = 0.f;
        for (int c = 0; c < 64; c++)
            s += ew[l * 768 + k * DD + h * 64 + c] * ae[l * DD + h * 64 + c];
        wd[j] = s;   // layout [l][k][h]
        return;
    }
    int l = b >> 8, k = b & 255;
    float v = gw[l * 65536 + k * 256 + j];
    wt[l * 65536 + j * 256 + k] = f2bf(v);
}

// ---------- per-edge, per-layer, per-head edge-attr dots, bf16 packed ----------
__global__ void k_edot(const int* __restrict__ seid, const float* __restrict__ ea,
                       const float* __restrict__ lattr, const float* __restrict__ wd,
                       unsigned short* __restrict__ edot) {
    int p = blockIdx.x * 256 + threadIdx.x;
    if (p >= ETC) return;
    int e = seid[p];
    float a0, a1, a2;
    if (e < EE)       { a0 = ea[e * 3]; a1 = ea[e * 3 + 1]; a2 = ea[e * 3 + 2]; }
    else if (e < E2C) { a0 = 0.5f; a1 = 0.f; a2 = 0.f; }
    else              { int v = e - E2C; a0 = lattr[v * 3]; a1 = lattr[v * 3 + 1]; a2 = lattr[v * 3 + 2]; }
#pragma unroll
    for (int l = 0; l < 3; l++) {
        ushort4 o;
        o.x = f2bf(a0 * wd[l * 12 + 0] + a1 * wd[l * 12 + 4] + a2 * wd[l * 12 + 8]);
        o.y = f2bf(a0 * wd[l * 12 + 1] + a1 * wd[l * 12 + 5] + a2 * wd[l * 12 + 9]);
        o.z = f2bf(a0 * wd[l * 12 + 2] + a1 * wd[l * 12 + 6] + a2 * wd[l * 12 + 10]);
        o.w = f2bf(a0 * wd[l * 12 + 3] + a1 * wd[l * 12 + 7] + a2 * wd[l * 12 + 11]);
        *(ushort4*)(edot + (size_t)l * ETC * 4 + (size_t)p * 4) = o;
    }
}

// ---------- xs = h @ W via bf16 MFMA, N-split: 314 blocks (64 rows x 128 cols) ----------
__global__ void __launch_bounds__(256) k_gemm_mfma(
        const unsigned short* __restrict__ hb, const unsigned short* __restrict__ wt,
        const float* __restrict__ as_, const float* __restrict__ ad_,
        unsigned short* __restrict__ xsb, float* __restrict__ als, float* __restrict__ ald) {
    __shared__ unsigned short tile[64][128];
    int bx = blockIdx.x;
    int v0 = (bx >> 1) * 64;
    int n0 = (bx & 1) * 128;          // column offset; heads hg0 = n0/64 .. +1
    int t = threadIdx.x, lane = t & 63, w = t >> 6;
    int rbase = v0 + w * 16;
    int li = lane & 15, g = lane >> 4;
    int arow = rbase + li; if (arow > NN) arow = NN;
    int koff = g * 8;
    const unsigned short* aptr = hb + (size_t)arow * DD + koff;
    const unsigned short* bptr = wt + (size_t)(n0 + li) * DD + koff;
    f32x4 acc[8];
#pragma unroll
    for (int n = 0; n < 8; n++) acc[n] = (f32x4){0.f, 0.f, 0.f, 0.f};
#pragma unroll
    for (int kb = 0; kb < 8; kb++) {
        s16x8 af = *(const s16x8*)(aptr + kb * 32);
#pragma unroll
        for (int n = 0; n < 8; n++) {
            s16x8 bf = *(const s16x8*)(bptr + (size_t)n * 16 * DD + kb * 32);
            acc[n] = __builtin_amdgcn_mfma_f32_16x16x32_bf16(af, bf, acc[n], 0, 0, 0);
        }
    }
    float asv[8], adv[8];
#pragma unroll
    for (int n = 0; n < 8; n++) { asv[n] = as_[n0 + n * 16 + li]; adv[n] = ad_[n0 + n * 16 + li]; }
    int hg0 = n0 >> 6;
#pragma unroll
    for (int r = 0; r < 4; r++) {
        int vrow = rbase + 4 * g + r;
#pragma unroll
        for (int h = 0; h < 2; h++) {
            float ps = acc[4 * h][r] * asv[4 * h] + acc[4 * h + 1][r] * asv[4 * h + 1]
                     + acc[4 * h + 2][r] * asv[4 * h + 2] + acc[4 * h + 3][r] * asv[4 * h + 3];
            float pd = acc[4 * h][r] * adv[4 * h] + acc[4 * h + 1][r] * adv[4 * h + 1]
                     + acc[4 * h + 2][r] * adv[4 * h + 2] + acc[4 * h + 3][r] * adv[4 * h + 3];
#pragma unroll
            for (int o = 1; o < 16; o <<= 1) {
                ps += __shfl_xor(ps, o, 64);
                pd += __shfl_xor(pd, o, 64);
            }
            if (li == 0 && vrow <= NN) { als[vrow * 4 + hg0 + h] = ps; ald[vrow * 4 + hg0 + h] = pd; }
        }
    }
#pragma unroll
    for (int n = 0; n < 8; n++)
#pragma unroll
        for (int r = 0; r < 4; r++)
            tile[w * 16 + 4 * g + r][n * 16 + li] = f2bf(acc[n][r]);
    // wave-local rows: 16 rows x 16 c8-slots = 256 slots, 4 iters of 64 lanes
#pragma unroll
    for (int it = 0; it < 4; it++) {
        int flat = it * 64 + lane;
        int row = w * 16 + (flat >> 4);
        int c8 = flat & 15;
        int vrow = v0 + row;
        if (vrow <= NN)
            *(uint4*)(xsb + (size_t)vrow * DD + n0 + c8 * 8) = *(const uint4*)(&tile[row][c8 * 8]);
    }
}

// ---------- softmax-aggregation + fused LN/residual, WAVE-PER-DST ----------
// blocks [0..RB): 4 regular dsts each (one per wave, no barriers);
// blocks [RB..RB+VB): virtual-node partial blocks (256-thread layout).
__global__ void __launch_bounds__(256) k_msg(
        const int* __restrict__ offs, const int* __restrict__ ssrc,
        const unsigned short* __restrict__ edotL,
        const float* __restrict__ als, const float* __restrict__ ald,
        const unsigned short* __restrict__ xsb,
        const float* __restrict__ bias, const float* __restrict__ g,
        const float* __restrict__ bt, const float* __restrict__ hin,
        float* __restrict__ hout, unsigned short* __restrict__ hbout,
        float* __restrict__ pvacc, float* __restrict__ pws) {
    int b = blockIdx.x;
    int t = threadIdx.x, lane = t & 63, w = t >> 6;
    if (b >= RB) {
        // ---- virtual-node partial block bb over rows [bb*64, bb*64+64) ----
        int sub = lane >> 5, l32 = lane & 31, slot = w * 2 + sub;
        int hh = l32 >> 3;
        __shared__ float red[4][8][33];
        __shared__ float wsred[4][4];
        int bb = b - RB;
        int b0 = offs[NN];
        float adh = ald[NN * 4 + hh];
        int i0 = bb * 64, i1 = i0 + 64;
        if (i1 > NN + 1) i1 = NN + 1;
        float acc[8];
#pragma unroll
        for (int q = 0; q < 8; q++) acc[q] = 0.f;
        float swt = 0.f;
        for (int i = i0 + slot; i < i1; i += 8) {
            float a = als[i * 4 + hh] + bf2f(edotL[(size_t)(b0 + i) * 4 + hh]) + adh;
            a = a > 0.f ? a : 0.2f * a;
            float wt = __expf(a);
            uint4 xq = *(const uint4*)(xsb + (size_t)i * DD + l32 * 8);
            const unsigned short* xp = (const unsigned short*)&xq;
#pragma unroll
            for (int q = 0; q < 8; q++) acc[q] += wt * bf2f(xp[q]);
            if ((l32 & 7) == 0) swt += wt;
        }
#pragma unroll
        for (int q = 0; q < 8; q++) acc[q] += __shfl_xor(acc[q], 32, 64);
        swt += __shfl_xor(swt, 32, 64);
        if (sub == 0) {
#pragma unroll
            for (int q = 0; q < 8; q++) red[w][q][l32] = acc[q];
            if ((l32 & 7) == 0) wsred[w][hh] = swt;
        }
        __syncthreads();
        int c = t, q = c & 7, l = c >> 3;
        pvacc[(size_t)bb * DD + c] = red[0][q][l] + red[1][q][l] + red[2][q][l] + red[3][q][l];
        if (t < 4) pws[bb * 4 + t] = wsred[0][t] + wsred[1][t] + wsred[2][t] + wsred[3][t];
        return;
    }
    // ---- regular dst: wave w owns dst v; lane owns channels lane*4..+3 ----
    __shared__ int   lsrc[4][64];
    __shared__ float lw[4][64][4];
    int v = b * 4 + w;                       // RB*4 == NN exactly
    int b0 = offs[v], deg = offs[v + 1] - b0;
    int hh = lane >> 4;
    float4 ad4 = *(const float4*)(ald + v * 4);
    float a0c = 0.f, a1c = 0.f, a2c = 0.f, a3c = 0.f;
    float ws = 0.f;
    for (int base = 0; base < deg; base += 64) {
        int rem = deg - base; if (rem > 64) rem = 64;
        // phase A: lane e resolves edge e of this chunk (all 4 head weights)
        if (lane < rem) {
            int p = b0 + base + lane;
            int src = ssrc[p];
            lsrc[w][lane] = src;
            ushort4 ed = *(const ushort4*)(edotL + (size_t)p * 4);
            float4 a4 = *(const float4*)(als + src * 4);
            float f0 = a4.x + bf2f(ed.x) + ad4.x; f0 = f0 > 0.f ? f0 : 0.2f * f0;
            float f1 = a4.y + bf2f(ed.y) + ad4.y; f1 = f1 > 0.f ? f1 : 0.2f * f1;
            float f2 = a4.z + bf2f(ed.z) + ad4.z; f2 = f2 > 0.f ? f2 : 0.2f * f2;
            float f3 = a4.w + bf2f(ed.w) + ad4.w; f3 = f3 > 0.f ? f3 : 0.2f * f3;
            lw[w][lane][0] = __expf(f0);
            lw[w][lane][1] = __expf(f1);
            lw[w][lane][2] = __expf(f2);
            lw[w][lane][3] = __expf(f3);
        }
        // wave-synchronous: HW orders ds_write -> ds_read within a wave
        // phase B: stream the rows; every lane accumulates the full head-sum
        for (int i = 0; i < rem; i++) {
            float wt = lw[w][i][hh];
            int src = lsrc[w][i];
            ushort4 xq = *(const ushort4*)(xsb + (size_t)src * DD + lane * 4);
            a0c += wt * bf2f(xq.x);
            a1c += wt * bf2f(xq.y);
            a2c += wt * bf2f(xq.z);
            a3c += wt * bf2f(xq.w);
            ws += wt;
        }
    }
    float inv = 1.f / (ws + 1e-16f);
    float4 bi4 = *(const float4*)(bias + lane * 4);
    float t0 = a0c * inv + bi4.x;
    float t1 = a1c * inv + bi4.y;
    float t2 = a2c * inv + bi4.z;
    float t3 = a3c * inv + bi4.w;
    float s1 = t0 + t1 + t2 + t3;
    float s2 = t0 * t0 + t1 * t1 + t2 * t2 + t3 * t3;
#pragma unroll
    for (int o = 32; o > 0; o >>= 1) {
        s1 += __shfl_xor(s1, o, 64);
        s2 += __shfl_xor(s2, o, 64);
    }
    float m = s1 * (1.f / DD);
    float var = s2 * (1.f / DD) - m * m;
    float rs = rsqrtf(var + 1e-5f);
    float4 g4 = *(const float4*)(g + lane * 4);
    float4 b4 = *(const float4*)(bt + lane * 4);
    float4 h4 = *(const float4*)(hin + (size_t)v * DD + lane * 4);
    float4 r4;
    r4.x = fmaxf((t0 - m) * rs * g4.x + b4.x + h4.x, 0.f);
    r4.y = fmaxf((t1 - m) * rs * g4.y + b4.y + h4.y, 0.f);
    r4.z = fmaxf((t2 - m) * rs * g4.z + b4.z + h4.z, 0.f);
    r4.w = fmaxf((t3 - m) * rs * g4.w + b4.w + h4.w, 0.f);
    *(float4*)(hout + (size_t)v * DD + lane * 4) = r4;
    ushort4 u4;
    u4.x = f2bf(r4.x); u4.y = f2bf(r4.y); u4.z = f2bf(r4.z); u4.w = f2bf(r4.w);
    *(ushort4*)(hbout + (size_t)v * DD + lane * 4) = u4;
}

// ---------- virtual-node normalize + LN + residual (+ agent encoder on last) ----------
__global__ void k_vpost(const float* __restrict__ pvacc, const float* __restrict__ pws,
                        const float* __restrict__ bias, const float* __restrict__ g,
                        const float* __restrict__ bt, const float* __restrict__ hin,
                        float* __restrict__ hout, unsigned short* __restrict__ hb,
                        float* __restrict__ jkslot,
                        int last, const float* __restrict__ af,
                        const float* __restrict__ agw, const float* __restrict__ agb,
                        const float* __restrict__ agg, const float* __restrict__ agbt,
                        float* __restrict__ comb) {
    __shared__ float2 sm4[4];
    int j = threadIdx.x, hh = j >> 6;
    float acc = 0.f;
    for (int b = 0; b < VB; b++) acc += pvacc[(size_t)b * DD + j];
    float ws = 0.f;
    for (int b = 0; b < VB; b++) ws += pws[b * 4 + hh];
    float o = acc / (ws + 1e-16f);
    float tt = o + bias[j];
    float2 mm = blk_sum2(tt, tt * tt, sm4);
    float m = mm.x * (1.f / DD);
    float var = mm.y * (1.f / DD) - m * m;
    float y = (tt - m) * rsqrtf(var + 1e-5f) * g[j] + bt[j];
    float r = fmaxf(y + hin[(size_t)NN * DD + j], 0.f);
    hout[(size_t)NN * DD + j] = r;
    hb[(size_t)NN * DD + j] = f2bf(r);
    jkslot[j] = r;
    if (last) {
        float a2 = agb[j];
#pragma unroll
        for (int k = 0; k < 10; k++) a2 += af[k] * agw[k * DD + j];
        float2 m2 = blk_sum2(a2, a2 * a2, sm4);
        float mu = m2.x * (1.f / DD);
        float vv = m2.y * (1.f / DD) - mu * mu;
        float ya = (a2 - mu) * rsqrtf(vv + 1e-5f) * agg[j] + agbt[j];
        comb[1024 + j] = fmaxf(ya, 0.f);
    }
}

// ---------- dueling head: 40 k-slice blocks + fan-in final block ----------
// (fan-in is safe here: nothing else runs concurrently at the tail)
__global__ void k_head(const float* __restrict__ comb,
                       const float* __restrict__ vw1, const float* __restrict__ aw1,
                       float* __restrict__ pv, float* __restrict__ pa,
                       int* __restrict__ cnt,
                       const float* __restrict__ vb1, const float* __restrict__ vg,
                       const float* __restrict__ vbt, const float* __restrict__ vw2,
                       const float* __restrict__ vb2,
                       const float* __restrict__ ab1, const float* __restrict__ ag,
                       const float* __restrict__ abt, const float* __restrict__ aw2,
                       const float* __restrict__ ab2, float* __restrict__ out) {
    __shared__ float2 sm4[4];
    __shared__ float sm1[4];
    __shared__ float tl[DD];
    __shared__ float adv[9];
    __shared__ float valv;
    __shared__ int islast;
    int j = threadIdx.x, s = blockIdx.x;
    int k0 = s * 32;
    float accv = 0.f, acca = 0.f;
#pragma unroll
    for (int kk = 0; kk < 32; kk++) {
        float c = comb[k0 + kk];
        accv += c * vw1[(k0 + kk) * DD + j];
        acca += c * aw1[(k0 + kk) * DD + j];
    }
    pv[s * DD + j] = accv;
    pa[s * DD + j] = acca;
    __threadfence();
    if (j == 0) islast = (atomicAdd(cnt, 1) == 39) ? 1 : 0;
    __syncthreads();
    if (!islast) return;
    __threadfence();
    float acc = vb1[j], acc2 = ab1[j];
    for (int ss = 0; ss < 40; ss++) { acc += pv[ss * DD + j]; acc2 += pa[ss * DD + j]; }
    float2 mm = blk_sum2(acc, acc * acc, sm4);
    float m = mm.x * (1.f / DD);
    float var = mm.y * (1.f / DD) - m * m;
    float y = fmaxf((acc - m) * rsqrtf(var + 1e-5f) * vg[j] + vbt[j], 0.f);
    float vs = blk_sum256(y * vw2[j], sm1);
    if (j == 0) valv = vs + vb2[0];
    float2 mm2 = blk_sum2(acc2, acc2 * acc2, sm4);
    float m2 = mm2.x * (1.f / DD);
    float var2 = mm2.y * (1.f / DD) - m2 * m2;
    float y2 = fmaxf((acc2 - m2) * rsqrtf(var2 + 1e-5f) * ag[j] + abt[j], 0.f);
    tl[j] = y2;
    __syncthreads();
    if (j < 9) {
        float ss = ab2[j];
        for (int k = 0; k < DD; k++) ss += tl[k] * aw2[k * 9 + j];
        adv[j] = ss;
    }
    __syncthreads();
    if (j < 9) {
        float mean = 0.f;
        for (int o = 0; o < 9; o++) mean += adv[o];
        mean *= (1.f / 9.f);
        out[j] = valv + adv[j] - mean;
    }
}

extern "C" void kernel_launch(void* const* d_in, const int* in_sizes, int n_in,
                              void* d_out, int out_size, void* d_ws, size_t ws_size,
                              hipStream_t stream) {
    (void)in_sizes; (void)n_in; (void)out_size; (void)ws_size;
    const float* x      = (const float*)d_in[0];
    const int*   ei     = (const int*)d_in[1];
    const float* ea     = (const float*)d_in[2];
    const float* af     = (const float*)d_in[3];
    const float* enc_w  = (const float*)d_in[4];
    const float* enc_b  = (const float*)d_in[5];
    const float* enc_g  = (const float*)d_in[6];
    const float* enc_bt = (const float*)d_in[7];
    const float* vn_base= (const float*)d_in[8];
    const float* vn_w1  = (const float*)d_in[9];
    const float* vn_b1  = (const float*)d_in[10];
    const float* vn_g   = (const float*)d_in[11];
    const float* vn_bt  = (const float*)d_in[12];
    const float* vn_w2  = (const float*)d_in[13];
    const float* vn_b2  = (const float*)d_in[14];
    const float* gat_w  = (const float*)d_in[15];
    const float* att_src= (const float*)d_in[16];
    const float* att_dst= (const float*)d_in[17];
    const float* att_edge=(const float*)d_in[18];
    const float* edge_w = (const float*)d_in[19];
    const float* gat_b  = (const float*)d_in[20];
    const float* ln_g   = (const float*)d_in[21];
    const float* ln_b   = (const float*)d_in[22];
    const float* ag_w   = (const float*)d_in[23];
    const float* ag_b   = (const float*)d_in[24];
    const float* ag_g   = (const float*)d_in[25];
    const float* ag_bt  = (const float*)d_in[26];
    const float* v_w1   = (const float*)d_in[27];
    const float* v_b1   = (const float*)d_in[28];
    const float* v_g    = (const float*)d_in[29];
    const float* v_bt   = (const float*)d_in[30];
    const float* v_w2   = (const float*)d_in[31];
    const float* v_b2   = (const float*)d_in[32];
    const float* a_w1   = (const float*)d_in[33];
    const float* a_b1   = (const float*)d_in[34];
    const float* a_g    = (const float*)d_in[35];
    const float* a_bt   = (const float*)d_in[36];
    const float* a_w2   = (const float*)d_in[37];
    const float* a_b2   = (const float*)d_in[38];

    char* p = (char*)d_ws;
    auto alloc = [&](size_t bytes) {
        char* r = p;
        p += (bytes + 255) & ~(size_t)255;
        return r;
    };
    float* big0  = (float*)alloc((size_t)NT * DD * 4);
    float* big2  = (float*)alloc((size_t)NT * DD * 4);
    unsigned short* hb   = (unsigned short*)alloc((size_t)NT * DD * 2);
    unsigned short* xsb  = (unsigned short*)alloc((size_t)NT * DD * 2);
    unsigned short* wt   = (unsigned short*)alloc((size_t)3 * DD * DD * 2);
    unsigned short* edot = (unsigned short*)alloc((size_t)3 * ETC * 4 * 2);
    int* ssrc    = (int*)alloc((size_t)ETC * 4);
    int* seid    = (int*)alloc((size_t)ETC * 4);
    float* als   = (float*)alloc((size_t)NT * 4 * 4);
    float* ald   = (float*)alloc((size_t)NT * 4 * 4);
    float* part  = (float*)alloc((size_t)256 * DD * 4);
    float* comb  = (float*)alloc(1280 * 4);
    float* lattr = (float*)alloc((size_t)NT * 3 * 4);
    float* wd    = (float*)alloc(36 * 4);
    float* pvacc = (float*)alloc((size_t)VB * DD * 4);
    float* pws   = (float*)alloc((size_t)VB * 4 * 4);
    float* pv    = (float*)alloc(40 * DD * 4);
    float* pa    = (float*)alloc(40 * DD * 4);
    int* degi    = (int*)alloc((size_t)(NT + 16) * 4);   // degi[NT] then fan-in counter
    int* cnt     = degi + NT;
    int* offs    = (int*)alloc((size_t)(NT + 1) * 4);
    int* cursor  = (int*)alloc((size_t)NT * 4);

    hipMemsetAsync(degi, 0, (size_t)(NT + 16) * 4, stream);

    k_enc<<<2500, 256, 0, stream>>>(x, enc_w, enc_b, enc_g, enc_bt, big0, hb);
    k_ctx1deg<<<256, 256, 0, stream>>>(big0, part, ei, degi);
    k_vn<<<1, 256, 0, stream>>>(part, vn_w1, vn_b1, vn_g, vn_bt, vn_w2, vn_b2, vn_base, big0, hb, comb);
    k_scan<<<1, 1024, 0, stream>>>(degi, offs, cursor);
    k_scatter<<<(EE + 255) / 256, 256, 0, stream>>>(ei, cursor, ssrc, seid);
    k_flattr<<<(NT + 3) / 4, 256, 0, stream>>>(offs, ssrc, seid, ea, lattr);
    k_wconv<<<769, 256, 0, stream>>>(gat_w, wt, edge_w, att_edge, wd);
    k_edot<<<(ETC + 255) / 256, 256, 0, stream>>>(seid, ea, lattr, wd, edot);

    float* cur = big0;
    float* po  = big2;
    for (int l = 0; l < 3; l++) {
        const unsigned short* edotL = edot + (size_t)l * ETC * 4;
        k_gemm_mfma<<<((NT + 63) / 64) * 2, 256, 0, stream>>>(hb, wt + (size_t)l * DD * DD,
                                                              att_src + l * DD, att_dst + l * DD,
                                                              xsb, als, ald);
        k_msg<<<RB + VB, 256, 0, stream>>>(offs, ssrc, edotL, als, ald, xsb,
                                           gat_b + l * DD, ln_g + l * DD, ln_b + l * DD,
                                           cur, po, hb, pvacc, pws);
        k_vpost<<<1, 256, 0, stream>>>(pvacc, pws, gat_b + l * DD, ln_g + l * DD, ln_b + l * DD,
                                       cur, po, hb, comb + (l + 1) * DD,
                                       (l == 2) ? 1 : 0, af, ag_w, ag_b, ag_g, ag_bt, comb);
        float* t = cur; cur = po; po = t;
    }
    k_head<<<40, 256, 0, stream>>>(comb, v_w1, a_w1, pv, pa, cnt,
                                   v_b1, v_g, v_bt, v_w2, v_b2,
                                   a_b1, a_g, a_bt, a_w2, a_b2, (float*)d_out);
}